// Round 1
// baseline (1095.807 us; speedup 1.0000x reference)
//
#include <hip/hip_runtime.h>
#include <hip/hip_bf16.h>

#define HDIM 2048
#define IDIM 8192
#define NHEADS 16
#define HEADD 128
#define BATCH 2
#define SEQ 2048
#define MTOK 4096

typedef unsigned short u16;
typedef __bf16 bf16x8 __attribute__((ext_vector_type(8)));
typedef float f32x4 __attribute__((ext_vector_type(4)));
typedef unsigned short u16x8 __attribute__((ext_vector_type(8)));

__device__ __forceinline__ u16 f2b(float f) {
  unsigned u = __builtin_bit_cast(unsigned, f);
  u += 0x7FFFu + ((u >> 16) & 1u);
  return (u16)(u >> 16);
}
__device__ __forceinline__ float b2f(u16 b) {
  unsigned u = ((unsigned)b) << 16;
  return __builtin_bit_cast(float, u);
}
// global -> LDS direct copy, 16B per lane. LDS dest must be wave-uniform base;
// HW adds lane*16. CK-style addrspace casts (low 32 bits of generic shared ptr
// are the LDS byte offset).
__device__ __forceinline__ void gl_lds16(const void* g, void* l) {
  auto gp = (const __attribute__((address_space(1))) unsigned int*)((unsigned long long)g);
  auto lp = (__attribute__((address_space(3))) unsigned int*)((unsigned)(unsigned long long)l);
  __builtin_amdgcn_global_load_lds(gp, lp, 16, 0, 0);
}

// ---------------- weight transpose-convert: W (K x N fp32) -> Wt (N x K bf16) ----------------
__global__ __launch_bounds__(256) void wtrans_k(const float* __restrict__ W, u16* __restrict__ Wt,
                                                int K, int N, int rowoff) {
  __shared__ float t[32][33];
  int n0 = blockIdx.x * 32, k0 = blockIdx.y * 32;
  int tx = threadIdx.x, ty = threadIdx.y;
#pragma unroll
  for (int i = 0; i < 4; i++)
    t[ty + i * 8][tx] = W[(size_t)(k0 + ty + i * 8) * N + n0 + tx];
  __syncthreads();
#pragma unroll
  for (int i = 0; i < 4; i++)
    Wt[(size_t)(rowoff + n0 + ty + i * 8) * K + k0 + tx] = f2b(t[tx][ty + i * 8]);
}

// ---------------- V transpose: qkv v-slice (s x d per head) -> vt (bh, d, s) bf16 ----------------
__global__ __launch_bounds__(256) void vtrans_k(const u16* __restrict__ qkv, u16* __restrict__ vt) {
  __shared__ u16 t[32][33];
  int s0 = blockIdx.x * 32, d0 = blockIdx.y * 32, bh = blockIdx.z;
  int b = bh >> 4, h = bh & 15;
  int tx = threadIdx.x, ty = threadIdx.y;
#pragma unroll
  for (int i = 0; i < 4; i++)
    t[ty + i * 8][tx] = qkv[(size_t)(b * SEQ + s0 + ty + i * 8) * 6144 + 4096 + h * HEADD + d0 + tx];
  __syncthreads();
#pragma unroll
  for (int i = 0; i < 4; i++)
    vt[(size_t)(bh * HEADD + d0 + ty + i * 8) * SEQ + s0 + tx] = t[tx][ty + i * 8];
}

// ---------------- RMSNorm: fp32 in -> bf16 out ----------------
__global__ __launch_bounds__(256) void rmsnorm_k(const float* __restrict__ X, const float* __restrict__ W,
                                                 u16* __restrict__ O) {
  int row = blockIdx.x;
  int tid = threadIdx.x;
  const float* x = X + (size_t)row * HDIM;
  float4 v0 = ((const float4*)x)[tid * 2];
  float4 v1 = ((const float4*)x)[tid * 2 + 1];
  float ss = v0.x * v0.x + v0.y * v0.y + v0.z * v0.z + v0.w * v0.w
           + v1.x * v1.x + v1.y * v1.y + v1.z * v1.z + v1.w * v1.w;
#pragma unroll
  for (int off = 32; off > 0; off >>= 1) ss += __shfl_down(ss, off);
  __shared__ float red[4];
  if ((tid & 63) == 0) red[tid >> 6] = ss;
  __syncthreads();
  float rs = rsqrtf((red[0] + red[1] + red[2] + red[3]) * (1.0f / HDIM) + 1e-6f);
  const float* w = W + tid * 8;
  u16* o = O + (size_t)row * HDIM + tid * 8;
  float vals[8] = {v0.x, v0.y, v0.z, v0.w, v1.x, v1.y, v1.z, v1.w};
#pragma unroll
  for (int j = 0; j < 8; j++) o[j] = f2b(w[j] * vals[j] * rs);
}

// ---------------- GEMM: C = A(MxK bf16) * Bt(NxK bf16)^T, 128x128 tile, BK=32 ----------------
// EPI 0: store bf16. 1: store bf16(silu(v)). 2: Gm[idx] = bf16(b2f(Gm[idx]) * v). 3: Cf = Res + v.
template <int EPI>
__global__ __launch_bounds__(256) void gemm_bt(const u16* __restrict__ A, const u16* __restrict__ Bt,
                                               int M, int N, int K,
                                               u16* __restrict__ Cb, float* __restrict__ Cf,
                                               const float* __restrict__ Res, u16* __restrict__ Gm) {
  __shared__ u16 Al[128 * 32];
  __shared__ u16 Bl[128 * 32];
  int tid = threadIdx.x;
  int lane = tid & 63, w = tid >> 6;
  int wm = w >> 1, wn = w & 1;
  int n0 = blockIdx.x * 128, m0 = blockIdx.y * 128;
  const f32x4 fz = {0.f, 0.f, 0.f, 0.f};
  f32x4 acc[4][4];
#pragma unroll
  for (int i = 0; i < 4; i++)
#pragma unroll
    for (int j = 0; j < 4; j++) acc[i][j] = fz;
  int sr = lane >> 2;          // 0..15
  int sc = (lane & 3) * 8;     // 0,8,16,24
  const u16* Ag = A + (size_t)(m0 + w * 32 + sr) * K + sc;
  const u16* Bg = Bt + (size_t)(n0 + w * 32 + sr) * K + sc;
  int arow = wm * 64 + (lane & 15);
  int brow = wn * 64 + (lane & 15);
  int kslice = (lane >> 4) * 8;
  int nk = K >> 5;
  for (int kt = 0; kt < nk; kt++) {
    __syncthreads();
    gl_lds16(Ag + kt * 32,              &Al[(w * 2 + 0) * 512]);
    gl_lds16(Ag + kt * 32 + 16 * K,     &Al[(w * 2 + 1) * 512]);
    gl_lds16(Bg + kt * 32,              &Bl[(w * 2 + 0) * 512]);
    gl_lds16(Bg + kt * 32 + 16 * K,     &Bl[(w * 2 + 1) * 512]);
    __syncthreads();
    bf16x8 a[4], b[4];
#pragma unroll
    for (int mf = 0; mf < 4; mf++)
      a[mf] = *(const bf16x8*)&Al[(arow + mf * 16) * 32 + kslice];
#pragma unroll
    for (int nf = 0; nf < 4; nf++)
      b[nf] = *(const bf16x8*)&Bl[(brow + nf * 16) * 32 + kslice];
#pragma unroll
    for (int mf = 0; mf < 4; mf++)
#pragma unroll
      for (int nf = 0; nf < 4; nf++)
        acc[mf][nf] = __builtin_amdgcn_mfma_f32_16x16x32_bf16(a[mf], b[nf], acc[mf][nf], 0, 0, 0);
  }
  int r0 = (lane >> 4) * 4;
  int cl = lane & 15;
#pragma unroll
  for (int mf = 0; mf < 4; mf++) {
#pragma unroll
    for (int j = 0; j < 4; j++) {
      int m = m0 + wm * 64 + mf * 16 + r0 + j;
#pragma unroll
      for (int nf = 0; nf < 4; nf++) {
        int n = n0 + wn * 64 + nf * 16 + cl;
        float v = acc[mf][nf][j];
        size_t idx = (size_t)m * N + n;
        if (EPI == 0) {
          Cb[idx] = f2b(v);
        } else if (EPI == 1) {
          float sg = v / (1.f + __expf(-v));
          Cb[idx] = f2b(sg);
        } else if (EPI == 2) {
          float gv = b2f(Gm[idx]);
          Gm[idx] = f2b(gv * v);
        } else {
          Cf[idx] = Res[idx] + v;
        }
      }
    }
  }
}

// ---------------- flash attention: grid (qb=32, bh=32), 256 threads ----------------
__global__ __launch_bounds__(256) void attn_k(const u16* __restrict__ qkv, const u16* __restrict__ vt,
                                              u16* __restrict__ out) {
  __shared__ u16 Kl[64 * 128];   // 16KB, swizzled
  __shared__ u16 Vl[128 * 64];   // 16KB, swizzled (rows = d, cols = kv)
  __shared__ u16 Pl[4][16 * 64]; // per-wave P tile
  int tid = threadIdx.x, lane = tid & 63, w = tid >> 6;
  int qb = blockIdx.x, bh = blockIdx.y;
  int b = bh >> 4, h = bh & 15;
  const float scale = 0.088388347648318447f; // 1/sqrt(128)
  int l15 = lane & 15, l4 = lane >> 4;
  // preload Q fragments (A-frag: row = l15, k-slice = l4*8)
  bf16x8 q[4];
  {
    int qrow = qb * 64 + w * 16 + l15;
    const u16* qp = qkv + (size_t)(b * SEQ + qrow) * 6144 + h * HEADD + l4 * 8;
#pragma unroll
    for (int ks = 0; ks < 4; ks++) q[ks] = *(const bf16x8*)(qp + ks * 32);
  }
  const f32x4 fz = {0.f, 0.f, 0.f, 0.f};
  f32x4 o[8];
#pragma unroll
  for (int i = 0; i < 8; i++) o[i] = fz;
  float mrow[4] = {-1e30f, -1e30f, -1e30f, -1e30f};
  float lrow[4] = {0.f, 0.f, 0.f, 0.f};
  char* Kc = (char*)Kl;
  char* Vc = (char*)Vl;
  char* Pc = (char*)&Pl[w][0];
  for (int kv0 = 0; kv0 < SEQ; kv0 += 64) {
    __syncthreads();
#pragma unroll
    for (int it = 0; it < 4; it++) {
      int ch = it * 256 + tid;
      int r = ch >> 4, c = ch & 15;  // K tile: 64 rows x 16 chunks
      u16x8 kd = *(const u16x8*)(qkv + (size_t)(b * SEQ + kv0 + r) * 6144 + HDIM + h * HEADD + c * 8);
      *(u16x8*)(Kc + ((r * 256 + c * 16) ^ ((r & 7) << 4))) = kd;
      int rv = ch >> 3, cv = ch & 7; // V tile: 128 rows x 8 chunks
      u16x8 vd = *(const u16x8*)(vt + (size_t)(bh * HEADD + rv) * SEQ + kv0 + cv * 8);
      *(u16x8*)(Vc + ((rv * 128 + cv * 16) ^ ((rv & 7) << 4))) = vd;
    }
    __syncthreads();
    // S = Q K^T  (16 q-rows x 64 kv)
    f32x4 s[4];
#pragma unroll
    for (int kf = 0; kf < 4; kf++) {
      f32x4 accs = fz;
      int r = kf * 16 + l15;
#pragma unroll
      for (int ks = 0; ks < 4; ks++) {
        bf16x8 kb = *(const bf16x8*)(Kc + ((r * 256 + ks * 64 + l4 * 16) ^ ((r & 7) << 4)));
        accs = __builtin_amdgcn_mfma_f32_16x16x32_bf16(q[ks], kb, accs, 0, 0, 0);
      }
      s[kf] = accs;
    }
    // online softmax (row = l4*4 + j, cols across l15 and kf)
    u16 pb[4][4];
#pragma unroll
    for (int j = 0; j < 4; j++) {
      float vmax = fmaxf(fmaxf(s[0][j], s[1][j]), fmaxf(s[2][j], s[3][j]));
      vmax = fmaxf(vmax, __shfl_xor(vmax, 1));
      vmax = fmaxf(vmax, __shfl_xor(vmax, 2));
      vmax = fmaxf(vmax, __shfl_xor(vmax, 4));
      vmax = fmaxf(vmax, __shfl_xor(vmax, 8));
      float mnew = fmaxf(mrow[j], vmax * scale);
      float alpha = __expf(mrow[j] - mnew);
      mrow[j] = mnew;
      float rsum = 0.f;
#pragma unroll
      for (int kf = 0; kf < 4; kf++) {
        float p = __expf(s[kf][j] * scale - mnew);
        pb[kf][j] = f2b(p);
        rsum += p;
      }
      rsum += __shfl_xor(rsum, 1);
      rsum += __shfl_xor(rsum, 2);
      rsum += __shfl_xor(rsum, 4);
      rsum += __shfl_xor(rsum, 8);
      lrow[j] = lrow[j] * alpha + rsum;
#pragma unroll
      for (int df = 0; df < 8; df++) o[df][j] *= alpha;
    }
    // write P (C-layout) to wave-private LDS
#pragma unroll
    for (int j = 0; j < 4; j++) {
      int r = l4 * 4 + j;
#pragma unroll
      for (int kf = 0; kf < 4; kf++) {
        int col = kf * 16 + l15;
        *(u16*)(Pc + ((r * 128 + col * 2) ^ ((r & 7) << 4))) = pb[kf][j];
      }
    }
    __syncthreads();
    // O += P V   (A-frag of P: row = l15, k = kv)
#pragma unroll
    for (int ks = 0; ks < 2; ks++) {
      bf16x8 pa = *(const bf16x8*)(Pc + ((l15 * 128 + ks * 64 + l4 * 16) ^ ((l15 & 7) << 4)));
#pragma unroll
      for (int df = 0; df < 8; df++) {
        int r = df * 16 + l15;
        bf16x8 vb = *(const bf16x8*)(Vc + ((r * 128 + ks * 64 + l4 * 16) ^ ((r & 7) << 4)));
        o[df] = __builtin_amdgcn_mfma_f32_16x16x32_bf16(pa, vb, o[df], 0, 0, 0);
      }
    }
  }
  int m = b * SEQ + qb * 64 + w * 16;
#pragma unroll
  for (int j = 0; j < 4; j++) {
    float inv = 1.0f / lrow[j];
    int mm = m + l4 * 4 + j;
#pragma unroll
    for (int df = 0; df < 8; df++) {
      out[(size_t)mm * HDIM + h * HEADD + df * 16 + l15] = f2b(o[df][j] * inv);
    }
  }
}

extern "C" void kernel_launch(void* const* d_in, const int* in_sizes, int n_in,
                              void* d_out, int out_size, void* d_ws, size_t ws_size,
                              hipStream_t stream) {
  const float* hs  = (const float*)d_in[0];
  const float* wq  = (const float*)d_in[1];
  const float* wk  = (const float*)d_in[2];
  const float* wv  = (const float*)d_in[3];
  const float* wo  = (const float*)d_in[4];
  const float* wg  = (const float*)d_in[5];
  const float* wu  = (const float*)d_in[6];
  const float* wd  = (const float*)d_in[7];
  const float* ln1 = (const float*)d_in[8];
  const float* ln2 = (const float*)d_in[9];
  char* ws = (char*)d_ws;
  // workspace layout (bytes); total 256 MiB
  u16*   wqkvT = (u16*)(ws);                      // 3H x H bf16   (25,165,824)
  u16*   woT   = (u16*)(ws + 25165824ull);        // H x H         (8,388,608)
  u16*   wgT   = (u16*)(ws + 33554432ull);        // I x H         (33,554,432)
  u16*   wuT   = (u16*)(ws + 67108864ull);        // I x H         (33,554,432)
  u16*   wdT   = (u16*)(ws + 100663296ull);       // H x I         (33,554,432)
  u16*   xb    = (u16*)(ws + 134217728ull);       // M x H bf16    (16,777,216)
  float* hid   = (float*)(ws + 150994944ull);     // M x H fp32    (33,554,432)
  u16*   qkv   = (u16*)(ws + 184549376ull);       // M x 3H bf16   (50,331,648)
  u16*   vtb   = (u16*)(ws + 234881024ull);       // bh x d x s    (16,777,216)
  u16*   attn  = (u16*)(ws + 251658368ull);       // M x H bf16    (16,777,216)
  u16*   g     = qkv;                             // alias: M x I bf16 (67,108,864) over qkv+vt

  dim3 tb(32, 8);
  wtrans_k<<<dim3(64, 64), tb, 0, stream>>>(wq, wqkvT, HDIM, HDIM, 0);
  wtrans_k<<<dim3(64, 64), tb, 0, stream>>>(wk, wqkvT, HDIM, HDIM, 2048);
  wtrans_k<<<dim3(64, 64), tb, 0, stream>>>(wv, wqkvT, HDIM, HDIM, 4096);
  wtrans_k<<<dim3(64, 64), tb, 0, stream>>>(wo, woT, HDIM, HDIM, 0);
  wtrans_k<<<dim3(256, 64), tb, 0, stream>>>(wg, wgT, HDIM, IDIM, 0);
  wtrans_k<<<dim3(256, 64), tb, 0, stream>>>(wu, wuT, HDIM, IDIM, 0);
  wtrans_k<<<dim3(64, 256), tb, 0, stream>>>(wd, wdT, IDIM, HDIM, 0);

  rmsnorm_k<<<MTOK, 256, 0, stream>>>(hs, ln1, xb);
  gemm_bt<0><<<dim3(48, 32), 256, 0, stream>>>(xb, wqkvT, MTOK, 6144, HDIM, qkv, nullptr, nullptr, nullptr);
  vtrans_k<<<dim3(64, 4, 32), tb, 0, stream>>>(qkv, vtb);
  attn_k<<<dim3(32, 32), 256, 0, stream>>>(qkv, vtb, attn);
  gemm_bt<3><<<dim3(16, 32), 256, 0, stream>>>(attn, woT, MTOK, HDIM, HDIM, nullptr, hid, hs, nullptr);
  rmsnorm_k<<<MTOK, 256, 0, stream>>>(hid, ln2, xb);
  gemm_bt<1><<<dim3(64, 32), 256, 0, stream>>>(xb, wgT, MTOK, IDIM, HDIM, g, nullptr, nullptr, nullptr);
  gemm_bt<2><<<dim3(64, 32), 256, 0, stream>>>(xb, wuT, MTOK, IDIM, HDIM, nullptr, nullptr, nullptr, g);
  gemm_bt<3><<<dim3(16, 32), 256, 0, stream>>>(g, wdT, MTOK, HDIM, IDIM, nullptr, (float*)d_out, hid, nullptr);
}

// Round 2
// 894.993 us; speedup vs baseline: 1.2244x; 1.2244x over previous
//
#include <hip/hip_runtime.h>
#include <hip/hip_bf16.h>

#define HDIM 2048
#define IDIM 8192
#define NHEADS 16
#define HEADD 128
#define BATCH 2
#define SEQ 2048
#define MTOK 4096

typedef unsigned short u16;
typedef __bf16 bf16x8 __attribute__((ext_vector_type(8)));
typedef float f32x4 __attribute__((ext_vector_type(4)));
typedef unsigned short u16x8 __attribute__((ext_vector_type(8)));

__device__ __forceinline__ u16 f2b(float f) {
  unsigned u = __builtin_bit_cast(unsigned, f);
  u += 0x7FFFu + ((u >> 16) & 1u);
  return (u16)(u >> 16);
}
__device__ __forceinline__ float b2f(u16 b) {
  unsigned u = ((unsigned)b) << 16;
  return __builtin_bit_cast(float, u);
}
__device__ __forceinline__ void gl_lds16(const void* g, void* l) {
  auto gp = (const __attribute__((address_space(1))) unsigned int*)((unsigned long long)g);
  auto lp = (__attribute__((address_space(3))) unsigned int*)((unsigned)(unsigned long long)l);
  __builtin_amdgcn_global_load_lds(gp, lp, 16, 0, 0);
}

// ---------------- weight transpose-convert: W (K x N fp32) -> Wt (N x K bf16) ----------------
__global__ __launch_bounds__(256) void wtrans_k(const float* __restrict__ W, u16* __restrict__ Wt,
                                                int K, int N, int rowoff) {
  __shared__ float t[32][33];
  int n0 = blockIdx.x * 32, k0 = blockIdx.y * 32;
  int tx = threadIdx.x, ty = threadIdx.y;
#pragma unroll
  for (int i = 0; i < 4; i++)
    t[ty + i * 8][tx] = W[(size_t)(k0 + ty + i * 8) * N + n0 + tx];
  __syncthreads();
#pragma unroll
  for (int i = 0; i < 4; i++)
    Wt[(size_t)(rowoff + n0 + ty + i * 8) * K + k0 + tx] = f2b(t[tx][ty + i * 8]);
}

// ---------------- V transpose ----------------
__global__ __launch_bounds__(256) void vtrans_k(const u16* __restrict__ qkv, u16* __restrict__ vt) {
  __shared__ u16 t[32][33];
  int s0 = blockIdx.x * 32, d0 = blockIdx.y * 32, bh = blockIdx.z;
  int b = bh >> 4, h = bh & 15;
  int tx = threadIdx.x, ty = threadIdx.y;
#pragma unroll
  for (int i = 0; i < 4; i++)
    t[ty + i * 8][tx] = qkv[(size_t)(b * SEQ + s0 + ty + i * 8) * 6144 + 4096 + h * HEADD + d0 + tx];
  __syncthreads();
#pragma unroll
  for (int i = 0; i < 4; i++)
    vt[(size_t)(bh * HEADD + d0 + ty + i * 8) * SEQ + s0 + tx] = t[tx][ty + i * 8];
}

// ---------------- RMSNorm: fp32 in -> bf16 out ----------------
__global__ __launch_bounds__(256) void rmsnorm_k(const float* __restrict__ X, const float* __restrict__ W,
                                                 u16* __restrict__ O) {
  int row = blockIdx.x;
  int tid = threadIdx.x;
  const float* x = X + (size_t)row * HDIM;
  float4 v0 = ((const float4*)x)[tid * 2];
  float4 v1 = ((const float4*)x)[tid * 2 + 1];
  float ss = v0.x * v0.x + v0.y * v0.y + v0.z * v0.z + v0.w * v0.w
           + v1.x * v1.x + v1.y * v1.y + v1.z * v1.z + v1.w * v1.w;
#pragma unroll
  for (int off = 32; off > 0; off >>= 1) ss += __shfl_down(ss, off);
  __shared__ float red[4];
  if ((tid & 63) == 0) red[tid >> 6] = ss;
  __syncthreads();
  float rs = rsqrtf((red[0] + red[1] + red[2] + red[3]) * (1.0f / HDIM) + 1e-6f);
  const float* w = W + tid * 8;
  u16* o = O + (size_t)row * HDIM + tid * 8;
  float vals[8] = {v0.x, v0.y, v0.z, v0.w, v1.x, v1.y, v1.z, v1.w};
#pragma unroll
  for (int j = 0; j < 8; j++) o[j] = f2b(w[j] * vals[j] * rs);
}

// =====================================================================================
// 8-phase GEMM: C(MxN) = A(MxK bf16) * Bt(NxK bf16)^T.  BM=256, BN=128, BK=64.
// 512 threads = 8 waves as 4(M) x 2(N); per-wave output 64x64 (4x4 frags of 16x16).
// LDS: 2 buffers x (A 256x64 + B 128x64) bf16 = 96 KB, XOR-swizzled (slot ^= row&7).
// Staging via global_load_lds w=16 with pre-swizzled global source (rule 21).
// Per K-tile 4 phases; stage order P0:(t+1).B  P1:(t+2).A0  P2:(t+2).A1.
// Boundary s_waitcnt vmcnt(4) (2 half-tiles in flight), never 0 in the loop.
// Read deadlines (drained by lgkmcnt(0) before each phase-end barrier):
//   A0 readers (waves wm<2): all A reads at P0.   A1 readers (wm>=2): by P1.
// EPI 0: store bf16. 1: bf16(silu). 2: Gm *= v. 3: Cf = Res + v (fp32).
// =====================================================================================
template <int EPI>
__global__ __launch_bounds__(512, 2) void gemm256(const u16* __restrict__ A, const u16* __restrict__ Bt,
                                                  int M, int N, int K,
                                                  u16* __restrict__ Cb, float* __restrict__ Cf,
                                                  const float* __restrict__ Res, u16* __restrict__ Gm) {
  __shared__ char lds[98304];
  const int tid = threadIdx.x;
  const int lane = tid & 63, w = tid >> 6;
  const int wm = w >> 1, wn = w & 1;
  // XCD-aware block swizzle (all grids are multiples of 8)
  const int nwg = gridDim.x * gridDim.y;
  const int bid = blockIdx.y * gridDim.x + blockIdx.x;
  const int swz = (bid & 7) * (nwg >> 3) + (bid >> 3);
  const int bx = swz % gridDim.x, by = swz / gridDim.x;
  const int n0 = bx * 128, m0 = by * 256;
  const int NT = K >> 6;

  // staging source (pre-swizzled so linear LDS dest + swizzled read is correct)
  const int r8 = lane >> 3, s8 = lane & 7;
  const int slog8 = (s8 ^ r8) * 8;  // logical k-slot for this lane's LDS slot
  const u16* Abase = A + (size_t)(m0 + w * 8 + r8) * K + slog8;
  const u16* Bbase = Bt + (size_t)(n0 + w * 8 + r8) * K + slog8;
  const int stA = w * 1024;  // wave-uniform LDS byte offset (8 rows * 128B)

#define STAGE_A(buf, kt, h)                                                        \
  {                                                                                \
    const u16* s_ = Abase + (size_t)(h) * 128 * K + (size_t)(kt) * 64;             \
    gl_lds16(s_, lds + (buf) * 49152 + (h) * 16384 + stA);                         \
    gl_lds16(s_ + 64 * (size_t)K, lds + (buf) * 49152 + (h) * 16384 + stA + 8192); \
  }
#define STAGE_B(buf, kt)                                                   \
  {                                                                        \
    const u16* s_ = Bbase + (size_t)(kt) * 64;                             \
    gl_lds16(s_, lds + (buf) * 49152 + 32768 + stA);                       \
    gl_lds16(s_ + 64 * (size_t)K, lds + (buf) * 49152 + 32768 + stA + 8192); \
  }
#define LG0 { asm volatile("s_waitcnt lgkmcnt(0)" ::: "memory"); __builtin_amdgcn_sched_barrier(0); }

  // read-address precompute (byte offsets inside a buffer)
  const int l15 = lane & 15, l4 = lane >> 4;
  const int kq0 = (l4 * 16) ^ ((lane & 7) << 4);
  const int kq1 = (64 + l4 * 16) ^ ((lane & 7) << 4);
  const int aro = (wm >> 1) * 16384 + ((wm & 1) * 64 + l15) * 128;
  const int bro = 32768 + (wn * 64 + l15) * 128;

  const f32x4 fz = {0.f, 0.f, 0.f, 0.f};
  f32x4 acc[4][4];
#pragma unroll
  for (int i = 0; i < 4; i++)
#pragma unroll
    for (int j = 0; j < 4; j++) acc[i][j] = fz;
  bf16x8 af[4][2], bfr[4][2];

  // ---- prologue: stage (0).A0 (0).A1 (0).B (1).A0 (1).A1 ----
  STAGE_A(0, 0, 0);
  STAGE_A(0, 0, 1);
  STAGE_B(0, 0);
  STAGE_A(1, 1, 0);
  STAGE_A(1, 1, 1);
  asm volatile("s_waitcnt vmcnt(4)" ::: "memory");
  __builtin_amdgcn_s_barrier();

  for (int t = 0; t < NT; ++t) {
    const int buf = t & 1;
    const char* Lb = lds + buf * 49152;
    const int t1 = (t + 1 < NT) ? t + 1 : NT - 1;
    const int t2 = (t + 2 < NT) ? t + 2 : NT - 1;
    // ---------- P0 ----------
    if (wm < 2) {
#pragma unroll
      for (int mf = 0; mf < 4; mf++) {
        af[mf][0] = *(const bf16x8*)(Lb + aro + mf * 2048 + kq0);
        af[mf][1] = *(const bf16x8*)(Lb + aro + mf * 2048 + kq1);
      }
    } else {
#pragma unroll
      for (int mf = 0; mf < 4; mf++)
        af[mf][0] = *(const bf16x8*)(Lb + aro + mf * 2048 + kq0);
    }
#pragma unroll
    for (int nf = 0; nf < 4; nf++)
      bfr[nf][0] = *(const bf16x8*)(Lb + bro + nf * 2048 + kq0);
    STAGE_B((t + 1) & 1, t1);
    __builtin_amdgcn_s_barrier();
    LG0;
    __builtin_amdgcn_s_setprio(1);
#pragma unroll
    for (int nf = 0; nf < 4; nf++) {
      acc[0][nf] = __builtin_amdgcn_mfma_f32_16x16x32_bf16(af[0][0], bfr[nf][0], acc[0][nf], 0, 0, 0);
      acc[1][nf] = __builtin_amdgcn_mfma_f32_16x16x32_bf16(af[1][0], bfr[nf][0], acc[1][nf], 0, 0, 0);
    }
    __builtin_amdgcn_s_setprio(0);
    __builtin_amdgcn_s_barrier();
    // ---------- P1 ----------
    if (wm >= 2) {
#pragma unroll
      for (int mf = 0; mf < 4; mf++)
        af[mf][1] = *(const bf16x8*)(Lb + aro + mf * 2048 + kq1);
    }
#pragma unroll
    for (int nf = 0; nf < 4; nf++)
      bfr[nf][1] = *(const bf16x8*)(Lb + bro + nf * 2048 + kq1);
    STAGE_A(buf, t2, 0);
    __builtin_amdgcn_s_barrier();
    LG0;
    __builtin_amdgcn_s_setprio(1);
#pragma unroll
    for (int nf = 0; nf < 4; nf++) {
      acc[2][nf] = __builtin_amdgcn_mfma_f32_16x16x32_bf16(af[2][0], bfr[nf][0], acc[2][nf], 0, 0, 0);
      acc[3][nf] = __builtin_amdgcn_mfma_f32_16x16x32_bf16(af[3][0], bfr[nf][0], acc[3][nf], 0, 0, 0);
    }
    __builtin_amdgcn_s_setprio(0);
    __builtin_amdgcn_s_barrier();
    // ---------- P2 ----------
    STAGE_A(buf, t2, 1);
    __builtin_amdgcn_s_barrier();
    LG0;
    __builtin_amdgcn_s_setprio(1);
#pragma unroll
    for (int nf = 0; nf < 4; nf++) {
      acc[0][nf] = __builtin_amdgcn_mfma_f32_16x16x32_bf16(af[0][1], bfr[nf][1], acc[0][nf], 0, 0, 0);
      acc[1][nf] = __builtin_amdgcn_mfma_f32_16x16x32_bf16(af[1][1], bfr[nf][1], acc[1][nf], 0, 0, 0);
    }
    __builtin_amdgcn_s_setprio(0);
    __builtin_amdgcn_s_barrier();
    // ---------- P3 ----------
    __builtin_amdgcn_s_setprio(1);
#pragma unroll
    for (int nf = 0; nf < 4; nf++) {
      acc[2][nf] = __builtin_amdgcn_mfma_f32_16x16x32_bf16(af[2][1], bfr[nf][1], acc[2][nf], 0, 0, 0);
      acc[3][nf] = __builtin_amdgcn_mfma_f32_16x16x32_bf16(af[3][1], bfr[nf][1], acc[3][nf], 0, 0, 0);
    }
    __builtin_amdgcn_s_setprio(0);
    asm volatile("s_waitcnt vmcnt(4)" ::: "memory");
    __builtin_amdgcn_s_barrier();
  }
  asm volatile("s_waitcnt vmcnt(0)" ::: "memory");

  // ---------- epilogue ----------
  const int r0 = l4 * 4;
#pragma unroll
  for (int mf = 0; mf < 4; mf++) {
#pragma unroll
    for (int j = 0; j < 4; j++) {
      const int m = m0 + wm * 64 + mf * 16 + r0 + j;
#pragma unroll
      for (int nf = 0; nf < 4; nf++) {
        const int n = n0 + wn * 64 + nf * 16 + l15;
        float v = acc[mf][nf][j];
        size_t idx = (size_t)m * N + n;
        if (EPI == 0) {
          Cb[idx] = f2b(v);
        } else if (EPI == 1) {
          float sg = v / (1.f + __expf(-v));
          Cb[idx] = f2b(sg);
        } else if (EPI == 2) {
          float gv = b2f(Gm[idx]);
          Gm[idx] = f2b(gv * v);
        } else {
          Cf[idx] = Res[idx] + v;
        }
      }
    }
  }
#undef STAGE_A
#undef STAGE_B
#undef LG0
}

// ---------------- flash attention: grid (qb=32, bh=32), 256 threads ----------------
__global__ __launch_bounds__(256) void attn_k(const u16* __restrict__ qkv, const u16* __restrict__ vt,
                                              u16* __restrict__ out) {
  __shared__ u16 Kl[64 * 128];
  __shared__ u16 Vl[128 * 64];
  __shared__ u16 Pl[4][16 * 64];
  int tid = threadIdx.x, lane = tid & 63, w = tid >> 6;
  int qb = blockIdx.x, bh = blockIdx.y;
  int b = bh >> 4, h = bh & 15;
  const float scale = 0.088388347648318447f;
  int l15 = lane & 15, l4 = lane >> 4;
  bf16x8 q[4];
  {
    int qrow = qb * 64 + w * 16 + l15;
    const u16* qp = qkv + (size_t)(b * SEQ + qrow) * 6144 + h * HEADD + l4 * 8;
#pragma unroll
    for (int ks = 0; ks < 4; ks++) q[ks] = *(const bf16x8*)(qp + ks * 32);
  }
  const f32x4 fz = {0.f, 0.f, 0.f, 0.f};
  f32x4 o[8];
#pragma unroll
  for (int i = 0; i < 8; i++) o[i] = fz;
  float mrow[4] = {-1e30f, -1e30f, -1e30f, -1e30f};
  float lrow[4] = {0.f, 0.f, 0.f, 0.f};
  char* Kc = (char*)Kl;
  char* Vc = (char*)Vl;
  char* Pc = (char*)&Pl[w][0];
  for (int kv0 = 0; kv0 < SEQ; kv0 += 64) {
    __syncthreads();
#pragma unroll
    for (int it = 0; it < 4; it++) {
      int ch = it * 256 + tid;
      int r = ch >> 4, c = ch & 15;
      u16x8 kd = *(const u16x8*)(qkv + (size_t)(b * SEQ + kv0 + r) * 6144 + HDIM + h * HEADD + c * 8);
      *(u16x8*)(Kc + ((r * 256 + c * 16) ^ ((r & 7) << 4))) = kd;
      int rv = ch >> 3, cv = ch & 7;
      u16x8 vd = *(const u16x8*)(vt + (size_t)(bh * HEADD + rv) * SEQ + kv0 + cv * 8);
      *(u16x8*)(Vc + ((rv * 128 + cv * 16) ^ ((rv & 7) << 4))) = vd;
    }
    __syncthreads();
    f32x4 s[4];
#pragma unroll
    for (int kf = 0; kf < 4; kf++) {
      f32x4 accs = fz;
      int r = kf * 16 + l15;
#pragma unroll
      for (int ks = 0; ks < 4; ks++) {
        bf16x8 kb = *(const bf16x8*)(Kc + ((r * 256 + ks * 64 + l4 * 16) ^ ((r & 7) << 4)));
        accs = __builtin_amdgcn_mfma_f32_16x16x32_bf16(q[ks], kb, accs, 0, 0, 0);
      }
      s[kf] = accs;
    }
    u16 pb[4][4];
#pragma unroll
    for (int j = 0; j < 4; j++) {
      float vmax = fmaxf(fmaxf(s[0][j], s[1][j]), fmaxf(s[2][j], s[3][j]));
      vmax = fmaxf(vmax, __shfl_xor(vmax, 1));
      vmax = fmaxf(vmax, __shfl_xor(vmax, 2));
      vmax = fmaxf(vmax, __shfl_xor(vmax, 4));
      vmax = fmaxf(vmax, __shfl_xor(vmax, 8));
      float mnew = fmaxf(mrow[j], vmax * scale);
      float alpha = __expf(mrow[j] - mnew);
      mrow[j] = mnew;
      float rsum = 0.f;
#pragma unroll
      for (int kf = 0; kf < 4; kf++) {
        float p = __expf(s[kf][j] * scale - mnew);
        pb[kf][j] = f2b(p);
        rsum += p;
      }
      rsum += __shfl_xor(rsum, 1);
      rsum += __shfl_xor(rsum, 2);
      rsum += __shfl_xor(rsum, 4);
      rsum += __shfl_xor(rsum, 8);
      lrow[j] = lrow[j] * alpha + rsum;
#pragma unroll
      for (int df = 0; df < 8; df++) o[df][j] *= alpha;
    }
#pragma unroll
    for (int j = 0; j < 4; j++) {
      int r = l4 * 4 + j;
#pragma unroll
      for (int kf = 0; kf < 4; kf++) {
        int col = kf * 16 + l15;
        *(u16*)(Pc + ((r * 128 + col * 2) ^ ((r & 7) << 4))) = pb[kf][j];
      }
    }
    __syncthreads();
#pragma unroll
    for (int ks = 0; ks < 2; ks++) {
      bf16x8 pa = *(const bf16x8*)(Pc + ((l15 * 128 + ks * 64 + l4 * 16) ^ ((l15 & 7) << 4)));
#pragma unroll
      for (int df = 0; df < 8; df++) {
        int r = df * 16 + l15;
        bf16x8 vb = *(const bf16x8*)(Vc + ((r * 128 + ks * 64 + l4 * 16) ^ ((r & 7) << 4)));
        o[df] = __builtin_amdgcn_mfma_f32_16x16x32_bf16(pa, vb, o[df], 0, 0, 0);
      }
    }
  }
  int m = b * SEQ + qb * 64 + w * 16;
#pragma unroll
  for (int j = 0; j < 4; j++) {
    float inv = 1.0f / lrow[j];
    int mm = m + l4 * 4 + j;
#pragma unroll
    for (int df = 0; df < 8; df++) {
      out[(size_t)mm * HDIM + h * HEADD + df * 16 + l15] = f2b(o[df][j] * inv);
    }
  }
}

extern "C" void kernel_launch(void* const* d_in, const int* in_sizes, int n_in,
                              void* d_out, int out_size, void* d_ws, size_t ws_size,
                              hipStream_t stream) {
  const float* hs  = (const float*)d_in[0];
  const float* wq  = (const float*)d_in[1];
  const float* wk  = (const float*)d_in[2];
  const float* wv  = (const float*)d_in[3];
  const float* wo  = (const float*)d_in[4];
  const float* wg  = (const float*)d_in[5];
  const float* wu  = (const float*)d_in[6];
  const float* wd  = (const float*)d_in[7];
  const float* ln1 = (const float*)d_in[8];
  const float* ln2 = (const float*)d_in[9];
  char* ws = (char*)d_ws;
  u16*   wqkvT = (u16*)(ws);
  u16*   woT   = (u16*)(ws + 25165824ull);
  u16*   wgT   = (u16*)(ws + 33554432ull);
  u16*   wuT   = (u16*)(ws + 67108864ull);
  u16*   wdT   = (u16*)(ws + 100663296ull);
  u16*   xb    = (u16*)(ws + 134217728ull);
  float* hid   = (float*)(ws + 150994944ull);
  u16*   qkv   = (u16*)(ws + 184549376ull);
  u16*   vtb   = (u16*)(ws + 234881024ull);
  u16*   attn  = (u16*)(ws + 251658368ull);
  u16*   g     = qkv;  // alias M x I bf16 over qkv+vt region

  dim3 tb(32, 8);
  wtrans_k<<<dim3(64, 64), tb, 0, stream>>>(wq, wqkvT, HDIM, HDIM, 0);
  wtrans_k<<<dim3(64, 64), tb, 0, stream>>>(wk, wqkvT, HDIM, HDIM, 2048);
  wtrans_k<<<dim3(64, 64), tb, 0, stream>>>(wv, wqkvT, HDIM, HDIM, 4096);
  wtrans_k<<<dim3(64, 64), tb, 0, stream>>>(wo, woT, HDIM, HDIM, 0);
  wtrans_k<<<dim3(256, 64), tb, 0, stream>>>(wg, wgT, HDIM, IDIM, 0);
  wtrans_k<<<dim3(256, 64), tb, 0, stream>>>(wu, wuT, HDIM, IDIM, 0);
  wtrans_k<<<dim3(64, 256), tb, 0, stream>>>(wd, wdT, IDIM, HDIM, 0);

  rmsnorm_k<<<MTOK, 256, 0, stream>>>(hs, ln1, xb);
  gemm256<0><<<dim3(48, 16), 512, 0, stream>>>(xb, wqkvT, MTOK, 6144, HDIM, qkv, nullptr, nullptr, nullptr);
  vtrans_k<<<dim3(64, 4, 32), tb, 0, stream>>>(qkv, vtb);
  attn_k<<<dim3(32, 32), 256, 0, stream>>>(qkv, vtb, attn);
  gemm256<3><<<dim3(16, 16), 512, 0, stream>>>(attn, woT, MTOK, HDIM, HDIM, nullptr, hid, hs, nullptr);
  rmsnorm_k<<<MTOK, 256, 0, stream>>>(hid, ln2, xb);
  gemm256<1><<<dim3(64, 16), 512, 0, stream>>>(xb, wgT, MTOK, IDIM, HDIM, g, nullptr, nullptr, nullptr);
  gemm256<2><<<dim3(64, 16), 512, 0, stream>>>(xb, wuT, MTOK, IDIM, HDIM, nullptr, nullptr, nullptr, g);
  gemm256<3><<<dim3(16, 16), 512, 0, stream>>>(g, wdT, MTOK, HDIM, IDIM, nullptr, (float*)d_out, hid, nullptr);
}

// Round 3
// 877.714 us; speedup vs baseline: 1.2485x; 1.0197x over previous
//
#include <hip/hip_runtime.h>
#include <hip/hip_bf16.h>

#define HDIM 2048
#define IDIM 8192
#define NHEADS 16
#define HEADD 128
#define BATCH 2
#define SEQ 2048
#define MTOK 4096

typedef unsigned short u16;
typedef __bf16 bf16x8 __attribute__((ext_vector_type(8)));
typedef float f32x4 __attribute__((ext_vector_type(4)));
typedef unsigned short u16x8 __attribute__((ext_vector_type(8)));

__device__ __forceinline__ u16 f2b(float f) {
  unsigned u = __builtin_bit_cast(unsigned, f);
  u += 0x7FFFu + ((u >> 16) & 1u);
  return (u16)(u >> 16);
}
__device__ __forceinline__ float b2f(u16 b) {
  unsigned u = ((unsigned)b) << 16;
  return __builtin_bit_cast(float, u);
}
__device__ __forceinline__ void gl_lds16(const void* g, void* l) {
  auto gp = (const __attribute__((address_space(1))) unsigned int*)((unsigned long long)g);
  auto lp = (__attribute__((address_space(3))) unsigned int*)((unsigned)(unsigned long long)l);
  __builtin_amdgcn_global_load_lds(gp, lp, 16, 0, 0);
}

// ---------------- weight transpose-convert: W (K x N fp32) -> Wt (N x K bf16) ----------------
// 64x64 tile, float4 loads, u16x8 stores.
__global__ __launch_bounds__(256) void wtrans_k(const float* __restrict__ W, u16* __restrict__ Wt,
                                                int K, int N, int rowoff) {
  __shared__ float t[64][65];
  int n0 = blockIdx.x * 64, k0 = blockIdx.y * 64;
  int tid = threadIdx.x;
  int kr = tid >> 4, nc = (tid & 15) * 4;
#pragma unroll
  for (int p = 0; p < 4; p++) {
    float4 v = *(const float4*)&W[(size_t)(k0 + p * 16 + kr) * N + n0 + nc];
    t[nc + 0][p * 16 + kr] = v.x;
    t[nc + 1][p * 16 + kr] = v.y;
    t[nc + 2][p * 16 + kr] = v.z;
    t[nc + 3][p * 16 + kr] = v.w;
  }
  __syncthreads();
  int n = tid >> 2, kq = (tid & 3) * 16;
  u16 tmp[16];
#pragma unroll
  for (int i = 0; i < 16; i++) tmp[i] = f2b(t[n][kq + i]);
  *(u16x8*)&Wt[(size_t)(rowoff + n0 + n) * K + k0 + kq] = *(u16x8*)&tmp[0];
  *(u16x8*)&Wt[(size_t)(rowoff + n0 + n) * K + k0 + kq + 8] = *(u16x8*)&tmp[8];
}

// ---------------- V transpose ----------------
__global__ __launch_bounds__(256) void vtrans_k(const u16* __restrict__ qkv, u16* __restrict__ vt) {
  __shared__ u16 t[32][33];
  int s0 = blockIdx.x * 32, d0 = blockIdx.y * 32, bh = blockIdx.z;
  int b = bh >> 4, h = bh & 15;
  int tx = threadIdx.x, ty = threadIdx.y;
#pragma unroll
  for (int i = 0; i < 4; i++)
    t[ty + i * 8][tx] = qkv[(size_t)(b * SEQ + s0 + ty + i * 8) * 6144 + 4096 + h * HEADD + d0 + tx];
  __syncthreads();
#pragma unroll
  for (int i = 0; i < 4; i++)
    vt[(size_t)(bh * HEADD + d0 + ty + i * 8) * SEQ + s0 + tx] = t[tx][ty + i * 8];
}

// ---------------- RMSNorm: fp32 in -> bf16 out ----------------
__global__ __launch_bounds__(256) void rmsnorm_k(const float* __restrict__ X, const float* __restrict__ W,
                                                 u16* __restrict__ O) {
  int row = blockIdx.x;
  int tid = threadIdx.x;
  const float* x = X + (size_t)row * HDIM;
  float4 v0 = ((const float4*)x)[tid * 2];
  float4 v1 = ((const float4*)x)[tid * 2 + 1];
  float ss = v0.x * v0.x + v0.y * v0.y + v0.z * v0.z + v0.w * v0.w
           + v1.x * v1.x + v1.y * v1.y + v1.z * v1.z + v1.w * v1.w;
#pragma unroll
  for (int off = 32; off > 0; off >>= 1) ss += __shfl_down(ss, off);
  __shared__ float red[4];
  if ((tid & 63) == 0) red[tid >> 6] = ss;
  __syncthreads();
  float rs = rsqrtf((red[0] + red[1] + red[2] + red[3]) * (1.0f / HDIM) + 1e-6f);
  const float* w = W + tid * 8;
  u16* o = O + (size_t)row * HDIM + tid * 8;
  float vals[8] = {v0.x, v0.y, v0.z, v0.w, v1.x, v1.y, v1.z, v1.w};
#pragma unroll
  for (int j = 0; j < 8; j++) o[j] = f2b(w[j] * vals[j] * rs);
}

// =====================================================================================
// 8-phase GEMM (unchanged from round 1): C(MxN) = A(MxK bf16) * Bt(NxK bf16)^T.
// =====================================================================================
template <int EPI>
__global__ __launch_bounds__(512, 2) void gemm256(const u16* __restrict__ A, const u16* __restrict__ Bt,
                                                  int M, int N, int K,
                                                  u16* __restrict__ Cb, float* __restrict__ Cf,
                                                  const float* __restrict__ Res, u16* __restrict__ Gm) {
  __shared__ char lds[98304];
  const int tid = threadIdx.x;
  const int lane = tid & 63, w = tid >> 6;
  const int wm = w >> 1, wn = w & 1;
  const int nwg = gridDim.x * gridDim.y;
  const int bid = blockIdx.y * gridDim.x + blockIdx.x;
  const int swz = (bid & 7) * (nwg >> 3) + (bid >> 3);
  const int bx = swz % gridDim.x, by = swz / gridDim.x;
  const int n0 = bx * 128, m0 = by * 256;
  const int NT = K >> 6;

  const int r8 = lane >> 3, s8 = lane & 7;
  const int slog8 = (s8 ^ r8) * 8;
  const u16* Abase = A + (size_t)(m0 + w * 8 + r8) * K + slog8;
  const u16* Bbase = Bt + (size_t)(n0 + w * 8 + r8) * K + slog8;
  const int stA = w * 1024;

#define STAGE_A(buf, kt, h)                                                        \
  {                                                                                \
    const u16* s_ = Abase + (size_t)(h) * 128 * K + (size_t)(kt) * 64;             \
    gl_lds16(s_, lds + (buf) * 49152 + (h) * 16384 + stA);                         \
    gl_lds16(s_ + 64 * (size_t)K, lds + (buf) * 49152 + (h) * 16384 + stA + 8192); \
  }
#define STAGE_B(buf, kt)                                                     \
  {                                                                          \
    const u16* s_ = Bbase + (size_t)(kt) * 64;                               \
    gl_lds16(s_, lds + (buf) * 49152 + 32768 + stA);                         \
    gl_lds16(s_ + 64 * (size_t)K, lds + (buf) * 49152 + 32768 + stA + 8192); \
  }
#define LG0 { asm volatile("s_waitcnt lgkmcnt(0)" ::: "memory"); __builtin_amdgcn_sched_barrier(0); }

  const int l15 = lane & 15, l4 = lane >> 4;
  const int kq0 = (l4 * 16) ^ ((lane & 7) << 4);
  const int kq1 = (64 + l4 * 16) ^ ((lane & 7) << 4);
  const int aro = (wm >> 1) * 16384 + ((wm & 1) * 64 + l15) * 128;
  const int bro = 32768 + (wn * 64 + l15) * 128;

  const f32x4 fz = {0.f, 0.f, 0.f, 0.f};
  f32x4 acc[4][4];
#pragma unroll
  for (int i = 0; i < 4; i++)
#pragma unroll
    for (int j = 0; j < 4; j++) acc[i][j] = fz;
  bf16x8 af[4][2], bfr[4][2];

  STAGE_A(0, 0, 0);
  STAGE_A(0, 0, 1);
  STAGE_B(0, 0);
  STAGE_A(1, 1, 0);
  STAGE_A(1, 1, 1);
  asm volatile("s_waitcnt vmcnt(4)" ::: "memory");
  __builtin_amdgcn_s_barrier();

  for (int t = 0; t < NT; ++t) {
    const int buf = t & 1;
    const char* Lb = lds + buf * 49152;
    const int t1 = (t + 1 < NT) ? t + 1 : NT - 1;
    const int t2 = (t + 2 < NT) ? t + 2 : NT - 1;
    // ---------- P0 ----------
    if (wm < 2) {
#pragma unroll
      for (int mf = 0; mf < 4; mf++) {
        af[mf][0] = *(const bf16x8*)(Lb + aro + mf * 2048 + kq0);
        af[mf][1] = *(const bf16x8*)(Lb + aro + mf * 2048 + kq1);
      }
    } else {
#pragma unroll
      for (int mf = 0; mf < 4; mf++)
        af[mf][0] = *(const bf16x8*)(Lb + aro + mf * 2048 + kq0);
    }
#pragma unroll
    for (int nf = 0; nf < 4; nf++)
      bfr[nf][0] = *(const bf16x8*)(Lb + bro + nf * 2048 + kq0);
    STAGE_B((t + 1) & 1, t1);
    __builtin_amdgcn_s_barrier();
    LG0;
    __builtin_amdgcn_s_setprio(1);
#pragma unroll
    for (int nf = 0; nf < 4; nf++) {
      acc[0][nf] = __builtin_amdgcn_mfma_f32_16x16x32_bf16(af[0][0], bfr[nf][0], acc[0][nf], 0, 0, 0);
      acc[1][nf] = __builtin_amdgcn_mfma_f32_16x16x32_bf16(af[1][0], bfr[nf][0], acc[1][nf], 0, 0, 0);
    }
    __builtin_amdgcn_s_setprio(0);
    __builtin_amdgcn_s_barrier();
    // ---------- P1 ----------
    if (wm >= 2) {
#pragma unroll
      for (int mf = 0; mf < 4; mf++)
        af[mf][1] = *(const bf16x8*)(Lb + aro + mf * 2048 + kq1);
    }
#pragma unroll
    for (int nf = 0; nf < 4; nf++)
      bfr[nf][1] = *(const bf16x8*)(Lb + bro + nf * 2048 + kq1);
    STAGE_A(buf, t2, 0);
    __builtin_amdgcn_s_barrier();
    LG0;
    __builtin_amdgcn_s_setprio(1);
#pragma unroll
    for (int nf = 0; nf < 4; nf++) {
      acc[2][nf] = __builtin_amdgcn_mfma_f32_16x16x32_bf16(af[2][0], bfr[nf][0], acc[2][nf], 0, 0, 0);
      acc[3][nf] = __builtin_amdgcn_mfma_f32_16x16x32_bf16(af[3][0], bfr[nf][0], acc[3][nf], 0, 0, 0);
    }
    __builtin_amdgcn_s_setprio(0);
    __builtin_amdgcn_s_barrier();
    // ---------- P2 ----------
    STAGE_A(buf, t2, 1);
    __builtin_amdgcn_s_barrier();
    LG0;
    __builtin_amdgcn_s_setprio(1);
#pragma unroll
    for (int nf = 0; nf < 4; nf++) {
      acc[0][nf] = __builtin_amdgcn_mfma_f32_16x16x32_bf16(af[0][1], bfr[nf][1], acc[0][nf], 0, 0, 0);
      acc[1][nf] = __builtin_amdgcn_mfma_f32_16x16x32_bf16(af[1][1], bfr[nf][1], acc[1][nf], 0, 0, 0);
    }
    __builtin_amdgcn_s_setprio(0);
    __builtin_amdgcn_s_barrier();
    // ---------- P3 ----------
    __builtin_amdgcn_s_setprio(1);
#pragma unroll
    for (int nf = 0; nf < 4; nf++) {
      acc[2][nf] = __builtin_amdgcn_mfma_f32_16x16x32_bf16(af[2][1], bfr[nf][1], acc[2][nf], 0, 0, 0);
      acc[3][nf] = __builtin_amdgcn_mfma_f32_16x16x32_bf16(af[3][1], bfr[nf][1], acc[3][nf], 0, 0, 0);
    }
    __builtin_amdgcn_s_setprio(0);
    asm volatile("s_waitcnt vmcnt(4)" ::: "memory");
    __builtin_amdgcn_s_barrier();
  }
  asm volatile("s_waitcnt vmcnt(0)" ::: "memory");

  const int r0 = l4 * 4;
#pragma unroll
  for (int mf = 0; mf < 4; mf++) {
#pragma unroll
    for (int j = 0; j < 4; j++) {
      const int m = m0 + wm * 64 + mf * 16 + r0 + j;
#pragma unroll
      for (int nf = 0; nf < 4; nf++) {
        const int n = n0 + wn * 64 + nf * 16 + l15;
        float v = acc[mf][nf][j];
        size_t idx = (size_t)m * N + n;
        if (EPI == 0) {
          Cb[idx] = f2b(v);
        } else if (EPI == 1) {
          float sg = v / (1.f + __expf(-v));
          Cb[idx] = f2b(sg);
        } else if (EPI == 2) {
          float gv = b2f(Gm[idx]);
          Gm[idx] = f2b(gv * v);
        } else {
          Cf[idx] = Res[idx] + v;
        }
      }
    }
  }
#undef STAGE_A
#undef STAGE_B
#undef LG0
}

// =====================================================================================
// flash attention v2: 512 threads (8 waves), QBLK=128 (16 q/wave), KVBLK=64.
// Double-buffered K/V staged by global_load_lds (pre-swizzled source, rule 21),
// one barrier per tile, counted-free (vmcnt drain inside syncthreads is post-overlap).
// K tile rows 256B/16 slots, XOR slot^(r&15) -> conflict-free quarter-wave reads.
// V tile rows 128B/8 slots, XOR slot^(r&7) (2-way residual, acceptable).
// Online softmax in raw score space with defer-max (T13, thr = 8/scale).
// =====================================================================================
__global__ __launch_bounds__(512, 2) void attn_k(const u16* __restrict__ qkv, const u16* __restrict__ vt,
                                                 u16* __restrict__ out) {
  __shared__ char Kl[2][16384];
  __shared__ char Vl[2][16384];
  __shared__ char Pl[8][2048];
  int tid = threadIdx.x, lane = tid & 63, w = tid >> 6;
  // XCD swizzle: grid (16,32) = 512 blocks; each XCD gets 4 whole bh.
  int bid = blockIdx.y * 16 + blockIdx.x;
  int swzb = (bid & 7) * 64 + (bid >> 3);
  int qb = swzb & 15, bh = swzb >> 4;
  int b = bh >> 4, h = bh & 15;
  const float scale = 0.088388347648318447f; // 1/sqrt(128)
  const float RT = 90.51f;                   // 8 / scale
  int l15 = lane & 15, l4 = lane >> 4;

  bf16x8 q[4];
  {
    int qrow = qb * 128 + w * 16 + l15;
    const u16* qp = qkv + (size_t)(b * SEQ + qrow) * 6144 + h * HEADD + l4 * 8;
#pragma unroll
    for (int ks = 0; ks < 4; ks++) q[ks] = *(const bf16x8*)(qp + ks * 32);
  }
  const f32x4 fz = {0.f, 0.f, 0.f, 0.f};
  f32x4 o[8];
#pragma unroll
  for (int i = 0; i < 8; i++) o[i] = fz;
  float mrow[4] = {-1e30f, -1e30f, -1e30f, -1e30f};
  float lrow[4] = {0.f, 0.f, 0.f, 0.f};
  char* Pc = &Pl[w][0];

  // staging: wave-uniform LDS dest, per-lane pre-swizzled global source
  const int krow0 = w * 8;   // K rows staged by this wave (2 instrs x 4 rows)
  const int vrow0 = w * 16;  // V rows staged by this wave (2 instrs x 8 rows)
#define STAGE(buf, t)                                                                       \
  {                                                                                         \
    int kv0_ = (t) * 64;                                                                    \
    _Pragma("unroll") for (int i = 0; i < 2; i++) {                                         \
      int r = krow0 + i * 4 + (lane >> 4);                                                  \
      int col = ((lane & 15) ^ (r & 15)) * 8;                                               \
      const u16* src = qkv + (size_t)(b * SEQ + kv0_ + r) * 6144 + HDIM + h * HEADD + col;  \
      gl_lds16(src, &Kl[buf][(krow0 + i * 4) * 256]);                                       \
    }                                                                                       \
    _Pragma("unroll") for (int i = 0; i < 2; i++) {                                         \
      int r = vrow0 + i * 8 + (lane >> 3);                                                  \
      int col = ((lane & 7) ^ (r & 7)) * 8;                                                 \
      const u16* src = vt + (size_t)(bh * HEADD + r) * SEQ + kv0_ + col;                    \
      gl_lds16(src, &Vl[buf][(vrow0 + i * 8) * 128]);                                       \
    }                                                                                       \
  }

  STAGE(0, 0);
  __syncthreads();

  for (int t = 0; t < SEQ / 64; t++) {
    int buf = t & 1;
    if (t + 1 < SEQ / 64) STAGE(buf ^ 1, t + 1);
    const char* Kb = &Kl[buf][0];
    const char* Vb = &Vl[buf][0];
    // ---- S = Q K^T (raw scores) ----
    f32x4 s[4];
#pragma unroll
    for (int kf = 0; kf < 4; kf++) {
      f32x4 accs = fz;
      int rb = (kf * 16 + l15) * 256;
#pragma unroll
      for (int ks = 0; ks < 4; ks++) {
        bf16x8 kb = *(const bf16x8*)(Kb + rb + (((ks * 4 + l4) ^ l15) << 4));
        accs = __builtin_amdgcn_mfma_f32_16x16x32_bf16(q[ks], kb, accs, 0, 0, 0);
      }
      s[kf] = accs;
    }
    // ---- online softmax with defer-max ----
    u16 pb[4][4];
#pragma unroll
    for (int j = 0; j < 4; j++) {
      float vmax = fmaxf(fmaxf(s[0][j], s[1][j]), fmaxf(s[2][j], s[3][j]));
      vmax = fmaxf(vmax, __shfl_xor(vmax, 1));
      vmax = fmaxf(vmax, __shfl_xor(vmax, 2));
      vmax = fmaxf(vmax, __shfl_xor(vmax, 4));
      vmax = fmaxf(vmax, __shfl_xor(vmax, 8));
      if (vmax > mrow[j] + RT) {
        float alpha = __expf((mrow[j] - vmax) * scale);
        mrow[j] = vmax;
        lrow[j] *= alpha;
#pragma unroll
        for (int df = 0; df < 8; df++) o[df][j] *= alpha;
      }
      float m = mrow[j];
      float rsum = 0.f;
#pragma unroll
      for (int kf = 0; kf < 4; kf++) {
        float p = __expf((s[kf][j] - m) * scale);
        pb[kf][j] = f2b(p);
        rsum += p;
      }
      rsum += __shfl_xor(rsum, 1);
      rsum += __shfl_xor(rsum, 2);
      rsum += __shfl_xor(rsum, 4);
      rsum += __shfl_xor(rsum, 8);
      lrow[j] += rsum;
    }
    // ---- P to wave-private LDS (C-layout -> A-frag re-layout) ----
#pragma unroll
    for (int j = 0; j < 4; j++) {
      int r = l4 * 4 + j;
#pragma unroll
      for (int kf = 0; kf < 4; kf++) {
        int col = kf * 16 + l15;
        *(u16*)(Pc + ((r * 128 + col * 2) ^ ((r & 7) << 4))) = pb[kf][j];
      }
    }
    // ---- O += P V ----
#pragma unroll
    for (int ks = 0; ks < 2; ks++) {
      bf16x8 pa = *(const bf16x8*)(Pc + l15 * 128 + (((ks * 4 + l4) ^ (l15 & 7)) << 4));
#pragma unroll
      for (int df = 0; df < 8; df++) {
        int r = df * 16 + l15;
        bf16x8 vb = *(const bf16x8*)(Vb + r * 128 + (((ks * 4 + l4) ^ (l15 & 7)) << 4));
        o[df] = __builtin_amdgcn_mfma_f32_16x16x32_bf16(pa, vb, o[df], 0, 0, 0);
      }
    }
    __syncthreads();
  }
#undef STAGE

  int m0 = b * SEQ + qb * 128 + w * 16;
#pragma unroll
  for (int j = 0; j < 4; j++) {
    float inv = 1.0f / lrow[j];
    int mm = m0 + l4 * 4 + j;
#pragma unroll
    for (int df = 0; df < 8; df++) {
      out[(size_t)mm * HDIM + h * HEADD + df * 16 + l15] = f2b(o[df][j] * inv);
    }
  }
}

extern "C" void kernel_launch(void* const* d_in, const int* in_sizes, int n_in,
                              void* d_out, int out_size, void* d_ws, size_t ws_size,
                              hipStream_t stream) {
  const float* hs  = (const float*)d_in[0];
  const float* wq  = (const float*)d_in[1];
  const float* wk  = (const float*)d_in[2];
  const float* wv  = (const float*)d_in[3];
  const float* wo  = (const float*)d_in[4];
  const float* wg  = (const float*)d_in[5];
  const float* wu  = (const float*)d_in[6];
  const float* wd  = (const float*)d_in[7];
  const float* ln1 = (const float*)d_in[8];
  const float* ln2 = (const float*)d_in[9];
  char* ws = (char*)d_ws;
  u16*   wqkvT = (u16*)(ws);
  u16*   woT   = (u16*)(ws + 25165824ull);
  u16*   wgT   = (u16*)(ws + 33554432ull);
  u16*   wuT   = (u16*)(ws + 67108864ull);
  u16*   wdT   = (u16*)(ws + 100663296ull);
  u16*   xb    = (u16*)(ws + 134217728ull);
  float* hid   = (float*)(ws + 150994944ull);
  u16*   qkv   = (u16*)(ws + 184549376ull);
  u16*   vtb   = (u16*)(ws + 234881024ull);
  u16*   attn  = (u16*)(ws + 251658368ull);
  u16*   g     = qkv;  // alias M x I bf16 over qkv+vt region

  wtrans_k<<<dim3(32, 32), 256, 0, stream>>>(wq, wqkvT, HDIM, HDIM, 0);
  wtrans_k<<<dim3(32, 32), 256, 0, stream>>>(wk, wqkvT, HDIM, HDIM, 2048);
  wtrans_k<<<dim3(32, 32), 256, 0, stream>>>(wv, wqkvT, HDIM, HDIM, 4096);
  wtrans_k<<<dim3(32, 32), 256, 0, stream>>>(wo, woT, HDIM, HDIM, 0);
  wtrans_k<<<dim3(128, 32), 256, 0, stream>>>(wg, wgT, HDIM, IDIM, 0);
  wtrans_k<<<dim3(128, 32), 256, 0, stream>>>(wu, wuT, HDIM, IDIM, 0);
  wtrans_k<<<dim3(32, 128), 256, 0, stream>>>(wd, wdT, IDIM, HDIM, 0);

  rmsnorm_k<<<MTOK, 256, 0, stream>>>(hs, ln1, xb);
  gemm256<0><<<dim3(48, 16), 512, 0, stream>>>(xb, wqkvT, MTOK, 6144, HDIM, qkv, nullptr, nullptr, nullptr);
  vtrans_k<<<dim3(64, 4, 32), dim3(32, 8), 0, stream>>>(qkv, vtb);
  attn_k<<<dim3(16, 32), 512, 0, stream>>>(qkv, vtb, attn);
  gemm256<3><<<dim3(16, 16), 512, 0, stream>>>(attn, woT, MTOK, HDIM, HDIM, nullptr, hid, hs, nullptr);
  rmsnorm_k<<<MTOK, 256, 0, stream>>>(hid, ln2, xb);
  gemm256<1><<<dim3(64, 16), 512, 0, stream>>>(xb, wgT, MTOK, IDIM, HDIM, g, nullptr, nullptr, nullptr);
  gemm256<2><<<dim3(64, 16), 512, 0, stream>>>(xb, wuT, MTOK, IDIM, HDIM, nullptr, nullptr, nullptr, g);
  gemm256<3><<<dim3(16, 16), 512, 0, stream>>>(g, wdT, MTOK, HDIM, IDIM, nullptr, (float*)d_out, hid, nullptr);
}

// Round 4
// 808.030 us; speedup vs baseline: 1.3561x; 1.0862x over previous
//
#include <hip/hip_runtime.h>
#include <hip/hip_bf16.h>

#define HDIM 2048
#define IDIM 8192
#define NHEADS 16
#define HEADD 128
#define BATCH 2
#define SEQ 2048
#define MTOK 4096

typedef unsigned short u16;
typedef __bf16 bf16x8 __attribute__((ext_vector_type(8)));
typedef float f32x4 __attribute__((ext_vector_type(4)));
typedef float f32x16 __attribute__((ext_vector_type(16)));
typedef unsigned short u16x8 __attribute__((ext_vector_type(8)));
typedef unsigned int u32x2 __attribute__((ext_vector_type(2)));
typedef unsigned int u32x4 __attribute__((ext_vector_type(4)));
typedef unsigned int uv2 __attribute__((ext_vector_type(2)));

__device__ __forceinline__ u16 f2b(float f) {
  unsigned u = __builtin_bit_cast(unsigned, f);
  u += 0x7FFFu + ((u >> 16) & 1u);
  return (u16)(u >> 16);
}
__device__ __forceinline__ float b2f(u16 b) {
  unsigned u = ((unsigned)b) << 16;
  return __builtin_bit_cast(float, u);
}
__device__ __forceinline__ void gl_lds16(const void* g, void* l) {
  auto gp = (const __attribute__((address_space(1))) unsigned int*)((unsigned long long)g);
  auto lp = (__attribute__((address_space(3))) unsigned int*)((unsigned)(unsigned long long)l);
  __builtin_amdgcn_global_load_lds(gp, lp, 16, 0, 0);
}
__device__ __forceinline__ unsigned cvtpk(float lo, float hi) {
  unsigned r;
  asm("v_cvt_pk_bf16_f32 %0, %1, %2" : "=v"(r) : "v"(lo), "v"(hi));
  return r;
}

// ---------------- weight transpose-convert: W (K x N fp32) -> Wt (N x K bf16) ----------------
__global__ __launch_bounds__(256) void wtrans_k(const float* __restrict__ W, u16* __restrict__ Wt,
                                                int K, int N, int rowoff) {
  __shared__ float t[64][65];
  int n0 = blockIdx.x * 64, k0 = blockIdx.y * 64;
  int tid = threadIdx.x;
  int kr = tid >> 4, nc = (tid & 15) * 4;
#pragma unroll
  for (int p = 0; p < 4; p++) {
    float4 v = *(const float4*)&W[(size_t)(k0 + p * 16 + kr) * N + n0 + nc];
    t[nc + 0][p * 16 + kr] = v.x;
    t[nc + 1][p * 16 + kr] = v.y;
    t[nc + 2][p * 16 + kr] = v.z;
    t[nc + 3][p * 16 + kr] = v.w;
  }
  __syncthreads();
  int n = tid >> 2, kq = (tid & 3) * 16;
  u16 tmp[16];
#pragma unroll
  for (int i = 0; i < 16; i++) tmp[i] = f2b(t[n][kq + i]);
  *(u16x8*)&Wt[(size_t)(rowoff + n0 + n) * K + k0 + kq] = *(u16x8*)&tmp[0];
  *(u16x8*)&Wt[(size_t)(rowoff + n0 + n) * K + k0 + kq + 8] = *(u16x8*)&tmp[8];
}

// ---------------- V transpose ----------------
__global__ __launch_bounds__(256) void vtrans_k(const u16* __restrict__ qkv, u16* __restrict__ vt) {
  __shared__ u16 t[32][33];
  int s0 = blockIdx.x * 32, d0 = blockIdx.y * 32, bh = blockIdx.z;
  int b = bh >> 4, h = bh & 15;
  int tx = threadIdx.x, ty = threadIdx.y;
#pragma unroll
  for (int i = 0; i < 4; i++)
    t[ty + i * 8][tx] = qkv[(size_t)(b * SEQ + s0 + ty + i * 8) * 6144 + 4096 + h * HEADD + d0 + tx];
  __syncthreads();
#pragma unroll
  for (int i = 0; i < 4; i++)
    vt[(size_t)(bh * HEADD + d0 + ty + i * 8) * SEQ + s0 + tx] = t[tx][ty + i * 8];
}

// ---------------- RMSNorm: fp32 in -> bf16 out ----------------
__global__ __launch_bounds__(256) void rmsnorm_k(const float* __restrict__ X, const float* __restrict__ W,
                                                 u16* __restrict__ O) {
  int row = blockIdx.x;
  int tid = threadIdx.x;
  const float* x = X + (size_t)row * HDIM;
  float4 v0 = ((const float4*)x)[tid * 2];
  float4 v1 = ((const float4*)x)[tid * 2 + 1];
  float ss = v0.x * v0.x + v0.y * v0.y + v0.z * v0.z + v0.w * v0.w
           + v1.x * v1.x + v1.y * v1.y + v1.z * v1.z + v1.w * v1.w;
#pragma unroll
  for (int off = 32; off > 0; off >>= 1) ss += __shfl_down(ss, off);
  __shared__ float red[4];
  if ((tid & 63) == 0) red[tid >> 6] = ss;
  __syncthreads();
  float rs = rsqrtf((red[0] + red[1] + red[2] + red[3]) * (1.0f / HDIM) + 1e-6f);
  const float* w = W + tid * 8;
  u16* o = O + (size_t)row * HDIM + tid * 8;
  float vals[8] = {v0.x, v0.y, v0.z, v0.w, v1.x, v1.y, v1.z, v1.w};
#pragma unroll
  for (int j = 0; j < 8; j++) o[j] = f2b(w[j] * vals[j] * rs);
}

// =====================================================================================
// 8-phase GEMM (unchanged): C(MxN) = A(MxK bf16) * Bt(NxK bf16)^T.  BM=256 BN=128 BK=64.
// =====================================================================================
template <int EPI>
__global__ __launch_bounds__(512, 2) void gemm256(const u16* __restrict__ A, const u16* __restrict__ Bt,
                                                  int M, int N, int K,
                                                  u16* __restrict__ Cb, float* __restrict__ Cf,
                                                  const float* __restrict__ Res, u16* __restrict__ Gm) {
  __shared__ char lds[98304];
  const int tid = threadIdx.x;
  const int lane = tid & 63, w = tid >> 6;
  const int wm = w >> 1, wn = w & 1;
  const int nwg = gridDim.x * gridDim.y;
  const int bid = blockIdx.y * gridDim.x + blockIdx.x;
  const int swz = (bid & 7) * (nwg >> 3) + (bid >> 3);
  const int bx = swz % gridDim.x, by = swz / gridDim.x;
  const int n0 = bx * 128, m0 = by * 256;
  const int NT = K >> 6;

  const int r8 = lane >> 3, s8 = lane & 7;
  const int slog8 = (s8 ^ r8) * 8;
  const u16* Abase = A + (size_t)(m0 + w * 8 + r8) * K + slog8;
  const u16* Bbase = Bt + (size_t)(n0 + w * 8 + r8) * K + slog8;
  const int stA = w * 1024;

#define STAGE_A(buf, kt, h)                                                        \
  {                                                                                \
    const u16* s_ = Abase + (size_t)(h) * 128 * K + (size_t)(kt) * 64;             \
    gl_lds16(s_, lds + (buf) * 49152 + (h) * 16384 + stA);                         \
    gl_lds16(s_ + 64 * (size_t)K, lds + (buf) * 49152 + (h) * 16384 + stA + 8192); \
  }
#define STAGE_B(buf, kt)                                                     \
  {                                                                          \
    const u16* s_ = Bbase + (size_t)(kt) * 64;                               \
    gl_lds16(s_, lds + (buf) * 49152 + 32768 + stA);                         \
    gl_lds16(s_ + 64 * (size_t)K, lds + (buf) * 49152 + 32768 + stA + 8192); \
  }
#define LG0 { asm volatile("s_waitcnt lgkmcnt(0)" ::: "memory"); __builtin_amdgcn_sched_barrier(0); }

  const int l15 = lane & 15, l4 = lane >> 4;
  const int kq0 = (l4 * 16) ^ ((lane & 7) << 4);
  const int kq1 = (64 + l4 * 16) ^ ((lane & 7) << 4);
  const int aro = (wm >> 1) * 16384 + ((wm & 1) * 64 + l15) * 128;
  const int bro = 32768 + (wn * 64 + l15) * 128;

  const f32x4 fz = {0.f, 0.f, 0.f, 0.f};
  f32x4 acc[4][4];
#pragma unroll
  for (int i = 0; i < 4; i++)
#pragma unroll
    for (int j = 0; j < 4; j++) acc[i][j] = fz;
  bf16x8 af[4][2], bfr[4][2];

  STAGE_A(0, 0, 0);
  STAGE_A(0, 0, 1);
  STAGE_B(0, 0);
  STAGE_A(1, 1, 0);
  STAGE_A(1, 1, 1);
  asm volatile("s_waitcnt vmcnt(4)" ::: "memory");
  __builtin_amdgcn_s_barrier();

  for (int t = 0; t < NT; ++t) {
    const int buf = t & 1;
    const char* Lb = lds + buf * 49152;
    const int t1 = (t + 1 < NT) ? t + 1 : NT - 1;
    const int t2 = (t + 2 < NT) ? t + 2 : NT - 1;
    // ---------- P0 ----------
    if (wm < 2) {
#pragma unroll
      for (int mf = 0; mf < 4; mf++) {
        af[mf][0] = *(const bf16x8*)(Lb + aro + mf * 2048 + kq0);
        af[mf][1] = *(const bf16x8*)(Lb + aro + mf * 2048 + kq1);
      }
    } else {
#pragma unroll
      for (int mf = 0; mf < 4; mf++)
        af[mf][0] = *(const bf16x8*)(Lb + aro + mf * 2048 + kq0);
    }
#pragma unroll
    for (int nf = 0; nf < 4; nf++)
      bfr[nf][0] = *(const bf16x8*)(Lb + bro + nf * 2048 + kq0);
    STAGE_B((t + 1) & 1, t1);
    __builtin_amdgcn_s_barrier();
    LG0;
    __builtin_amdgcn_s_setprio(1);
#pragma unroll
    for (int nf = 0; nf < 4; nf++) {
      acc[0][nf] = __builtin_amdgcn_mfma_f32_16x16x32_bf16(af[0][0], bfr[nf][0], acc[0][nf], 0, 0, 0);
      acc[1][nf] = __builtin_amdgcn_mfma_f32_16x16x32_bf16(af[1][0], bfr[nf][0], acc[1][nf], 0, 0, 0);
    }
    __builtin_amdgcn_s_setprio(0);
    __builtin_amdgcn_s_barrier();
    // ---------- P1 ----------
    if (wm >= 2) {
#pragma unroll
      for (int mf = 0; mf < 4; mf++)
        af[mf][1] = *(const bf16x8*)(Lb + aro + mf * 2048 + kq1);
    }
#pragma unroll
    for (int nf = 0; nf < 4; nf++)
      bfr[nf][1] = *(const bf16x8*)(Lb + bro + nf * 2048 + kq1);
    STAGE_A(buf, t2, 0);
    __builtin_amdgcn_s_barrier();
    LG0;
    __builtin_amdgcn_s_setprio(1);
#pragma unroll
    for (int nf = 0; nf < 4; nf++) {
      acc[2][nf] = __builtin_amdgcn_mfma_f32_16x16x32_bf16(af[2][0], bfr[nf][0], acc[2][nf], 0, 0, 0);
      acc[3][nf] = __builtin_amdgcn_mfma_f32_16x16x32_bf16(af[3][0], bfr[nf][0], acc[3][nf], 0, 0, 0);
    }
    __builtin_amdgcn_s_setprio(0);
    __builtin_amdgcn_s_barrier();
    // ---------- P2 ----------
    STAGE_A(buf, t2, 1);
    __builtin_amdgcn_s_barrier();
    LG0;
    __builtin_amdgcn_s_setprio(1);
#pragma unroll
    for (int nf = 0; nf < 4; nf++) {
      acc[0][nf] = __builtin_amdgcn_mfma_f32_16x16x32_bf16(af[0][1], bfr[nf][1], acc[0][nf], 0, 0, 0);
      acc[1][nf] = __builtin_amdgcn_mfma_f32_16x16x32_bf16(af[1][1], bfr[nf][1], acc[1][nf], 0, 0, 0);
    }
    __builtin_amdgcn_s_setprio(0);
    __builtin_amdgcn_s_barrier();
    // ---------- P3 ----------
    __builtin_amdgcn_s_setprio(1);
#pragma unroll
    for (int nf = 0; nf < 4; nf++) {
      acc[2][nf] = __builtin_amdgcn_mfma_f32_16x16x32_bf16(af[2][1], bfr[nf][1], acc[2][nf], 0, 0, 0);
      acc[3][nf] = __builtin_amdgcn_mfma_f32_16x16x32_bf16(af[3][1], bfr[nf][1], acc[3][nf], 0, 0, 0);
    }
    __builtin_amdgcn_s_setprio(0);
    asm volatile("s_waitcnt vmcnt(4)" ::: "memory");
    __builtin_amdgcn_s_barrier();
  }
  asm volatile("s_waitcnt vmcnt(0)" ::: "memory");

  const int r0 = l4 * 4;
#pragma unroll
  for (int mf = 0; mf < 4; mf++) {
#pragma unroll
    for (int j = 0; j < 4; j++) {
      const int m = m0 + wm * 64 + mf * 16 + r0 + j;
#pragma unroll
      for (int nf = 0; nf < 4; nf++) {
        const int n = n0 + wn * 64 + nf * 16 + l15;
        float v = acc[mf][nf][j];
        size_t idx = (size_t)m * N + n;
        if (EPI == 0) {
          Cb[idx] = f2b(v);
        } else if (EPI == 1) {
          float sg = v / (1.f + __expf(-v));
          Cb[idx] = f2b(sg);
        } else if (EPI == 2) {
          float gv = b2f(Gm[idx]);
          Gm[idx] = f2b(gv * v);
        } else {
          Cf[idx] = Res[idx] + v;
        }
      }
    }
  }
#undef STAGE_A
#undef STAGE_B
#undef LG0
}

// =====================================================================================
// flash attention v3: swapped-operand 32x32x16 MFMA, in-register softmax (T12).
// 512 threads = 8 warps; warp owns 32 q-rows; block = 256 q of one (b,h). KVBLK=64.
// S^T = mfma(K,Q): lane holds q-col = lane&31, 32 kv scores in 2 f32x16 accs.
//   kv(reg) = (r&3) + 8*(r>>2) + 4*(lane>>5)  [+32*tile]
// Row max/sum: in-lane tree + one permlane32_swap (no ds_bpermute chains).
// P re-layout to B-frag fully in-register: 16 cvt_pk + 8 permlane32_swap per tile.
// O^T = mfma(V^T_frag, P_frag): lane q = lane&31 matches softmax state; rescale in-lane.
// K LDS [64][256B] swizzled slot^(r&15); V^T LDS [128][128B] swizzled slot^(d&7);
// staged via global_load_lds w=16, pre-swizzled global source (rule 21), dbuf.
// =====================================================================================
__global__ __launch_bounds__(512, 2) void attn_k(const u16* __restrict__ qkv, const u16* __restrict__ vt,
                                                 u16* __restrict__ out) {
  __shared__ char Kl[2][16384];
  __shared__ char Vl[2][16384];
  int tid = threadIdx.x, lane = tid & 63, w = tid >> 6;
  // grid (8 qb, 32 bh); XCD swizzle: each XCD gets 4 whole bh (4MB KV = its L2)
  int bid = blockIdx.y * 8 + blockIdx.x;
  int swz = (bid & 7) * 32 + (bid >> 3);
  int qb = swz & 7, bh = swz >> 3;
  int b = bh >> 4, h = bh & 15;
  int l31 = lane & 31, hi = lane >> 5;
  const float c = 0.088388347648318447f * 1.4426950408889634f;  // scale * log2(e)
  const float RT = 90.51f;                                      // 8 / scale (raw units)

  // Q B-frag: q[dt] = Q[qrow][dt*16 + hi*8 .. +7]
  const int qrow = qb * 256 + w * 32 + l31;
  bf16x8 q[8];
  {
    const u16* qp = qkv + (size_t)(b * SEQ + qrow) * 6144 + h * HEADD + hi * 8;
#pragma unroll
    for (int dt = 0; dt < 8; dt++) q[dt] = *(const bf16x8*)(qp + dt * 16);
  }
  f32x16 o[4];
#pragma unroll
  for (int i = 0; i < 4; i++)
#pragma unroll
    for (int j = 0; j < 16; j++) o[i][j] = 0.f;
  float mrow = -1e30f, lrow = 0.f;

  // staging: wave-uniform LDS dest + per-lane pre-swizzled global source
#define ASTAGE(buf, t)                                                                     \
  {                                                                                        \
    int kv0_ = (t) * 64;                                                                   \
    _Pragma("unroll") for (int i = 0; i < 2; i++) {                                        \
      int r = w * 8 + i * 4 + (lane >> 4);                                                 \
      int col = ((lane & 15) ^ (r & 15)) * 8;                                              \
      const u16* src = qkv + (size_t)(b * SEQ + kv0_ + r) * 6144 + HDIM + h * HEADD + col; \
      gl_lds16(src, &Kl[buf][(w * 8 + i * 4) * 256]);                                      \
    }                                                                                      \
    _Pragma("unroll") for (int i = 0; i < 2; i++) {                                        \
      int d = w * 16 + i * 8 + (lane >> 3);                                                \
      int col = ((lane & 7) ^ (d & 7)) * 8;                                                \
      const u16* src = vt + (size_t)(bh * HEADD + d) * SEQ + kv0_ + col;                   \
      gl_lds16(src, &Vl[buf][(w * 16 + i * 8) * 128]);                                     \
    }                                                                                      \
  }

  ASTAGE(0, 0);
  __syncthreads();

  for (int t = 0; t < SEQ / 64; t++) {
    const int buf = t & 1;
    if (t + 1 < SEQ / 64) ASTAGE(buf ^ 1, t + 1);
    const char* Kb = &Kl[buf][0];
    const char* Vb = &Vl[buf][0];
    // ---- S^T = mfma(K, Q): 2 kv-tiles of 32 ----
    f32x16 s0, s1;
#pragma unroll
    for (int j = 0; j < 16; j++) { s0[j] = 0.f; s1[j] = 0.f; }
    const int ksl = l31 & 15;
    __builtin_amdgcn_s_setprio(1);
#pragma unroll
    for (int dt = 0; dt < 8; dt++) {
      bf16x8 k0 = *(const bf16x8*)(Kb + (l31)*256 + (((dt * 2 + hi) ^ ksl) << 4));
      bf16x8 k1 = *(const bf16x8*)(Kb + (32 + l31) * 256 + (((dt * 2 + hi) ^ ksl) << 4));
      s0 = __builtin_amdgcn_mfma_f32_32x32x16_bf16(k0, q[dt], s0, 0, 0, 0);
      s1 = __builtin_amdgcn_mfma_f32_32x32x16_bf16(k1, q[dt], s1, 0, 0, 0);
    }
    __builtin_amdgcn_s_setprio(0);
    // ---- in-register online softmax ----
    float m8[8];
#pragma unroll
    for (int g = 0; g < 4; g++) {
      m8[g] = fmaxf(fmaxf(s0[4 * g], s0[4 * g + 1]), fmaxf(s0[4 * g + 2], s0[4 * g + 3]));
      m8[4 + g] = fmaxf(fmaxf(s1[4 * g], s1[4 * g + 1]), fmaxf(s1[4 * g + 2], s1[4 * g + 3]));
    }
    float vmax = fmaxf(fmaxf(fmaxf(m8[0], m8[1]), fmaxf(m8[2], m8[3])),
                       fmaxf(fmaxf(m8[4], m8[5]), fmaxf(m8[6], m8[7])));
    {
      uv2 pr = __builtin_amdgcn_permlane32_swap(__builtin_bit_cast(unsigned, vmax),
                                                __builtin_bit_cast(unsigned, vmax), false, false);
      vmax = fmaxf(__builtin_bit_cast(float, pr[0]), __builtin_bit_cast(float, pr[1]));
    }
    if (__any(vmax > mrow + RT)) {
      float mnew = fmaxf(mrow, vmax);
      float alpha = exp2f((mrow - mnew) * c);
      mrow = mnew;
      lrow *= alpha;
#pragma unroll
      for (int i = 0; i < 4; i++)
#pragma unroll
        for (int j = 0; j < 16; j++) o[i][j] *= alpha;
    }
    const float mc = mrow * c;
    float r4[4] = {0.f, 0.f, 0.f, 0.f};
#pragma unroll
    for (int j = 0; j < 16; j++) {
      s0[j] = exp2f(s0[j] * c - mc);
      r4[j & 3] += s0[j];
    }
#pragma unroll
    for (int j = 0; j < 16; j++) {
      s1[j] = exp2f(s1[j] * c - mc);
      r4[j & 3] += s1[j];
    }
    float rsum = (r4[0] + r4[1]) + (r4[2] + r4[3]);
    {
      uv2 pr = __builtin_amdgcn_permlane32_swap(__builtin_bit_cast(unsigned, rsum),
                                                __builtin_bit_cast(unsigned, rsum), false, false);
      rsum = __builtin_bit_cast(float, pr[0]) + __builtin_bit_cast(float, pr[1]);
    }
    lrow += rsum;
    // ---- P -> bf16 B-frags (T12: cvt_pk + permlane32_swap), 4 frags of k=16 ----
    bf16x8 pa[4];
#pragma unroll
    for (int half = 0; half < 2; half++) {
      const f32x16& sv = half ? s1 : s0;
#pragma unroll
      for (int blk = 0; blk < 2; blk++) {
        int base = blk * 8;
        unsigned A = cvtpk(sv[base + 0], sv[base + 1]);
        unsigned B = cvtpk(sv[base + 2], sv[base + 3]);
        unsigned C = cvtpk(sv[base + 4], sv[base + 5]);
        unsigned D = cvtpk(sv[base + 6], sv[base + 7]);
        uv2 ac = __builtin_amdgcn_permlane32_swap(A, C, false, false);
        uv2 bd = __builtin_amdgcn_permlane32_swap(B, D, false, false);
        u32x4 w4;
        w4[0] = ac[0]; w4[1] = bd[0]; w4[2] = ac[1]; w4[3] = bd[1];
        pa[half * 2 + blk] = __builtin_bit_cast(bf16x8, w4);
      }
    }
    // ---- O^T += mfma(V^T, P) ----
    __builtin_amdgcn_s_setprio(1);
#pragma unroll
    for (int dt4 = 0; dt4 < 4; dt4++) {
      const char* vbase = Vb + (dt4 * 32 + l31) * 128;
      const int vsl = l31 & 7;
#pragma unroll
      for (int ks = 0; ks < 4; ks++) {
        bf16x8 vb = *(const bf16x8*)(vbase + (((ks * 2 + hi) ^ vsl) << 4));
        o[dt4] = __builtin_amdgcn_mfma_f32_32x32x16_bf16(vb, pa[ks], o[dt4], 0, 0, 0);
      }
    }
    __builtin_amdgcn_s_setprio(0);
    __syncthreads();
  }
#undef ASTAGE

  // ---- epilogue: lane q = l31; d = dt4*32 + 8g + 4hi + {0..3} ----
  const float linv = 1.0f / lrow;
  u16* orow = out + (size_t)(b * SEQ + qrow) * HDIM + h * HEADD;
#pragma unroll
  for (int dt4 = 0; dt4 < 4; dt4++) {
#pragma unroll
    for (int g = 0; g < 4; g++) {
      u32x2 st;
      st[0] = cvtpk(o[dt4][4 * g + 0] * linv, o[dt4][4 * g + 1] * linv);
      st[1] = cvtpk(o[dt4][4 * g + 2] * linv, o[dt4][4 * g + 3] * linv);
      *(u32x2*)(orow + dt4 * 32 + 8 * g + 4 * hi) = st;
    }
  }
}

extern "C" void kernel_launch(void* const* d_in, const int* in_sizes, int n_in,
                              void* d_out, int out_size, void* d_ws, size_t ws_size,
                              hipStream_t stream) {
  const float* hs  = (const float*)d_in[0];
  const float* wq  = (const float*)d_in[1];
  const float* wk  = (const float*)d_in[2];
  const float* wv  = (const float*)d_in[3];
  const float* wo  = (const float*)d_in[4];
  const float* wg  = (const float*)d_in[5];
  const float* wu  = (const float*)d_in[6];
  const float* wd  = (const float*)d_in[7];
  const float* ln1 = (const float*)d_in[8];
  const float* ln2 = (const float*)d_in[9];
  char* ws = (char*)d_ws;
  u16*   wqkvT = (u16*)(ws);
  u16*   woT   = (u16*)(ws + 25165824ull);
  u16*   wgT   = (u16*)(ws + 33554432ull);
  u16*   wuT   = (u16*)(ws + 67108864ull);
  u16*   wdT   = (u16*)(ws + 100663296ull);
  u16*   xb    = (u16*)(ws + 134217728ull);
  float* hid   = (float*)(ws + 150994944ull);
  u16*   qkv   = (u16*)(ws + 184549376ull);
  u16*   vtb   = (u16*)(ws + 234881024ull);
  u16*   attn  = (u16*)(ws + 251658368ull);
  u16*   g     = qkv;  // alias M x I bf16 over qkv+vt region

  wtrans_k<<<dim3(32, 32), 256, 0, stream>>>(wq, wqkvT, HDIM, HDIM, 0);
  wtrans_k<<<dim3(32, 32), 256, 0, stream>>>(wk, wqkvT, HDIM, HDIM, 2048);
  wtrans_k<<<dim3(32, 32), 256, 0, stream>>>(wv, wqkvT, HDIM, HDIM, 4096);
  wtrans_k<<<dim3(32, 32), 256, 0, stream>>>(wo, woT, HDIM, HDIM, 0);
  wtrans_k<<<dim3(128, 32), 256, 0, stream>>>(wg, wgT, HDIM, IDIM, 0);
  wtrans_k<<<dim3(128, 32), 256, 0, stream>>>(wu, wuT, HDIM, IDIM, 0);
  wtrans_k<<<dim3(32, 128), 256, 0, stream>>>(wd, wdT, IDIM, HDIM, 0);

  rmsnorm_k<<<MTOK, 256, 0, stream>>>(hs, ln1, xb);
  gemm256<0><<<dim3(48, 16), 512, 0, stream>>>(xb, wqkvT, MTOK, 6144, HDIM, qkv, nullptr, nullptr, nullptr);
  vtrans_k<<<dim3(64, 4, 32), dim3(32, 8), 0, stream>>>(qkv, vtb);
  attn_k<<<dim3(8, 32), 512, 0, stream>>>(qkv, vtb, attn);
  gemm256<3><<<dim3(16, 16), 512, 0, stream>>>(attn, woT, MTOK, HDIM, HDIM, nullptr, hid, hs, nullptr);
  rmsnorm_k<<<MTOK, 256, 0, stream>>>(hid, ln2, xb);
  gemm256<1><<<dim3(64, 16), 512, 0, stream>>>(xb, wgT, MTOK, IDIM, HDIM, g, nullptr, nullptr, nullptr);
  gemm256<2><<<dim3(64, 16), 512, 0, stream>>>(xb, wuT, MTOK, IDIM, HDIM, nullptr, nullptr, nullptr, g);
  gemm256<3><<<dim3(16, 16), 512, 0, stream>>>(g, wdT, MTOK, HDIM, IDIM, nullptr, (float*)d_out, hid, nullptr);
}

// Round 5
// 773.425 us; speedup vs baseline: 1.4168x; 1.0447x over previous
//
#include <hip/hip_runtime.h>
#include <hip/hip_bf16.h>

#define HDIM 2048
#define IDIM 8192
#define NHEADS 16
#define HEADD 128
#define BATCH 2
#define SEQ 2048
#define MTOK 4096

typedef unsigned short u16;
typedef __bf16 bf16x8 __attribute__((ext_vector_type(8)));
typedef float f32x4 __attribute__((ext_vector_type(4)));
typedef float f32x16 __attribute__((ext_vector_type(16)));
typedef unsigned short u16x8 __attribute__((ext_vector_type(8)));
typedef unsigned int u32x2 __attribute__((ext_vector_type(2)));
typedef unsigned int u32x4 __attribute__((ext_vector_type(4)));
typedef unsigned int uv2 __attribute__((ext_vector_type(2)));

__device__ __forceinline__ u16 f2b(float f) {
  unsigned u = __builtin_bit_cast(unsigned, f);
  u += 0x7FFFu + ((u >> 16) & 1u);
  return (u16)(u >> 16);
}
__device__ __forceinline__ float b2f(u16 b) {
  unsigned u = ((unsigned)b) << 16;
  return __builtin_bit_cast(float, u);
}
__device__ __forceinline__ void gl_lds16(const void* g, void* l) {
  auto gp = (const __attribute__((address_space(1))) unsigned int*)((unsigned long long)g);
  auto lp = (__attribute__((address_space(3))) unsigned int*)((unsigned)(unsigned long long)l);
  __builtin_amdgcn_global_load_lds(gp, lp, 16, 0, 0);
}
__device__ __forceinline__ unsigned cvtpk(float lo, float hi) {
  unsigned r;
  asm("v_cvt_pk_bf16_f32 %0, %1, %2" : "=v"(r) : "v"(lo), "v"(hi));
  return r;
}

// ---------------- weight transpose-convert: W (K x N fp32) -> Wt (N x K bf16) ----------------
__global__ __launch_bounds__(256) void wtrans_k(const float* __restrict__ W, u16* __restrict__ Wt,
                                                int K, int N, int rowoff) {
  __shared__ float t[64][65];
  int n0 = blockIdx.x * 64, k0 = blockIdx.y * 64;
  int tid = threadIdx.x;
  int kr = tid >> 4, nc = (tid & 15) * 4;
#pragma unroll
  for (int p = 0; p < 4; p++) {
    float4 v = *(const float4*)&W[(size_t)(k0 + p * 16 + kr) * N + n0 + nc];
    t[nc + 0][p * 16 + kr] = v.x;
    t[nc + 1][p * 16 + kr] = v.y;
    t[nc + 2][p * 16 + kr] = v.z;
    t[nc + 3][p * 16 + kr] = v.w;
  }
  __syncthreads();
  int n = tid >> 2, kq = (tid & 3) * 16;
  u16 tmp[16];
#pragma unroll
  for (int i = 0; i < 16; i++) tmp[i] = f2b(t[n][kq + i]);
  *(u16x8*)&Wt[(size_t)(rowoff + n0 + n) * K + k0 + kq] = *(u16x8*)&tmp[0];
  *(u16x8*)&Wt[(size_t)(rowoff + n0 + n) * K + k0 + kq + 8] = *(u16x8*)&tmp[8];
}

// ---------------- V transpose ----------------
__global__ __launch_bounds__(256) void vtrans_k(const u16* __restrict__ qkv, u16* __restrict__ vt) {
  __shared__ u16 t[32][33];
  int s0 = blockIdx.x * 32, d0 = blockIdx.y * 32, bh = blockIdx.z;
  int b = bh >> 4, h = bh & 15;
  int tx = threadIdx.x, ty = threadIdx.y;
#pragma unroll
  for (int i = 0; i < 4; i++)
    t[ty + i * 8][tx] = qkv[(size_t)(b * SEQ + s0 + ty + i * 8) * 6144 + 4096 + h * HEADD + d0 + tx];
  __syncthreads();
#pragma unroll
  for (int i = 0; i < 4; i++)
    vt[(size_t)(bh * HEADD + d0 + ty + i * 8) * SEQ + s0 + tx] = t[tx][ty + i * 8];
}

// ---------------- RMSNorm: fp32 in -> bf16 out ----------------
__global__ __launch_bounds__(256) void rmsnorm_k(const float* __restrict__ X, const float* __restrict__ W,
                                                 u16* __restrict__ O) {
  int row = blockIdx.x;
  int tid = threadIdx.x;
  const float* x = X + (size_t)row * HDIM;
  float4 v0 = ((const float4*)x)[tid * 2];
  float4 v1 = ((const float4*)x)[tid * 2 + 1];
  float ss = v0.x * v0.x + v0.y * v0.y + v0.z * v0.z + v0.w * v0.w
           + v1.x * v1.x + v1.y * v1.y + v1.z * v1.z + v1.w * v1.w;
#pragma unroll
  for (int off = 32; off > 0; off >>= 1) ss += __shfl_down(ss, off);
  __shared__ float red[4];
  if ((tid & 63) == 0) red[tid >> 6] = ss;
  __syncthreads();
  float rs = rsqrtf((red[0] + red[1] + red[2] + red[3]) * (1.0f / HDIM) + 1e-6f);
  const float* w = W + tid * 8;
  u16* o = O + (size_t)row * HDIM + tid * 8;
  float vals[8] = {v0.x, v0.y, v0.z, v0.w, v1.x, v1.y, v1.z, v1.w};
#pragma unroll
  for (int j = 0; j < 8; j++) o[j] = f2b(w[j] * vals[j] * rs);
}

// =====================================================================================
// gemm_w: 256x256 tile, BK=64, 512 thr = 8 waves (2M x 4N), per-wave 128x64.
// LDS 128KB: 2 buf x {A0,A1,B0,B1} 16KB half-tiles, rows 128B, slot^(row&7) swizzle.
// Phases per K-tile: P0(mh0,kh0, 8 rd, stage A1B1(t+1)), P1(mh1,kh0, 4 rd),
// P2(mh0,kh1, 8 rd), P3(mh1,kh1, 4 rd, stage A0B0(t+2), vmcnt(4)).
// Region-death proofs: A1/B1(buf^1) dead after t-1.P3/P2 barriers; A0/B0(buf) dead
// after t.P2 barrier. vmcnt(4) at P3 == all of tile t+1 landed before t+1.P0.
// Supertile swizzle: 16-block (4by x 4bx) supertiles round-robined over 8 XCDs
// (requires nst = (gy/4)*(gx/4) % 8 == 0: QKV 24, gate/up 32).
// EPI: 0 store bf16; 1 bf16(silu); 2 Gm *= v; 3 Cf = Res + v.
// =====================================================================================
template <int EPI>
__global__ __launch_bounds__(512, 2) void gemm_w(const u16* __restrict__ A, const u16* __restrict__ Bt,
                                                 int M, int N, int K,
                                                 u16* __restrict__ Cb, float* __restrict__ Cf,
                                                 const float* __restrict__ Res, u16* __restrict__ Gm) {
  __shared__ char lds[131072];
  const int tid = threadIdx.x;
  const int lane = tid & 63, w = tid >> 6;
  const int wm = w >> 2, wn = w & 3;
  // supertile XCD swizzle
  const int bid = blockIdx.y * gridDim.x + blockIdx.x;
  const int xcd = bid & 7, idx = bid >> 3;
  const int round = idx >> 4, j = idx & 15;
  const int nsy4 = gridDim.y >> 2;
  const int st = round * 8 + xcd;
  const int sx = st / nsy4, syi = st % nsy4;
  const int by = syi * 4 + (j & 3), bx = sx * 4 + (j >> 2);
  const int m0 = by * 256, n0 = bx * 256;
  const int NT = K >> 6;

  // staging source (pre-swizzled k so linear LDS dest + swizzled read is correct)
  const int srow = w * 8 + (lane >> 3);             // 0..63 within a 64-row issue
  const int kko = ((lane & 7) ^ (lane >> 3)) * 8;   // element offset within BK chunk
  const u16* Asrc = A + (size_t)(m0 + srow) * K + kko;
  const u16* Bsrc = Bt + (size_t)(n0 + srow) * K + kko;
  const int wofs = w * 1024;

#define STAGE_AH(buf, kt, h)                                                          \
  {                                                                                   \
    gl_lds16(Asrc + ((size_t)((h) * 128) * K) + (size_t)(kt) * 64,                    \
             lds + (buf) * 65536 + (h) * 16384 + wofs);                               \
    gl_lds16(Asrc + ((size_t)((h) * 128 + 64) * K) + (size_t)(kt) * 64,               \
             lds + (buf) * 65536 + (h) * 16384 + 8192 + wofs);                        \
  }
#define STAGE_BH(buf, kt, h)                                                          \
  {                                                                                   \
    gl_lds16(Bsrc + ((size_t)((h) * 128) * K) + (size_t)(kt) * 64,                    \
             lds + (buf) * 65536 + 32768 + (h) * 16384 + wofs);                       \
    gl_lds16(Bsrc + ((size_t)((h) * 128 + 64) * K) + (size_t)(kt) * 64,               \
             lds + (buf) * 65536 + 32768 + (h) * 16384 + 8192 + wofs);                \
  }
#define LG0 { asm volatile("s_waitcnt lgkmcnt(0)" ::: "memory"); __builtin_amdgcn_sched_barrier(0); }

  const int l15 = lane & 15, l4 = lane >> 4;
  const int kq0 = ((l4) ^ (l15 & 7)) << 4;        // kh0 slot
  const int kq1 = ((4 + l4) ^ (l15 & 7)) << 4;    // kh1 slot
  const int abase = wm * 16384 + l15 * 128;
  const int bbase = 32768 + (wn >> 1) * 16384 + ((wn & 1) * 64 + l15) * 128;

  const f32x4 fz = {0.f, 0.f, 0.f, 0.f};
  f32x4 acc[8][4];
#pragma unroll
  for (int i = 0; i < 8; i++)
#pragma unroll
    for (int jj = 0; jj < 4; jj++) acc[i][jj] = fz;
  bf16x8 af[4], bfr[4];

  // prologue: tile0 full + A0,B0 of tile1
  STAGE_AH(0, 0, 0);
  STAGE_AH(0, 0, 1);
  STAGE_BH(0, 0, 0);
  STAGE_BH(0, 0, 1);
  STAGE_AH(1, 1, 0);
  STAGE_BH(1, 1, 0);
  asm volatile("s_waitcnt vmcnt(4)" ::: "memory");
  __builtin_amdgcn_s_barrier();

  for (int t = 0; t < NT; ++t) {
    const int buf = t & 1, nbuf = buf ^ 1;
    const char* Lb = lds + buf * 65536;
    const int t1 = (t + 1 < NT) ? t + 1 : NT - 1;
    const int t2 = (t + 2 < NT) ? t + 2 : NT - 1;
    // ---------- P0: mh0, kh0 ----------
#pragma unroll
    for (int mf = 0; mf < 4; mf++) af[mf] = *(const bf16x8*)(Lb + abase + mf * 2048 + kq0);
#pragma unroll
    for (int nf = 0; nf < 4; nf++) bfr[nf] = *(const bf16x8*)(Lb + bbase + nf * 2048 + kq0);
    STAGE_AH(nbuf, t1, 1);
    STAGE_BH(nbuf, t1, 1);
    __builtin_amdgcn_s_barrier();
    LG0;
    __builtin_amdgcn_s_setprio(1);
#pragma unroll
    for (int mf = 0; mf < 4; mf++)
#pragma unroll
      for (int nf = 0; nf < 4; nf++)
        acc[mf][nf] = __builtin_amdgcn_mfma_f32_16x16x32_bf16(af[mf], bfr[nf], acc[mf][nf], 0, 0, 0);
    __builtin_amdgcn_s_setprio(0);
    __builtin_amdgcn_s_barrier();
    // ---------- P1: mh1, kh0 ----------
#pragma unroll
    for (int mf = 0; mf < 4; mf++) af[mf] = *(const bf16x8*)(Lb + abase + (mf + 4) * 2048 + kq0);
    __builtin_amdgcn_s_barrier();
    LG0;
    __builtin_amdgcn_s_setprio(1);
#pragma unroll
    for (int mf = 0; mf < 4; mf++)
#pragma unroll
      for (int nf = 0; nf < 4; nf++)
        acc[mf + 4][nf] = __builtin_amdgcn_mfma_f32_16x16x32_bf16(af[mf], bfr[nf], acc[mf + 4][nf], 0, 0, 0);
    __builtin_amdgcn_s_setprio(0);
    __builtin_amdgcn_s_barrier();
    // ---------- P2: mh0, kh1 ----------
#pragma unroll
    for (int mf = 0; mf < 4; mf++) af[mf] = *(const bf16x8*)(Lb + abase + mf * 2048 + kq1);
#pragma unroll
    for (int nf = 0; nf < 4; nf++) bfr[nf] = *(const bf16x8*)(Lb + bbase + nf * 2048 + kq1);
    __builtin_amdgcn_s_barrier();
    LG0;
    __builtin_amdgcn_s_setprio(1);
#pragma unroll
    for (int mf = 0; mf < 4; mf++)
#pragma unroll
      for (int nf = 0; nf < 4; nf++)
        acc[mf][nf] = __builtin_amdgcn_mfma_f32_16x16x32_bf16(af[mf], bfr[nf], acc[mf][nf], 0, 0, 0);
    __builtin_amdgcn_s_setprio(0);
    __builtin_amdgcn_s_barrier();
    // ---------- P3: mh1, kh1 ----------
#pragma unroll
    for (int mf = 0; mf < 4; mf++) af[mf] = *(const bf16x8*)(Lb + abase + (mf + 4) * 2048 + kq1);
    STAGE_AH(buf, t2, 0);
    STAGE_BH(buf, t2, 0);
    __builtin_amdgcn_s_barrier();
    LG0;
    __builtin_amdgcn_s_setprio(1);
#pragma unroll
    for (int mf = 0; mf < 4; mf++)
#pragma unroll
      for (int nf = 0; nf < 4; nf++)
        acc[mf + 4][nf] = __builtin_amdgcn_mfma_f32_16x16x32_bf16(af[mf], bfr[nf], acc[mf + 4][nf], 0, 0, 0);
    __builtin_amdgcn_s_setprio(0);
    asm volatile("s_waitcnt vmcnt(4)" ::: "memory");
    __builtin_amdgcn_s_barrier();
  }
  asm volatile("s_waitcnt vmcnt(0)" ::: "memory");

  // ---------- epilogue ----------
  const int r0 = l4 * 4;
#pragma unroll
  for (int mf = 0; mf < 8; mf++) {
#pragma unroll
    for (int jr = 0; jr < 4; jr++) {
      const int m = m0 + wm * 128 + mf * 16 + r0 + jr;
#pragma unroll
      for (int nf = 0; nf < 4; nf++) {
        const int n = n0 + wn * 64 + nf * 16 + l15;
        float v = acc[mf][nf][jr];
        size_t idx = (size_t)m * N + n;
        if (EPI == 0) {
          Cb[idx] = f2b(v);
        } else if (EPI == 1) {
          float sg = v / (1.f + __expf(-v));
          Cb[idx] = f2b(sg);
        } else if (EPI == 2) {
          float gv = b2f(Gm[idx]);
          Gm[idx] = f2b(gv * v);
        } else {
          Cf[idx] = Res[idx] + v;
        }
      }
    }
  }
#undef STAGE_AH
#undef STAGE_BH
#undef LG0
}

// =====================================================================================
// 8-phase GEMM (BM=256 BN=128, unchanged) for N=2048 GEMMs (o-proj, down): grid 256.
// =====================================================================================
template <int EPI>
__global__ __launch_bounds__(512, 2) void gemm256(const u16* __restrict__ A, const u16* __restrict__ Bt,
                                                  int M, int N, int K,
                                                  u16* __restrict__ Cb, float* __restrict__ Cf,
                                                  const float* __restrict__ Res, u16* __restrict__ Gm) {
  __shared__ char lds[98304];
  const int tid = threadIdx.x;
  const int lane = tid & 63, w = tid >> 6;
  const int wm = w >> 1, wn = w & 1;
  const int nwg = gridDim.x * gridDim.y;
  const int bid = blockIdx.y * gridDim.x + blockIdx.x;
  const int swz = (bid & 7) * (nwg >> 3) + (bid >> 3);
  const int bx = swz % gridDim.x, by = swz / gridDim.x;
  const int n0 = bx * 128, m0 = by * 256;
  const int NT = K >> 6;

  const int r8 = lane >> 3, s8 = lane & 7;
  const int slog8 = (s8 ^ r8) * 8;
  const u16* Abase = A + (size_t)(m0 + w * 8 + r8) * K + slog8;
  const u16* Bbase = Bt + (size_t)(n0 + w * 8 + r8) * K + slog8;
  const int stA = w * 1024;

#define STAGE_A(buf, kt, h)                                                        \
  {                                                                                \
    const u16* s_ = Abase + (size_t)(h) * 128 * K + (size_t)(kt) * 64;             \
    gl_lds16(s_, lds + (buf) * 49152 + (h) * 16384 + stA);                         \
    gl_lds16(s_ + 64 * (size_t)K, lds + (buf) * 49152 + (h) * 16384 + stA + 8192); \
  }
#define STAGE_B(buf, kt)                                                     \
  {                                                                          \
    const u16* s_ = Bbase + (size_t)(kt) * 64;                               \
    gl_lds16(s_, lds + (buf) * 49152 + 32768 + stA);                         \
    gl_lds16(s_ + 64 * (size_t)K, lds + (buf) * 49152 + 32768 + stA + 8192); \
  }
#define LG0 { asm volatile("s_waitcnt lgkmcnt(0)" ::: "memory"); __builtin_amdgcn_sched_barrier(0); }

  const int l15 = lane & 15, l4 = lane >> 4;
  const int kq0 = (l4 * 16) ^ ((lane & 7) << 4);
  const int kq1 = (64 + l4 * 16) ^ ((lane & 7) << 4);
  const int aro = (wm >> 1) * 16384 + ((wm & 1) * 64 + l15) * 128;
  const int bro = 32768 + (wn * 64 + l15) * 128;

  const f32x4 fz = {0.f, 0.f, 0.f, 0.f};
  f32x4 acc[4][4];
#pragma unroll
  for (int i = 0; i < 4; i++)
#pragma unroll
    for (int j = 0; j < 4; j++) acc[i][j] = fz;
  bf16x8 af[4][2], bfr[4][2];

  STAGE_A(0, 0, 0);
  STAGE_A(0, 0, 1);
  STAGE_B(0, 0);
  STAGE_A(1, 1, 0);
  STAGE_A(1, 1, 1);
  asm volatile("s_waitcnt vmcnt(4)" ::: "memory");
  __builtin_amdgcn_s_barrier();

  for (int t = 0; t < NT; ++t) {
    const int buf = t & 1;
    const char* Lb = lds + buf * 49152;
    const int t1 = (t + 1 < NT) ? t + 1 : NT - 1;
    const int t2 = (t + 2 < NT) ? t + 2 : NT - 1;
    if (wm < 2) {
#pragma unroll
      for (int mf = 0; mf < 4; mf++) {
        af[mf][0] = *(const bf16x8*)(Lb + aro + mf * 2048 + kq0);
        af[mf][1] = *(const bf16x8*)(Lb + aro + mf * 2048 + kq1);
      }
    } else {
#pragma unroll
      for (int mf = 0; mf < 4; mf++)
        af[mf][0] = *(const bf16x8*)(Lb + aro + mf * 2048 + kq0);
    }
#pragma unroll
    for (int nf = 0; nf < 4; nf++)
      bfr[nf][0] = *(const bf16x8*)(Lb + bro + nf * 2048 + kq0);
    STAGE_B((t + 1) & 1, t1);
    __builtin_amdgcn_s_barrier();
    LG0;
    __builtin_amdgcn_s_setprio(1);
#pragma unroll
    for (int nf = 0; nf < 4; nf++) {
      acc[0][nf] = __builtin_amdgcn_mfma_f32_16x16x32_bf16(af[0][0], bfr[nf][0], acc[0][nf], 0, 0, 0);
      acc[1][nf] = __builtin_amdgcn_mfma_f32_16x16x32_bf16(af[1][0], bfr[nf][0], acc[1][nf], 0, 0, 0);
    }
    __builtin_amdgcn_s_setprio(0);
    __builtin_amdgcn_s_barrier();
    if (wm >= 2) {
#pragma unroll
      for (int mf = 0; mf < 4; mf++)
        af[mf][1] = *(const bf16x8*)(Lb + aro + mf * 2048 + kq1);
    }
#pragma unroll
    for (int nf = 0; nf < 4; nf++)
      bfr[nf][1] = *(const bf16x8*)(Lb + bro + nf * 2048 + kq1);
    STAGE_A(buf, t2, 0);
    __builtin_amdgcn_s_barrier();
    LG0;
    __builtin_amdgcn_s_setprio(1);
#pragma unroll
    for (int nf = 0; nf < 4; nf++) {
      acc[2][nf] = __builtin_amdgcn_mfma_f32_16x16x32_bf16(af[2][0], bfr[nf][0], acc[2][nf], 0, 0, 0);
      acc[3][nf] = __builtin_amdgcn_mfma_f32_16x16x32_bf16(af[3][0], bfr[nf][0], acc[3][nf], 0, 0, 0);
    }
    __builtin_amdgcn_s_setprio(0);
    __builtin_amdgcn_s_barrier();
    STAGE_A(buf, t2, 1);
    __builtin_amdgcn_s_barrier();
    LG0;
    __builtin_amdgcn_s_setprio(1);
#pragma unroll
    for (int nf = 0; nf < 4; nf++) {
      acc[0][nf] = __builtin_amdgcn_mfma_f32_16x16x32_bf16(af[0][1], bfr[nf][1], acc[0][nf], 0, 0, 0);
      acc[1][nf] = __builtin_amdgcn_mfma_f32_16x16x32_bf16(af[1][1], bfr[nf][1], acc[1][nf], 0, 0, 0);
    }
    __builtin_amdgcn_s_setprio(0);
    __builtin_amdgcn_s_barrier();
    __builtin_amdgcn_s_setprio(1);
#pragma unroll
    for (int nf = 0; nf < 4; nf++) {
      acc[2][nf] = __builtin_amdgcn_mfma_f32_16x16x32_bf16(af[2][1], bfr[nf][1], acc[2][nf], 0, 0, 0);
      acc[3][nf] = __builtin_amdgcn_mfma_f32_16x16x32_bf16(af[3][1], bfr[nf][1], acc[3][nf], 0, 0, 0);
    }
    __builtin_amdgcn_s_setprio(0);
    asm volatile("s_waitcnt vmcnt(4)" ::: "memory");
    __builtin_amdgcn_s_barrier();
  }
  asm volatile("s_waitcnt vmcnt(0)" ::: "memory");

  const int r0 = l4 * 4;
#pragma unroll
  for (int mf = 0; mf < 4; mf++) {
#pragma unroll
    for (int j = 0; j < 4; j++) {
      const int m = m0 + wm * 64 + mf * 16 + r0 + j;
#pragma unroll
      for (int nf = 0; nf < 4; nf++) {
        const int n = n0 + wn * 64 + nf * 16 + l15;
        float v = acc[mf][nf][j];
        size_t idx = (size_t)m * N + n;
        if (EPI == 0) {
          Cb[idx] = f2b(v);
        } else if (EPI == 1) {
          float sg = v / (1.f + __expf(-v));
          Cb[idx] = f2b(sg);
        } else if (EPI == 2) {
          float gv = b2f(Gm[idx]);
          Gm[idx] = f2b(gv * v);
        } else {
          Cf[idx] = Res[idx] + v;
        }
      }
    }
  }
#undef STAGE_A
#undef STAGE_B
#undef LG0
}

// =====================================================================================
// flash attention v3 (unchanged): swapped-operand 32x32x16, in-register softmax.
// =====================================================================================
__global__ __launch_bounds__(512, 2) void attn_k(const u16* __restrict__ qkv, const u16* __restrict__ vt,
                                                 u16* __restrict__ out) {
  __shared__ char Kl[2][16384];
  __shared__ char Vl[2][16384];
  int tid = threadIdx.x, lane = tid & 63, w = tid >> 6;
  int bid = blockIdx.y * 8 + blockIdx.x;
  int swz = (bid & 7) * 32 + (bid >> 3);
  int qb = swz & 7, bh = swz >> 3;
  int b = bh >> 4, h = bh & 15;
  int l31 = lane & 31, hi = lane >> 5;
  const float c = 0.088388347648318447f * 1.4426950408889634f;
  const float RT = 90.51f;

  const int qrow = qb * 256 + w * 32 + l31;
  bf16x8 q[8];
  {
    const u16* qp = qkv + (size_t)(b * SEQ + qrow) * 6144 + h * HEADD + hi * 8;
#pragma unroll
    for (int dt = 0; dt < 8; dt++) q[dt] = *(const bf16x8*)(qp + dt * 16);
  }
  f32x16 o[4];
#pragma unroll
  for (int i = 0; i < 4; i++)
#pragma unroll
    for (int j = 0; j < 16; j++) o[i][j] = 0.f;
  float mrow = -1e30f, lrow = 0.f;

#define ASTAGE(buf, t)                                                                     \
  {                                                                                        \
    int kv0_ = (t) * 64;                                                                   \
    _Pragma("unroll") for (int i = 0; i < 2; i++) {                                        \
      int r = w * 8 + i * 4 + (lane >> 4);                                                 \
      int col = ((lane & 15) ^ (r & 15)) * 8;                                              \
      const u16* src = qkv + (size_t)(b * SEQ + kv0_ + r) * 6144 + HDIM + h * HEADD + col; \
      gl_lds16(src, &Kl[buf][(w * 8 + i * 4) * 256]);                                      \
    }                                                                                      \
    _Pragma("unroll") for (int i = 0; i < 2; i++) {                                        \
      int d = w * 16 + i * 8 + (lane >> 3);                                                \
      int col = ((lane & 7) ^ (d & 7)) * 8;                                                \
      const u16* src = vt + (size_t)(bh * HEADD + d) * SEQ + kv0_ + col;                   \
      gl_lds16(src, &Vl[buf][(w * 16 + i * 8) * 128]);                                     \
    }                                                                                      \
  }

  ASTAGE(0, 0);
  __syncthreads();

  for (int t = 0; t < SEQ / 64; t++) {
    const int buf = t & 1;
    if (t + 1 < SEQ / 64) ASTAGE(buf ^ 1, t + 1);
    const char* Kb = &Kl[buf][0];
    const char* Vb = &Vl[buf][0];
    f32x16 s0, s1;
#pragma unroll
    for (int j = 0; j < 16; j++) { s0[j] = 0.f; s1[j] = 0.f; }
    const int ksl = l31 & 15;
    __builtin_amdgcn_s_setprio(1);
#pragma unroll
    for (int dt = 0; dt < 8; dt++) {
      bf16x8 k0 = *(const bf16x8*)(Kb + (l31)*256 + (((dt * 2 + hi) ^ ksl) << 4));
      bf16x8 k1 = *(const bf16x8*)(Kb + (32 + l31) * 256 + (((dt * 2 + hi) ^ ksl) << 4));
      s0 = __builtin_amdgcn_mfma_f32_32x32x16_bf16(k0, q[dt], s0, 0, 0, 0);
      s1 = __builtin_amdgcn_mfma_f32_32x32x16_bf16(k1, q[dt], s1, 0, 0, 0);
    }
    __builtin_amdgcn_s_setprio(0);
    float m8[8];
#pragma unroll
    for (int g = 0; g < 4; g++) {
      m8[g] = fmaxf(fmaxf(s0[4 * g], s0[4 * g + 1]), fmaxf(s0[4 * g + 2], s0[4 * g + 3]));
      m8[4 + g] = fmaxf(fmaxf(s1[4 * g], s1[4 * g + 1]), fmaxf(s1[4 * g + 2], s1[4 * g + 3]));
    }
    float vmax = fmaxf(fmaxf(fmaxf(m8[0], m8[1]), fmaxf(m8[2], m8[3])),
                       fmaxf(fmaxf(m8[4], m8[5]), fmaxf(m8[6], m8[7])));
    {
      uv2 pr = __builtin_amdgcn_permlane32_swap(__builtin_bit_cast(unsigned, vmax),
                                                __builtin_bit_cast(unsigned, vmax), false, false);
      vmax = fmaxf(__builtin_bit_cast(float, pr[0]), __builtin_bit_cast(float, pr[1]));
    }
    if (__any(vmax > mrow + RT)) {
      float mnew = fmaxf(mrow, vmax);
      float alpha = exp2f((mrow - mnew) * c);
      mrow = mnew;
      lrow *= alpha;
#pragma unroll
      for (int i = 0; i < 4; i++)
#pragma unroll
        for (int j = 0; j < 16; j++) o[i][j] *= alpha;
    }
    const float mc = mrow * c;
    float r4[4] = {0.f, 0.f, 0.f, 0.f};
#pragma unroll
    for (int j = 0; j < 16; j++) {
      s0[j] = exp2f(s0[j] * c - mc);
      r4[j & 3] += s0[j];
    }
#pragma unroll
    for (int j = 0; j < 16; j++) {
      s1[j] = exp2f(s1[j] * c - mc);
      r4[j & 3] += s1[j];
    }
    float rsum = (r4[0] + r4[1]) + (r4[2] + r4[3]);
    {
      uv2 pr = __builtin_amdgcn_permlane32_swap(__builtin_bit_cast(unsigned, rsum),
                                                __builtin_bit_cast(unsigned, rsum), false, false);
      rsum = __builtin_bit_cast(float, pr[0]) + __builtin_bit_cast(float, pr[1]);
    }
    lrow += rsum;
    bf16x8 pa[4];
#pragma unroll
    for (int half = 0; half < 2; half++) {
      const f32x16& sv = half ? s1 : s0;
#pragma unroll
      for (int blk = 0; blk < 2; blk++) {
        int base = blk * 8;
        unsigned A = cvtpk(sv[base + 0], sv[base + 1]);
        unsigned B = cvtpk(sv[base + 2], sv[base + 3]);
        unsigned C = cvtpk(sv[base + 4], sv[base + 5]);
        unsigned D = cvtpk(sv[base + 6], sv[base + 7]);
        uv2 ac = __builtin_amdgcn_permlane32_swap(A, C, false, false);
        uv2 bd = __builtin_amdgcn_permlane32_swap(B, D, false, false);
        u32x4 w4;
        w4[0] = ac[0]; w4[1] = bd[0]; w4[2] = ac[1]; w4[3] = bd[1];
        pa[half * 2 + blk] = __builtin_bit_cast(bf16x8, w4);
      }
    }
    __builtin_amdgcn_s_setprio(1);
#pragma unroll
    for (int dt4 = 0; dt4 < 4; dt4++) {
      const char* vbase = Vb + (dt4 * 32 + l31) * 128;
      const int vsl = l31 & 7;
#pragma unroll
      for (int ks = 0; ks < 4; ks++) {
        bf16x8 vb = *(const bf16x8*)(vbase + (((ks * 2 + hi) ^ vsl) << 4));
        o[dt4] = __builtin_amdgcn_mfma_f32_32x32x16_bf16(vb, pa[ks], o[dt4], 0, 0, 0);
      }
    }
    __builtin_amdgcn_s_setprio(0);
    __syncthreads();
  }
#undef ASTAGE

  const float linv = 1.0f / lrow;
  u16* orow = out + (size_t)(b * SEQ + qrow) * HDIM + h * HEADD;
#pragma unroll
  for (int dt4 = 0; dt4 < 4; dt4++) {
#pragma unroll
    for (int g = 0; g < 4; g++) {
      u32x2 st;
      st[0] = cvtpk(o[dt4][4 * g + 0] * linv, o[dt4][4 * g + 1] * linv);
      st[1] = cvtpk(o[dt4][4 * g + 2] * linv, o[dt4][4 * g + 3] * linv);
      *(u32x2*)(orow + dt4 * 32 + 8 * g + 4 * hi) = st;
    }
  }
}

extern "C" void kernel_launch(void* const* d_in, const int* in_sizes, int n_in,
                              void* d_out, int out_size, void* d_ws, size_t ws_size,
                              hipStream_t stream) {
  const float* hs  = (const float*)d_in[0];
  const float* wq  = (const float*)d_in[1];
  const float* wk  = (const float*)d_in[2];
  const float* wv  = (const float*)d_in[3];
  const float* wo  = (const float*)d_in[4];
  const float* wg  = (const float*)d_in[5];
  const float* wu  = (const float*)d_in[6];
  const float* wd  = (const float*)d_in[7];
  const float* ln1 = (const float*)d_in[8];
  const float* ln2 = (const float*)d_in[9];
  char* ws = (char*)d_ws;
  u16*   wqkvT = (u16*)(ws);
  u16*   woT   = (u16*)(ws + 25165824ull);
  u16*   wgT   = (u16*)(ws + 33554432ull);
  u16*   wuT   = (u16*)(ws + 67108864ull);
  u16*   wdT   = (u16*)(ws + 100663296ull);
  u16*   xb    = (u16*)(ws + 134217728ull);
  float* hid   = (float*)(ws + 150994944ull);
  u16*   qkv   = (u16*)(ws + 184549376ull);
  u16*   vtb   = (u16*)(ws + 234881024ull);
  u16*   attn  = (u16*)(ws + 251658368ull);
  u16*   g     = qkv;  // alias M x I bf16 over qkv+vt region

  wtrans_k<<<dim3(32, 32), 256, 0, stream>>>(wq, wqkvT, HDIM, HDIM, 0);
  wtrans_k<<<dim3(32, 32), 256, 0, stream>>>(wk, wqkvT, HDIM, HDIM, 2048);
  wtrans_k<<<dim3(32, 32), 256, 0, stream>>>(wv, wqkvT, HDIM, HDIM, 4096);
  wtrans_k<<<dim3(32, 32), 256, 0, stream>>>(wo, woT, HDIM, HDIM, 0);
  wtrans_k<<<dim3(128, 32), 256, 0, stream>>>(wg, wgT, HDIM, IDIM, 0);
  wtrans_k<<<dim3(128, 32), 256, 0, stream>>>(wu, wuT, HDIM, IDIM, 0);
  wtrans_k<<<dim3(32, 128), 256, 0, stream>>>(wd, wdT, IDIM, HDIM, 0);

  rmsnorm_k<<<MTOK, 256, 0, stream>>>(hs, ln1, xb);
  gemm_w<0><<<dim3(24, 16), 512, 0, stream>>>(xb, wqkvT, MTOK, 6144, HDIM, qkv, nullptr, nullptr, nullptr);
  vtrans_k<<<dim3(64, 4, 32), dim3(32, 8), 0, stream>>>(qkv, vtb);
  attn_k<<<dim3(8, 32), 512, 0, stream>>>(qkv, vtb, attn);
  gemm256<3><<<dim3(16, 16), 512, 0, stream>>>(attn, woT, MTOK, HDIM, HDIM, nullptr, hid, hs, nullptr);
  rmsnorm_k<<<MTOK, 256, 0, stream>>>(hid, ln2, xb);
  gemm_w<1><<<dim3(32, 16), 512, 0, stream>>>(xb, wgT, MTOK, IDIM, HDIM, g, nullptr, nullptr, nullptr);
  gemm_w<2><<<dim3(32, 16), 512, 0, stream>>>(xb, wuT, MTOK, IDIM, HDIM, nullptr, nullptr, nullptr, g);
  gemm256<3><<<dim3(16, 16), 512, 0, stream>>>(g, wdT, MTOK, HDIM, IDIM, nullptr, (float*)d_out, hid, nullptr);
}

// Round 6
// 726.694 us; speedup vs baseline: 1.5079x; 1.0643x over previous
//
#include <hip/hip_runtime.h>
#include <hip/hip_bf16.h>

#define HDIM 2048
#define IDIM 8192
#define NHEADS 16
#define HEADD 128
#define BATCH 2
#define SEQ 2048
#define MTOK 4096

typedef unsigned short u16;
typedef __bf16 bf16x8 __attribute__((ext_vector_type(8)));
typedef float f32x4 __attribute__((ext_vector_type(4)));
typedef float f32x16 __attribute__((ext_vector_type(16)));
typedef unsigned short u16x8 __attribute__((ext_vector_type(8)));
typedef unsigned int u32x2 __attribute__((ext_vector_type(2)));
typedef unsigned int u32x4 __attribute__((ext_vector_type(4)));
typedef unsigned int uv2 __attribute__((ext_vector_type(2)));

__device__ __forceinline__ u16 f2b(float f) {
  unsigned u = __builtin_bit_cast(unsigned, f);
  u += 0x7FFFu + ((u >> 16) & 1u);
  return (u16)(u >> 16);
}
__device__ __forceinline__ float b2f(u16 b) {
  unsigned u = ((unsigned)b) << 16;
  return __builtin_bit_cast(float, u);
}
__device__ __forceinline__ void gl_lds16(const void* g, void* l) {
  auto gp = (const __attribute__((address_space(1))) unsigned int*)((unsigned long long)g);
  auto lp = (__attribute__((address_space(3))) unsigned int*)((unsigned)(unsigned long long)l);
  __builtin_amdgcn_global_load_lds(gp, lp, 16, 0, 0);
}
__device__ __forceinline__ unsigned cvtpk(float lo, float hi) {
  unsigned r;
  asm("v_cvt_pk_bf16_f32 %0, %1, %2" : "=v"(r) : "v"(lo), "v"(hi));
  return r;
}

// ---------------- merged weight transpose-convert: all 7 weights, one launch ----------------
// Each block does a 64x64 tile of W (K x N fp32) -> Wt (N x K bf16).
__global__ __launch_bounds__(256) void wtrans_all(const float* __restrict__ wq, const float* __restrict__ wk,
                                                  const float* __restrict__ wv, const float* __restrict__ wo,
                                                  const float* __restrict__ wg, const float* __restrict__ wu,
                                                  const float* __restrict__ wd,
                                                  u16* __restrict__ wqkvT, u16* __restrict__ woT,
                                                  u16* __restrict__ wgT, u16* __restrict__ wuT,
                                                  u16* __restrict__ wdT) {
  int bidf = blockIdx.x;
  const float* W;
  u16* Wt;
  int K, N, rowoff, bx, by;
  if (bidf < 3072) {  // wq, wk, wv -> wqkvT
    int s = bidf >> 10, r = bidf & 1023;
    W = s == 0 ? wq : (s == 1 ? wk : wv);
    Wt = wqkvT; K = 2048; N = 2048; rowoff = s * 2048;
    bx = r & 31; by = r >> 5;
  } else if (bidf < 4096) {
    int r = bidf - 3072;
    W = wo; Wt = woT; K = 2048; N = 2048; rowoff = 0;
    bx = r & 31; by = r >> 5;
  } else if (bidf < 8192) {
    int r = bidf - 4096;
    W = wg; Wt = wgT; K = 2048; N = 8192; rowoff = 0;
    bx = r & 127; by = r >> 7;
  } else if (bidf < 12288) {
    int r = bidf - 8192;
    W = wu; Wt = wuT; K = 2048; N = 8192; rowoff = 0;
    bx = r & 127; by = r >> 7;
  } else {
    int r = bidf - 12288;
    W = wd; Wt = wdT; K = 8192; N = 2048; rowoff = 0;
    bx = r & 31; by = r >> 5;
  }
  __shared__ float t[64][65];
  int n0 = bx * 64, k0 = by * 64;
  int tid = threadIdx.x;
  int kr = tid >> 4, nc = (tid & 15) * 4;
#pragma unroll
  for (int p = 0; p < 4; p++) {
    float4 v = *(const float4*)&W[(size_t)(k0 + p * 16 + kr) * N + n0 + nc];
    t[nc + 0][p * 16 + kr] = v.x;
    t[nc + 1][p * 16 + kr] = v.y;
    t[nc + 2][p * 16 + kr] = v.z;
    t[nc + 3][p * 16 + kr] = v.w;
  }
  __syncthreads();
  int n = tid >> 2, kq = (tid & 3) * 16;
  u16 tmp[16];
#pragma unroll
  for (int i = 0; i < 16; i++) tmp[i] = f2b(t[n][kq + i]);
  *(u16x8*)&Wt[(size_t)(rowoff + n0 + n) * K + k0 + kq] = *(u16x8*)&tmp[0];
  *(u16x8*)&Wt[(size_t)(rowoff + n0 + n) * K + k0 + kq + 8] = *(u16x8*)&tmp[8];
}

// ---------------- V transpose ----------------
__global__ __launch_bounds__(256) void vtrans_k(const u16* __restrict__ qkv, u16* __restrict__ vt) {
  __shared__ u16 t[32][33];
  int s0 = blockIdx.x * 32, d0 = blockIdx.y * 32, bh = blockIdx.z;
  int b = bh >> 4, h = bh & 15;
  int tx = threadIdx.x, ty = threadIdx.y;
#pragma unroll
  for (int i = 0; i < 4; i++)
    t[ty + i * 8][tx] = qkv[(size_t)(b * SEQ + s0 + ty + i * 8) * 6144 + 4096 + h * HEADD + d0 + tx];
  __syncthreads();
#pragma unroll
  for (int i = 0; i < 4; i++)
    vt[(size_t)(bh * HEADD + d0 + ty + i * 8) * SEQ + s0 + tx] = t[tx][ty + i * 8];
}

// ---------------- RMSNorm: fp32 in -> bf16 out ----------------
__global__ __launch_bounds__(256) void rmsnorm_k(const float* __restrict__ X, const float* __restrict__ W,
                                                 u16* __restrict__ O) {
  int row = blockIdx.x;
  int tid = threadIdx.x;
  const float* x = X + (size_t)row * HDIM;
  float4 v0 = ((const float4*)x)[tid * 2];
  float4 v1 = ((const float4*)x)[tid * 2 + 1];
  float ss = v0.x * v0.x + v0.y * v0.y + v0.z * v0.z + v0.w * v0.w
           + v1.x * v1.x + v1.y * v1.y + v1.z * v1.z + v1.w * v1.w;
#pragma unroll
  for (int off = 32; off > 0; off >>= 1) ss += __shfl_down(ss, off);
  __shared__ float red[4];
  if ((tid & 63) == 0) red[tid >> 6] = ss;
  __syncthreads();
  float rs = rsqrtf((red[0] + red[1] + red[2] + red[3]) * (1.0f / HDIM) + 1e-6f);
  const float* w = W + tid * 8;
  u16* o = O + (size_t)row * HDIM + tid * 8;
  float vals[8] = {v0.x, v0.y, v0.z, v0.w, v1.x, v1.y, v1.z, v1.w};
#pragma unroll
  for (int j = 0; j < 8; j++) o[j] = f2b(w[j] * vals[j] * rs);
}

// =====================================================================================
// gemm_fgu: fused gate+up. G = silu(A*Wg^T) * (A*Wu^T), bf16 out.
// M=4096, N=8192, K=2048 fixed. BM=256, BN=128 (per matrix), BK=64.
// 512 thr = 8 waves 2M x 4N; per-wave 128x32 per matrix; acc 64+64 f32x4-equiv VGPR.
// LDS 128KB: 2 buf x {A 32KB(rows 0-255), Bg 16KB, Bu 16KB}; rows 128B, slot^(row&7).
// Phases/K-tile: P0 G-kh0 (rd af[8]+bg[2]; stage A0,Bg(t+1); vmcnt(4) at end),
//   P1 U-kh0 (rd bu[2]; stage A1(t+1)), P2 G-kh1 (rd af[8]+bg[2]),
//   P3 U-kh1 (rd bu[2]; stage Bu(t+1); vmcnt(2) at end).
// Deadlines: A0/Bg@t.P0, A1@t.P1 retired by t.P3-end vmcnt(2) (>=2 phases slack);
//   Bu@t.P3 retired by t+1.P0-end vmcnt(4) (2 phases). Never drain in-loop.
// =====================================================================================
__global__ __launch_bounds__(512, 2) void gemm_fgu(const u16* __restrict__ A, const u16* __restrict__ Bg,
                                                   const u16* __restrict__ Bu, u16* __restrict__ G) {
  __shared__ char lds[131072];
  const int tid = threadIdx.x, lane = tid & 63, w = tid >> 6;
  const int wm = w >> 2, wn = w & 3;
  const int bid = blockIdx.y * 64 + blockIdx.x;  // grid (64,16) = 1024
  const int swz = (bid & 7) * 128 + (bid >> 3);
  const int bx = swz & 63, by = swz >> 6;
  const int m0 = by * 256, n0 = bx * 128;
  const int NT = 32;  // K/64

  const int srow = w * 8 + (lane >> 3);
  const int kko = ((lane & 7) ^ (lane >> 3)) * 8;
  const u16* Asrc = A + (size_t)(m0 + srow) * 2048 + kko;
  const u16* Bgsrc = Bg + (size_t)(n0 + srow) * 2048 + kko;
  const u16* Busrc = Bu + (size_t)(n0 + srow) * 2048 + kko;
  const int wofs = w * 1024;

#define SA0(buf, kt)                                                        \
  {                                                                         \
    gl_lds16(Asrc + (kt) * 64, lds + (buf) * 65536 + wofs);                 \
    gl_lds16(Asrc + 64 * 2048 + (kt) * 64, lds + (buf) * 65536 + 8192 + wofs); \
  }
#define SA1(buf, kt)                                                              \
  {                                                                               \
    gl_lds16(Asrc + 128 * 2048 + (kt) * 64, lds + (buf) * 65536 + 16384 + wofs);  \
    gl_lds16(Asrc + 192 * 2048 + (kt) * 64, lds + (buf) * 65536 + 24576 + wofs);  \
  }
#define SBG(buf, kt)                                                              \
  {                                                                               \
    gl_lds16(Bgsrc + (kt) * 64, lds + (buf) * 65536 + 32768 + wofs);              \
    gl_lds16(Bgsrc + 64 * 2048 + (kt) * 64, lds + (buf) * 65536 + 40960 + wofs);  \
  }
#define SBU(buf, kt)                                                              \
  {                                                                               \
    gl_lds16(Busrc + (kt) * 64, lds + (buf) * 65536 + 49152 + wofs);              \
    gl_lds16(Busrc + 64 * 2048 + (kt) * 64, lds + (buf) * 65536 + 57344 + wofs);  \
  }
#define LG0 { asm volatile("s_waitcnt lgkmcnt(0)" ::: "memory"); __builtin_amdgcn_sched_barrier(0); }

  const int l15 = lane & 15, l4 = lane >> 4;
  const int kq0 = ((l4) ^ (l15 & 7)) << 4;
  const int kq1 = ((4 + l4) ^ (l15 & 7)) << 4;
  const int abase = (wm * 128 + l15) * 128;
  const int gbase = 32768 + (wn * 32 + l15) * 128;
  const int ubase = 49152 + (wn * 32 + l15) * 128;

  const f32x4 fz = {0.f, 0.f, 0.f, 0.f};
  f32x4 ag[8][2], au[8][2];
#pragma unroll
  for (int i = 0; i < 8; i++)
#pragma unroll
    for (int j = 0; j < 2; j++) { ag[i][j] = fz; au[i][j] = fz; }
  bf16x8 af[8], bgf[2], buf2[2];

  // prologue: tile0 (Bu last), leave SBU(0) outstanding
  SA0(0, 0);
  SBG(0, 0);
  SA1(0, 0);
  SBU(0, 0);
  asm volatile("s_waitcnt vmcnt(2)" ::: "memory");
  __builtin_amdgcn_s_barrier();

  for (int t = 0; t < NT; ++t) {
    const int buf = t & 1, nb = buf ^ 1;
    const char* Lb = lds + buf * 65536;
    const int t1 = (t + 1 < NT) ? t + 1 : NT - 1;
    // ---------- P0: G, kh0 ----------
#pragma unroll
    for (int mf = 0; mf < 8; mf++) af[mf] = *(const bf16x8*)(Lb + abase + mf * 2048 + kq0);
    bgf[0] = *(const bf16x8*)(Lb + gbase + kq0);
    bgf[1] = *(const bf16x8*)(Lb + gbase + 2048 + kq0);
    SA0(nb, t1);
    SBG(nb, t1);
    __builtin_amdgcn_s_barrier();
    LG0;
    __builtin_amdgcn_s_setprio(1);
#pragma unroll
    for (int mf = 0; mf < 8; mf++) {
      ag[mf][0] = __builtin_amdgcn_mfma_f32_16x16x32_bf16(af[mf], bgf[0], ag[mf][0], 0, 0, 0);
      ag[mf][1] = __builtin_amdgcn_mfma_f32_16x16x32_bf16(af[mf], bgf[1], ag[mf][1], 0, 0, 0);
    }
    __builtin_amdgcn_s_setprio(0);
    asm volatile("s_waitcnt vmcnt(4)" ::: "memory");
    __builtin_amdgcn_s_barrier();
    // ---------- P1: U, kh0 ----------
    buf2[0] = *(const bf16x8*)(Lb + ubase + kq0);
    buf2[1] = *(const bf16x8*)(Lb + ubase + 2048 + kq0);
    SA1(nb, t1);
    __builtin_amdgcn_s_barrier();
    LG0;
    __builtin_amdgcn_s_setprio(1);
#pragma unroll
    for (int mf = 0; mf < 8; mf++) {
      au[mf][0] = __builtin_amdgcn_mfma_f32_16x16x32_bf16(af[mf], buf2[0], au[mf][0], 0, 0, 0);
      au[mf][1] = __builtin_amdgcn_mfma_f32_16x16x32_bf16(af[mf], buf2[1], au[mf][1], 0, 0, 0);
    }
    __builtin_amdgcn_s_setprio(0);
    __builtin_amdgcn_s_barrier();
    // ---------- P2: G, kh1 ----------
#pragma unroll
    for (int mf = 0; mf < 8; mf++) af[mf] = *(const bf16x8*)(Lb + abase + mf * 2048 + kq1);
    bgf[0] = *(const bf16x8*)(Lb + gbase + kq1);
    bgf[1] = *(const bf16x8*)(Lb + gbase + 2048 + kq1);
    __builtin_amdgcn_s_barrier();
    LG0;
    __builtin_amdgcn_s_setprio(1);
#pragma unroll
    for (int mf = 0; mf < 8; mf++) {
      ag[mf][0] = __builtin_amdgcn_mfma_f32_16x16x32_bf16(af[mf], bgf[0], ag[mf][0], 0, 0, 0);
      ag[mf][1] = __builtin_amdgcn_mfma_f32_16x16x32_bf16(af[mf], bgf[1], ag[mf][1], 0, 0, 0);
    }
    __builtin_amdgcn_s_setprio(0);
    __builtin_amdgcn_s_barrier();
    // ---------- P3: U, kh1 ----------
    buf2[0] = *(const bf16x8*)(Lb + ubase + kq1);
    buf2[1] = *(const bf16x8*)(Lb + ubase + 2048 + kq1);
    SBU(nb, t1);
    __builtin_amdgcn_s_barrier();
    LG0;
    __builtin_amdgcn_s_setprio(1);
#pragma unroll
    for (int mf = 0; mf < 8; mf++) {
      au[mf][0] = __builtin_amdgcn_mfma_f32_16x16x32_bf16(af[mf], buf2[0], au[mf][0], 0, 0, 0);
      au[mf][1] = __builtin_amdgcn_mfma_f32_16x16x32_bf16(af[mf], buf2[1], au[mf][1], 0, 0, 0);
    }
    __builtin_amdgcn_s_setprio(0);
    asm volatile("s_waitcnt vmcnt(2)" ::: "memory");
    __builtin_amdgcn_s_barrier();
  }
  asm volatile("s_waitcnt vmcnt(0)" ::: "memory");

  // epilogue: G = f2b(silu(g) * u)
#pragma unroll
  for (int mf = 0; mf < 8; mf++) {
#pragma unroll
    for (int jr = 0; jr < 4; jr++) {
      const int m = m0 + wm * 128 + mf * 16 + l4 * 4 + jr;
#pragma unroll
      for (int nf = 0; nf < 2; nf++) {
        const int n = n0 + wn * 32 + nf * 16 + l15;
        float g = ag[mf][nf][jr];
        float u = au[mf][nf][jr];
        float sg = g / (1.f + __expf(-g));
        G[(size_t)m * IDIM + n] = f2b(sg * u);
      }
    }
  }
#undef SA0
#undef SA1
#undef SBG
#undef SBU
#undef LG0
}

// =====================================================================================
// gemm_w (unchanged, used for QKV): 256x256 tile, BK=64, supertile XCD swizzle.
// =====================================================================================
template <int EPI>
__global__ __launch_bounds__(512, 2) void gemm_w(const u16* __restrict__ A, const u16* __restrict__ Bt,
                                                 int M, int N, int K,
                                                 u16* __restrict__ Cb, float* __restrict__ Cf,
                                                 const float* __restrict__ Res, u16* __restrict__ Gm) {
  __shared__ char lds[131072];
  const int tid = threadIdx.x;
  const int lane = tid & 63, w = tid >> 6;
  const int wm = w >> 2, wn = w & 3;
  const int bid = blockIdx.y * gridDim.x + blockIdx.x;
  const int xcd = bid & 7, idx = bid >> 3;
  const int round = idx >> 4, j = idx & 15;
  const int nsy4 = gridDim.y >> 2;
  const int st = round * 8 + xcd;
  const int sx = st / nsy4, syi = st % nsy4;
  const int by = syi * 4 + (j & 3), bx = sx * 4 + (j >> 2);
  const int m0 = by * 256, n0 = bx * 256;
  const int NT = K >> 6;

  const int srow = w * 8 + (lane >> 3);
  const int kko = ((lane & 7) ^ (lane >> 3)) * 8;
  const u16* Asrc = A + (size_t)(m0 + srow) * K + kko;
  const u16* Bsrc = Bt + (size_t)(n0 + srow) * K + kko;
  const int wofs = w * 1024;

#define STAGE_AH(buf, kt, h)                                                          \
  {                                                                                   \
    gl_lds16(Asrc + ((size_t)((h) * 128) * K) + (size_t)(kt) * 64,                    \
             lds + (buf) * 65536 + (h) * 16384 + wofs);                               \
    gl_lds16(Asrc + ((size_t)((h) * 128 + 64) * K) + (size_t)(kt) * 64,               \
             lds + (buf) * 65536 + (h) * 16384 + 8192 + wofs);                        \
  }
#define STAGE_BH(buf, kt, h)                                                          \
  {                                                                                   \
    gl_lds16(Bsrc + ((size_t)((h) * 128) * K) + (size_t)(kt) * 64,                    \
             lds + (buf) * 65536 + 32768 + (h) * 16384 + wofs);                       \
    gl_lds16(Bsrc + ((size_t)((h) * 128 + 64) * K) + (size_t)(kt) * 64,               \
             lds + (buf) * 65536 + 32768 + (h) * 16384 + 8192 + wofs);                \
  }
#define LG0 { asm volatile("s_waitcnt lgkmcnt(0)" ::: "memory"); __builtin_amdgcn_sched_barrier(0); }

  const int l15 = lane & 15, l4 = lane >> 4;
  const int kq0 = ((l4) ^ (l15 & 7)) << 4;
  const int kq1 = ((4 + l4) ^ (l15 & 7)) << 4;
  const int abase = wm * 16384 + l15 * 128;
  const int bbase = 32768 + (wn >> 1) * 16384 + ((wn & 1) * 64 + l15) * 128;

  const f32x4 fz = {0.f, 0.f, 0.f, 0.f};
  f32x4 acc[8][4];
#pragma unroll
  for (int i = 0; i < 8; i++)
#pragma unroll
    for (int jj = 0; jj < 4; jj++) acc[i][jj] = fz;
  bf16x8 af[4], bfr[4];

  STAGE_AH(0, 0, 0);
  STAGE_AH(0, 0, 1);
  STAGE_BH(0, 0, 0);
  STAGE_BH(0, 0, 1);
  STAGE_AH(1, 1, 0);
  STAGE_BH(1, 1, 0);
  asm volatile("s_waitcnt vmcnt(4)" ::: "memory");
  __builtin_amdgcn_s_barrier();

  for (int t = 0; t < NT; ++t) {
    const int buf = t & 1, nbuf = buf ^ 1;
    const char* Lb = lds + buf * 65536;
    const int t1 = (t + 1 < NT) ? t + 1 : NT - 1;
    const int t2 = (t + 2 < NT) ? t + 2 : NT - 1;
    // P0
#pragma unroll
    for (int mf = 0; mf < 4; mf++) af[mf] = *(const bf16x8*)(Lb + abase + mf * 2048 + kq0);
#pragma unroll
    for (int nf = 0; nf < 4; nf++) bfr[nf] = *(const bf16x8*)(Lb + bbase + nf * 2048 + kq0);
    STAGE_AH(nbuf, t1, 1);
    STAGE_BH(nbuf, t1, 1);
    __builtin_amdgcn_s_barrier();
    LG0;
    __builtin_amdgcn_s_setprio(1);
#pragma unroll
    for (int mf = 0; mf < 4; mf++)
#pragma unroll
      for (int nf = 0; nf < 4; nf++)
        acc[mf][nf] = __builtin_amdgcn_mfma_f32_16x16x32_bf16(af[mf], bfr[nf], acc[mf][nf], 0, 0, 0);
    __builtin_amdgcn_s_setprio(0);
    __builtin_amdgcn_s_barrier();
    // P1
#pragma unroll
    for (int mf = 0; mf < 4; mf++) af[mf] = *(const bf16x8*)(Lb + abase + (mf + 4) * 2048 + kq0);
    __builtin_amdgcn_s_barrier();
    LG0;
    __builtin_amdgcn_s_setprio(1);
#pragma unroll
    for (int mf = 0; mf < 4; mf++)
#pragma unroll
      for (int nf = 0; nf < 4; nf++)
        acc[mf + 4][nf] = __builtin_amdgcn_mfma_f32_16x16x32_bf16(af[mf], bfr[nf], acc[mf + 4][nf], 0, 0, 0);
    __builtin_amdgcn_s_setprio(0);
    __builtin_amdgcn_s_barrier();
    // P2
#pragma unroll
    for (int mf = 0; mf < 4; mf++) af[mf] = *(const bf16x8*)(Lb + abase + mf * 2048 + kq1);
#pragma unroll
    for (int nf = 0; nf < 4; nf++) bfr[nf] = *(const bf16x8*)(Lb + bbase + nf * 2048 + kq1);
    __builtin_amdgcn_s_barrier();
    LG0;
    __builtin_amdgcn_s_setprio(1);
#pragma unroll
    for (int mf = 0; mf < 4; mf++)
#pragma unroll
      for (int nf = 0; nf < 4; nf++)
        acc[mf][nf] = __builtin_amdgcn_mfma_f32_16x16x32_bf16(af[mf], bfr[nf], acc[mf][nf], 0, 0, 0);
    __builtin_amdgcn_s_setprio(0);
    __builtin_amdgcn_s_barrier();
    // P3
#pragma unroll
    for (int mf = 0; mf < 4; mf++) af[mf] = *(const bf16x8*)(Lb + abase + (mf + 4) * 2048 + kq1);
    STAGE_AH(buf, t2, 0);
    STAGE_BH(buf, t2, 0);
    __builtin_amdgcn_s_barrier();
    LG0;
    __builtin_amdgcn_s_setprio(1);
#pragma unroll
    for (int mf = 0; mf < 4; mf++)
#pragma unroll
      for (int nf = 0; nf < 4; nf++)
        acc[mf + 4][nf] = __builtin_amdgcn_mfma_f32_16x16x32_bf16(af[mf], bfr[nf], acc[mf + 4][nf], 0, 0, 0);
    __builtin_amdgcn_s_setprio(0);
    asm volatile("s_waitcnt vmcnt(4)" ::: "memory");
    __builtin_amdgcn_s_barrier();
  }
  asm volatile("s_waitcnt vmcnt(0)" ::: "memory");

  const int r0 = l4 * 4;
#pragma unroll
  for (int mf = 0; mf < 8; mf++) {
#pragma unroll
    for (int jr = 0; jr < 4; jr++) {
      const int m = m0 + wm * 128 + mf * 16 + r0 + jr;
#pragma unroll
      for (int nf = 0; nf < 4; nf++) {
        const int n = n0 + wn * 64 + nf * 16 + l15;
        float v = acc[mf][nf][jr];
        size_t idx = (size_t)m * N + n;
        if (EPI == 0) {
          Cb[idx] = f2b(v);
        } else if (EPI == 3) {
          Cf[idx] = Res[idx] + v;
        }
      }
    }
  }
#undef STAGE_AH
#undef STAGE_BH
#undef LG0
}

// =====================================================================================
// 8-phase GEMM (BM=256 BN=128, unchanged) for N=2048 GEMMs (o-proj, down): grid 256.
// =====================================================================================
template <int EPI>
__global__ __launch_bounds__(512, 2) void gemm256(const u16* __restrict__ A, const u16* __restrict__ Bt,
                                                  int M, int N, int K,
                                                  u16* __restrict__ Cb, float* __restrict__ Cf,
                                                  const float* __restrict__ Res, u16* __restrict__ Gm) {
  __shared__ char lds[98304];
  const int tid = threadIdx.x;
  const int lane = tid & 63, w = tid >> 6;
  const int wm = w >> 1, wn = w & 1;
  const int nwg = gridDim.x * gridDim.y;
  const int bid = blockIdx.y * gridDim.x + blockIdx.x;
  const int swz = (bid & 7) * (nwg >> 3) + (bid >> 3);
  const int bx = swz % gridDim.x, by = swz / gridDim.x;
  const int n0 = bx * 128, m0 = by * 256;
  const int NT = K >> 6;

  const int r8 = lane >> 3, s8 = lane & 7;
  const int slog8 = (s8 ^ r8) * 8;
  const u16* Abase = A + (size_t)(m0 + w * 8 + r8) * K + slog8;
  const u16* Bbase = Bt + (size_t)(n0 + w * 8 + r8) * K + slog8;
  const int stA = w * 1024;

#define STAGE_A(buf, kt, h)                                                        \
  {                                                                                \
    const u16* s_ = Abase + (size_t)(h) * 128 * K + (size_t)(kt) * 64;             \
    gl_lds16(s_, lds + (buf) * 49152 + (h) * 16384 + stA);                         \
    gl_lds16(s_ + 64 * (size_t)K, lds + (buf) * 49152 + (h) * 16384 + stA + 8192); \
  }
#define STAGE_B(buf, kt)                                                     \
  {                                                                          \
    const u16* s_ = Bbase + (size_t)(kt) * 64;                               \
    gl_lds16(s_, lds + (buf) * 49152 + 32768 + stA);                         \
    gl_lds16(s_ + 64 * (size_t)K, lds + (buf) * 49152 + 32768 + stA + 8192); \
  }
#define LG0 { asm volatile("s_waitcnt lgkmcnt(0)" ::: "memory"); __builtin_amdgcn_sched_barrier(0); }

  const int l15 = lane & 15, l4 = lane >> 4;
  const int kq0 = (l4 * 16) ^ ((lane & 7) << 4);
  const int kq1 = (64 + l4 * 16) ^ ((lane & 7) << 4);
  const int aro = (wm >> 1) * 16384 + ((wm & 1) * 64 + l15) * 128;
  const int bro = 32768 + (wn * 64 + l15) * 128;

  const f32x4 fz = {0.f, 0.f, 0.f, 0.f};
  f32x4 acc[4][4];
#pragma unroll
  for (int i = 0; i < 4; i++)
#pragma unroll
    for (int j = 0; j < 4; j++) acc[i][j] = fz;
  bf16x8 af[4][2], bfr[4][2];

  STAGE_A(0, 0, 0);
  STAGE_A(0, 0, 1);
  STAGE_B(0, 0);
  STAGE_A(1, 1, 0);
  STAGE_A(1, 1, 1);
  asm volatile("s_waitcnt vmcnt(4)" ::: "memory");
  __builtin_amdgcn_s_barrier();

  for (int t = 0; t < NT; ++t) {
    const int buf = t & 1;
    const char* Lb = lds + buf * 49152;
    const int t1 = (t + 1 < NT) ? t + 1 : NT - 1;
    const int t2 = (t + 2 < NT) ? t + 2 : NT - 1;
    if (wm < 2) {
#pragma unroll
      for (int mf = 0; mf < 4; mf++) {
        af[mf][0] = *(const bf16x8*)(Lb + aro + mf * 2048 + kq0);
        af[mf][1] = *(const bf16x8*)(Lb + aro + mf * 2048 + kq1);
      }
    } else {
#pragma unroll
      for (int mf = 0; mf < 4; mf++)
        af[mf][0] = *(const bf16x8*)(Lb + aro + mf * 2048 + kq0);
    }
#pragma unroll
    for (int nf = 0; nf < 4; nf++)
      bfr[nf][0] = *(const bf16x8*)(Lb + bro + nf * 2048 + kq0);
    STAGE_B((t + 1) & 1, t1);
    __builtin_amdgcn_s_barrier();
    LG0;
    __builtin_amdgcn_s_setprio(1);
#pragma unroll
    for (int nf = 0; nf < 4; nf++) {
      acc[0][nf] = __builtin_amdgcn_mfma_f32_16x16x32_bf16(af[0][0], bfr[nf][0], acc[0][nf], 0, 0, 0);
      acc[1][nf] = __builtin_amdgcn_mfma_f32_16x16x32_bf16(af[1][0], bfr[nf][0], acc[1][nf], 0, 0, 0);
    }
    __builtin_amdgcn_s_setprio(0);
    __builtin_amdgcn_s_barrier();
    if (wm >= 2) {
#pragma unroll
      for (int mf = 0; mf < 4; mf++)
        af[mf][1] = *(const bf16x8*)(Lb + aro + mf * 2048 + kq1);
    }
#pragma unroll
    for (int nf = 0; nf < 4; nf++)
      bfr[nf][1] = *(const bf16x8*)(Lb + bro + nf * 2048 + kq1);
    STAGE_A(buf, t2, 0);
    __builtin_amdgcn_s_barrier();
    LG0;
    __builtin_amdgcn_s_setprio(1);
#pragma unroll
    for (int nf = 0; nf < 4; nf++) {
      acc[2][nf] = __builtin_amdgcn_mfma_f32_16x16x32_bf16(af[2][0], bfr[nf][0], acc[2][nf], 0, 0, 0);
      acc[3][nf] = __builtin_amdgcn_mfma_f32_16x16x32_bf16(af[3][0], bfr[nf][0], acc[3][nf], 0, 0, 0);
    }
    __builtin_amdgcn_s_setprio(0);
    __builtin_amdgcn_s_barrier();
    STAGE_A(buf, t2, 1);
    __builtin_amdgcn_s_barrier();
    LG0;
    __builtin_amdgcn_s_setprio(1);
#pragma unroll
    for (int nf = 0; nf < 4; nf++) {
      acc[0][nf] = __builtin_amdgcn_mfma_f32_16x16x32_bf16(af[0][1], bfr[nf][1], acc[0][nf], 0, 0, 0);
      acc[1][nf] = __builtin_amdgcn_mfma_f32_16x16x32_bf16(af[1][1], bfr[nf][1], acc[1][nf], 0, 0, 0);
    }
    __builtin_amdgcn_s_setprio(0);
    __builtin_amdgcn_s_barrier();
    __builtin_amdgcn_s_setprio(1);
#pragma unroll
    for (int nf = 0; nf < 4; nf++) {
      acc[2][nf] = __builtin_amdgcn_mfma_f32_16x16x32_bf16(af[2][1], bfr[nf][1], acc[2][nf], 0, 0, 0);
      acc[3][nf] = __builtin_amdgcn_mfma_f32_16x16x32_bf16(af[3][1], bfr[nf][1], acc[3][nf], 0, 0, 0);
    }
    __builtin_amdgcn_s_setprio(0);
    asm volatile("s_waitcnt vmcnt(4)" ::: "memory");
    __builtin_amdgcn_s_barrier();
  }
  asm volatile("s_waitcnt vmcnt(0)" ::: "memory");

  const int r0 = l4 * 4;
#pragma unroll
  for (int mf = 0; mf < 4; mf++) {
#pragma unroll
    for (int j = 0; j < 4; j++) {
      const int m = m0 + wm * 64 + mf * 16 + r0 + j;
#pragma unroll
      for (int nf = 0; nf < 4; nf++) {
        const int n = n0 + wn * 64 + nf * 16 + l15;
        float v = acc[mf][nf][j];
        size_t idx = (size_t)m * N + n;
        if (EPI == 0) {
          Cb[idx] = f2b(v);
        } else if (EPI == 3) {
          Cf[idx] = Res[idx] + v;
        }
      }
    }
  }
#undef STAGE_A
#undef STAGE_B
#undef LG0
}

// =====================================================================================
// flash attention v3 (unchanged): swapped-operand 32x32x16, in-register softmax.
// =====================================================================================
__global__ __launch_bounds__(512, 2) void attn_k(const u16* __restrict__ qkv, const u16* __restrict__ vt,
                                                 u16* __restrict__ out) {
  __shared__ char Kl[2][16384];
  __shared__ char Vl[2][16384];
  int tid = threadIdx.x, lane = tid & 63, w = tid >> 6;
  int bid = blockIdx.y * 8 + blockIdx.x;
  int swz = (bid & 7) * 32 + (bid >> 3);
  int qb = swz & 7, bh = swz >> 3;
  int b = bh >> 4, h = bh & 15;
  int l31 = lane & 31, hi = lane >> 5;
  const float c = 0.088388347648318447f * 1.4426950408889634f;
  const float RT = 90.51f;

  const int qrow = qb * 256 + w * 32 + l31;
  bf16x8 q[8];
  {
    const u16* qp = qkv + (size_t)(b * SEQ + qrow) * 6144 + h * HEADD + hi * 8;
#pragma unroll
    for (int dt = 0; dt < 8; dt++) q[dt] = *(const bf16x8*)(qp + dt * 16);
  }
  f32x16 o[4];
#pragma unroll
  for (int i = 0; i < 4; i++)
#pragma unroll
    for (int j = 0; j < 16; j++) o[i][j] = 0.f;
  float mrow = -1e30f, lrow = 0.f;

#define ASTAGE(buf, t)                                                                     \
  {                                                                                        \
    int kv0_ = (t) * 64;                                                                   \
    _Pragma("unroll") for (int i = 0; i < 2; i++) {                                        \
      int r = w * 8 + i * 4 + (lane >> 4);                                                 \
      int col = ((lane & 15) ^ (r & 15)) * 8;                                              \
      const u16* src = qkv + (size_t)(b * SEQ + kv0_ + r) * 6144 + HDIM + h * HEADD + col; \
      gl_lds16(src, &Kl[buf][(w * 8 + i * 4) * 256]);                                      \
    }                                                                                      \
    _Pragma("unroll") for (int i = 0; i < 2; i++) {                                        \
      int d = w * 16 + i * 8 + (lane >> 3);                                                \
      int col = ((lane & 7) ^ (d & 7)) * 8;                                                \
      const u16* src = vt + (size_t)(bh * HEADD + d) * SEQ + kv0_ + col;                   \
      gl_lds16(src, &Vl[buf][(w * 16 + i * 8) * 128]);                                     \
    }                                                                                      \
  }

  ASTAGE(0, 0);
  __syncthreads();

  for (int t = 0; t < SEQ / 64; t++) {
    const int buf = t & 1;
    if (t + 1 < SEQ / 64) ASTAGE(buf ^ 1, t + 1);
    const char* Kb = &Kl[buf][0];
    const char* Vb = &Vl[buf][0];
    f32x16 s0, s1;
#pragma unroll
    for (int j = 0; j < 16; j++) { s0[j] = 0.f; s1[j] = 0.f; }
    const int ksl = l31 & 15;
    __builtin_amdgcn_s_setprio(1);
#pragma unroll
    for (int dt = 0; dt < 8; dt++) {
      bf16x8 k0 = *(const bf16x8*)(Kb + (l31)*256 + (((dt * 2 + hi) ^ ksl) << 4));
      bf16x8 k1 = *(const bf16x8*)(Kb + (32 + l31) * 256 + (((dt * 2 + hi) ^ ksl) << 4));
      s0 = __builtin_amdgcn_mfma_f32_32x32x16_bf16(k0, q[dt], s0, 0, 0, 0);
      s1 = __builtin_amdgcn_mfma_f32_32x32x16_bf16(k1, q[dt], s1, 0, 0, 0);
    }
    __builtin_amdgcn_s_setprio(0);
    float m8[8];
#pragma unroll
    for (int g = 0; g < 4; g++) {
      m8[g] = fmaxf(fmaxf(s0[4 * g], s0[4 * g + 1]), fmaxf(s0[4 * g + 2], s0[4 * g + 3]));
      m8[4 + g] = fmaxf(fmaxf(s1[4 * g], s1[4 * g + 1]), fmaxf(s1[4 * g + 2], s1[4 * g + 3]));
    }
    float vmax = fmaxf(fmaxf(fmaxf(m8[0], m8[1]), fmaxf(m8[2], m8[3])),
                       fmaxf(fmaxf(m8[4], m8[5]), fmaxf(m8[6], m8[7])));
    {
      uv2 pr = __builtin_amdgcn_permlane32_swap(__builtin_bit_cast(unsigned, vmax),
                                                __builtin_bit_cast(unsigned, vmax), false, false);
      vmax = fmaxf(__builtin_bit_cast(float, pr[0]), __builtin_bit_cast(float, pr[1]));
    }
    if (__any(vmax > mrow + RT)) {
      float mnew = fmaxf(mrow, vmax);
      float alpha = exp2f((mrow - mnew) * c);
      mrow = mnew;
      lrow *= alpha;
#pragma unroll
      for (int i = 0; i < 4; i++)
#pragma unroll
        for (int j = 0; j < 16; j++) o[i][j] *= alpha;
    }
    const float mc = mrow * c;
    float r4[4] = {0.f, 0.f, 0.f, 0.f};
#pragma unroll
    for (int j = 0; j < 16; j++) {
      s0[j] = exp2f(s0[j] * c - mc);
      r4[j & 3] += s0[j];
    }
#pragma unroll
    for (int j = 0; j < 16; j++) {
      s1[j] = exp2f(s1[j] * c - mc);
      r4[j & 3] += s1[j];
    }
    float rsum = (r4[0] + r4[1]) + (r4[2] + r4[3]);
    {
      uv2 pr = __builtin_amdgcn_permlane32_swap(__builtin_bit_cast(unsigned, rsum),
                                                __builtin_bit_cast(unsigned, rsum), false, false);
      rsum = __builtin_bit_cast(float, pr[0]) + __builtin_bit_cast(float, pr[1]);
    }
    lrow += rsum;
    bf16x8 pa[4];
#pragma unroll
    for (int half = 0; half < 2; half++) {
      const f32x16& sv = half ? s1 : s0;
#pragma unroll
      for (int blk = 0; blk < 2; blk++) {
        int base = blk * 8;
        unsigned A = cvtpk(sv[base + 0], sv[base + 1]);
        unsigned B = cvtpk(sv[base + 2], sv[base + 3]);
        unsigned C = cvtpk(sv[base + 4], sv[base + 5]);
        unsigned D = cvtpk(sv[base + 6], sv[base + 7]);
        uv2 ac = __builtin_amdgcn_permlane32_swap(A, C, false, false);
        uv2 bd = __builtin_amdgcn_permlane32_swap(B, D, false, false);
        u32x4 w4;
        w4[0] = ac[0]; w4[1] = bd[0]; w4[2] = ac[1]; w4[3] = bd[1];
        pa[half * 2 + blk] = __builtin_bit_cast(bf16x8, w4);
      }
    }
    __builtin_amdgcn_s_setprio(1);
#pragma unroll
    for (int dt4 = 0; dt4 < 4; dt4++) {
      const char* vbase = Vb + (dt4 * 32 + l31) * 128;
      const int vsl = l31 & 7;
#pragma unroll
      for (int ks = 0; ks < 4; ks++) {
        bf16x8 vb = *(const bf16x8*)(vbase + (((ks * 2 + hi) ^ vsl) << 4));
        o[dt4] = __builtin_amdgcn_mfma_f32_32x32x16_bf16(vb, pa[ks], o[dt4], 0, 0, 0);
      }
    }
    __builtin_amdgcn_s_setprio(0);
    __syncthreads();
  }
#undef ASTAGE

  const float linv = 1.0f / lrow;
  u16* orow = out + (size_t)(b * SEQ + qrow) * HDIM + h * HEADD;
#pragma unroll
  for (int dt4 = 0; dt4 < 4; dt4++) {
#pragma unroll
    for (int g = 0; g < 4; g++) {
      u32x2 st;
      st[0] = cvtpk(o[dt4][4 * g + 0] * linv, o[dt4][4 * g + 1] * linv);
      st[1] = cvtpk(o[dt4][4 * g + 2] * linv, o[dt4][4 * g + 3] * linv);
      *(u32x2*)(orow + dt4 * 32 + 8 * g + 4 * hi) = st;
    }
  }
}

extern "C" void kernel_launch(void* const* d_in, const int* in_sizes, int n_in,
                              void* d_out, int out_size, void* d_ws, size_t ws_size,
                              hipStream_t stream) {
  const float* hs  = (const float*)d_in[0];
  const float* wq  = (const float*)d_in[1];
  const float* wk  = (const float*)d_in[2];
  const float* wv  = (const float*)d_in[3];
  const float* wo  = (const float*)d_in[4];
  const float* wg  = (const float*)d_in[5];
  const float* wu  = (const float*)d_in[6];
  const float* wd  = (const float*)d_in[7];
  const float* ln1 = (const float*)d_in[8];
  const float* ln2 = (const float*)d_in[9];
  char* ws = (char*)d_ws;
  u16*   wqkvT = (u16*)(ws);
  u16*   woT   = (u16*)(ws + 25165824ull);
  u16*   wgT   = (u16*)(ws + 33554432ull);
  u16*   wuT   = (u16*)(ws + 67108864ull);
  u16*   wdT   = (u16*)(ws + 100663296ull);
  u16*   xb    = (u16*)(ws + 134217728ull);
  float* hid   = (float*)(ws + 150994944ull);
  u16*   qkv   = (u16*)(ws + 184549376ull);
  u16*   vtb   = (u16*)(ws + 234881024ull);
  u16*   attn  = (u16*)(ws + 251658368ull);
  u16*   g     = qkv;  // alias M x I bf16 over qkv+vt region

  wtrans_all<<<16384, 256, 0, stream>>>(wq, wk, wv, wo, wg, wu, wd, wqkvT, woT, wgT, wuT, wdT);

  rmsnorm_k<<<MTOK, 256, 0, stream>>>(hs, ln1, xb);
  gemm_w<0><<<dim3(24, 16), 512, 0, stream>>>(xb, wqkvT, MTOK, 6144, HDIM, qkv, nullptr, nullptr, nullptr);
  vtrans_k<<<dim3(64, 4, 32), dim3(32, 8), 0, stream>>>(qkv, vtb);
  attn_k<<<dim3(8, 32), 512, 0, stream>>>(qkv, vtb, attn);
  gemm256<3><<<dim3(16, 16), 512, 0, stream>>>(attn, woT, MTOK, HDIM, HDIM, nullptr, hid, hs, nullptr);
  rmsnorm_k<<<MTOK, 256, 0, stream>>>(hid, ln2, xb);
  gemm_fgu<<<dim3(64, 16), 512, 0, stream>>>(xb, wgT, wuT, g);
  gemm256<3><<<dim3(16, 16), 512, 0, stream>>>(g, wdT, MTOK, HDIM, IDIM, nullptr, (float*)d_out, hid, nullptr);
}

// Round 7
// 723.713 us; speedup vs baseline: 1.5141x; 1.0041x over previous
//
#include <hip/hip_runtime.h>
#include <hip/hip_bf16.h>

#define HDIM 2048
#define IDIM 8192
#define NHEADS 16
#define HEADD 128
#define BATCH 2
#define SEQ 2048
#define MTOK 4096

typedef unsigned short u16;
typedef __bf16 bf16x8 __attribute__((ext_vector_type(8)));
typedef float f32x4 __attribute__((ext_vector_type(4)));
typedef float f32x16 __attribute__((ext_vector_type(16)));
typedef unsigned short u16x8 __attribute__((ext_vector_type(8)));
typedef unsigned int u32x2 __attribute__((ext_vector_type(2)));
typedef unsigned int u32x4 __attribute__((ext_vector_type(4)));
typedef unsigned int uv2 __attribute__((ext_vector_type(2)));

__device__ __forceinline__ u16 f2b(float f) {
  unsigned u = __builtin_bit_cast(unsigned, f);
  u += 0x7FFFu + ((u >> 16) & 1u);
  return (u16)(u >> 16);
}
__device__ __forceinline__ float b2f(u16 b) {
  unsigned u = ((unsigned)b) << 16;
  return __builtin_bit_cast(float, u);
}
__device__ __forceinline__ void gl_lds16(const void* g, void* l) {
  auto gp = (const __attribute__((address_space(1))) unsigned int*)((unsigned long long)g);
  auto lp = (__attribute__((address_space(3))) unsigned int*)((unsigned)(unsigned long long)l);
  __builtin_amdgcn_global_load_lds(gp, lp, 16, 0, 0);
}
__device__ __forceinline__ unsigned cvtpk(float lo, float hi) {
  unsigned r;
  asm("v_cvt_pk_bf16_f32 %0, %1, %2" : "=v"(r) : "v"(lo), "v"(hi));
  return r;
}

// ---------------- merged weight transpose-convert: all 7 weights, one launch ----------------
__global__ __launch_bounds__(256) void wtrans_all(const float* __restrict__ wq, const float* __restrict__ wk,
                                                  const float* __restrict__ wv, const float* __restrict__ wo,
                                                  const float* __restrict__ wg, const float* __restrict__ wu,
                                                  const float* __restrict__ wd,
                                                  u16* __restrict__ wqkvT, u16* __restrict__ woT,
                                                  u16* __restrict__ wgT, u16* __restrict__ wuT,
                                                  u16* __restrict__ wdT) {
  int bidf = blockIdx.x;
  const float* W;
  u16* Wt;
  int K, N, rowoff, bx, by;
  if (bidf < 3072) {
    int s = bidf >> 10, r = bidf & 1023;
    W = s == 0 ? wq : (s == 1 ? wk : wv);
    Wt = wqkvT; K = 2048; N = 2048; rowoff = s * 2048;
    bx = r & 31; by = r >> 5;
  } else if (bidf < 4096) {
    int r = bidf - 3072;
    W = wo; Wt = woT; K = 2048; N = 2048; rowoff = 0;
    bx = r & 31; by = r >> 5;
  } else if (bidf < 8192) {
    int r = bidf - 4096;
    W = wg; Wt = wgT; K = 2048; N = 8192; rowoff = 0;
    bx = r & 127; by = r >> 7;
  } else if (bidf < 12288) {
    int r = bidf - 8192;
    W = wu; Wt = wuT; K = 2048; N = 8192; rowoff = 0;
    bx = r & 127; by = r >> 7;
  } else {
    int r = bidf - 12288;
    W = wd; Wt = wdT; K = 8192; N = 2048; rowoff = 0;
    bx = r & 31; by = r >> 5;
  }
  __shared__ float t[64][65];
  int n0 = bx * 64, k0 = by * 64;
  int tid = threadIdx.x;
  int kr = tid >> 4, nc = (tid & 15) * 4;
#pragma unroll
  for (int p = 0; p < 4; p++) {
    float4 v = *(const float4*)&W[(size_t)(k0 + p * 16 + kr) * N + n0 + nc];
    t[nc + 0][p * 16 + kr] = v.x;
    t[nc + 1][p * 16 + kr] = v.y;
    t[nc + 2][p * 16 + kr] = v.z;
    t[nc + 3][p * 16 + kr] = v.w;
  }
  __syncthreads();
  int n = tid >> 2, kq = (tid & 3) * 16;
  u16 tmp[16];
#pragma unroll
  for (int i = 0; i < 16; i++) tmp[i] = f2b(t[n][kq + i]);
  *(u16x8*)&Wt[(size_t)(rowoff + n0 + n) * K + k0 + kq] = *(u16x8*)&tmp[0];
  *(u16x8*)&Wt[(size_t)(rowoff + n0 + n) * K + k0 + kq + 8] = *(u16x8*)&tmp[8];
}

// ---------------- V transpose ----------------
__global__ __launch_bounds__(256) void vtrans_k(const u16* __restrict__ qkv, u16* __restrict__ vt) {
  __shared__ u16 t[32][33];
  int s0 = blockIdx.x * 32, d0 = blockIdx.y * 32, bh = blockIdx.z;
  int b = bh >> 4, h = bh & 15;
  int tx = threadIdx.x, ty = threadIdx.y;
#pragma unroll
  for (int i = 0; i < 4; i++)
    t[ty + i * 8][tx] = qkv[(size_t)(b * SEQ + s0 + ty + i * 8) * 6144 + 4096 + h * HEADD + d0 + tx];
  __syncthreads();
#pragma unroll
  for (int i = 0; i < 4; i++)
    vt[(size_t)(bh * HEADD + d0 + ty + i * 8) * SEQ + s0 + tx] = t[tx][ty + i * 8];
}

// ---------------- RMSNorm: fp32 in -> bf16 out ----------------
__global__ __launch_bounds__(256) void rmsnorm_k(const float* __restrict__ X, const float* __restrict__ W,
                                                 u16* __restrict__ O) {
  int row = blockIdx.x;
  int tid = threadIdx.x;
  const float* x = X + (size_t)row * HDIM;
  float4 v0 = ((const float4*)x)[tid * 2];
  float4 v1 = ((const float4*)x)[tid * 2 + 1];
  float ss = v0.x * v0.x + v0.y * v0.y + v0.z * v0.z + v0.w * v0.w
           + v1.x * v1.x + v1.y * v1.y + v1.z * v1.z + v1.w * v1.w;
#pragma unroll
  for (int off = 32; off > 0; off >>= 1) ss += __shfl_down(ss, off);
  __shared__ float red[4];
  if ((tid & 63) == 0) red[tid >> 6] = ss;
  __syncthreads();
  float rs = rsqrtf((red[0] + red[1] + red[2] + red[3]) * (1.0f / HDIM) + 1e-6f);
  const float* w = W + tid * 8;
  u16* o = O + (size_t)row * HDIM + tid * 8;
  float vals[8] = {v0.x, v0.y, v0.z, v0.w, v1.x, v1.y, v1.z, v1.w};
#pragma unroll
  for (int j = 0; j < 8; j++) o[j] = f2b(w[j] * vals[j] * rs);
}

// =====================================================================================
// gemm_s: single-B minimal-read 2-fat-phase GEMM. C = A(MxK) * Bt(NxK)^T.
// BM=256, BN=128, BK=64. 512 thr = 8 waves 2M x 4N; per-wave 128x64; acc[8][2].
// LDS 96KB: 2 buf x {A 32KB, B 16KB}; rows 128B; slot^(row&7) swizzle (src pre-swz).
// Per K-tile:
//  P0: rd af[8]@kh0 | SSA(t+1) | vmcnt(4)->SB(t) landed | BAR | rd b@kh0+kh1 |
//      lgkm0 | 16 MFMA kh0
//  P1: rd af[8]@kh1 | SSB(t+1) | vmcnt(2)->SA(t+1) landed | lgkm0 (reads done
//      pre-barrier => next STAGE-A safe) | BAR | 16 MFMA kh1 (regs only)
// b-frags read once per tile (20 ds_reads/tile). Counted vmcnt, never drained.
// Rect XCD swizzle: co-resident 32 blocks/XCD = 4by x 8bx rectangle.
// EPI: 0 store bf16; 3 Cf = Res + v (fp32).
// =====================================================================================
template <int EPI>
__global__ __launch_bounds__(512, 2) void gemm_s(const u16* __restrict__ A, const u16* __restrict__ Bt,
                                                 int M, int N, int K,
                                                 u16* __restrict__ Cb, float* __restrict__ Cf,
                                                 const float* __restrict__ Res) {
  __shared__ char lds[98304];
  const int tid = threadIdx.x, lane = tid & 63, w = tid >> 6;
  const int wm = w >> 2, wn = w & 3;
  const int GX = gridDim.x;
  const int bid = blockIdx.y * GX + blockIdx.x;
  const int xcd = bid & 7, ii = bid >> 3;
  const int j = ii & 31, rin = ii >> 5;
  const int rectIdx = rin * 8 + xcd;
  const int nry = gridDim.y >> 2;
  const int ry = rectIdx % nry, rx = rectIdx / nry;
  const int by = ry * 4 + (j >> 3), bx = rx * 8 + (j & 7);
  const int m0 = by * 256, n0 = bx * 128;
  const int NT = K >> 6;

  const int srow = w * 8 + (lane >> 3);
  const int kko = ((lane & 7) ^ (lane >> 3)) * 8;
  const u16* Asrc = A + (size_t)(m0 + srow) * K + kko;
  const u16* Bsrc = Bt + (size_t)(n0 + srow) * K + kko;
  const int wofs = w * 1024;

#define SSA(buf, kt)                                                                  \
  {                                                                                   \
    gl_lds16(Asrc + (size_t)(kt) * 64, lds + (buf) * 49152 + wofs);                   \
    gl_lds16(Asrc + 64 * (size_t)K + (size_t)(kt) * 64, lds + (buf) * 49152 + 8192 + wofs);   \
    gl_lds16(Asrc + 128 * (size_t)K + (size_t)(kt) * 64, lds + (buf) * 49152 + 16384 + wofs); \
    gl_lds16(Asrc + 192 * (size_t)K + (size_t)(kt) * 64, lds + (buf) * 49152 + 24576 + wofs); \
  }
#define SSB(buf, kt)                                                                  \
  {                                                                                   \
    gl_lds16(Bsrc + (size_t)(kt) * 64, lds + (buf) * 49152 + 32768 + wofs);           \
    gl_lds16(Bsrc + 64 * (size_t)K + (size_t)(kt) * 64, lds + (buf) * 49152 + 40960 + wofs);  \
  }

  const int l15 = lane & 15, l4 = lane >> 4;
  const int kq0 = ((l4) ^ (l15 & 7)) << 4;
  const int kq1 = ((4 + l4) ^ (l15 & 7)) << 4;
  const int abase = wm * 16384 + l15 * 128;
  const int bbase = 32768 + (wn * 32 + l15) * 128;

  const f32x4 fz = {0.f, 0.f, 0.f, 0.f};
  f32x4 acc[8][2];
#pragma unroll
  for (int i = 0; i < 8; i++) { acc[i][0] = fz; acc[i][1] = fz; }
  bf16x8 af[8], bq0[2], bq1[2];

  SSA(0, 0);
  SSB(0, 0);
  asm volatile("s_waitcnt vmcnt(2)" ::: "memory");
  __builtin_amdgcn_s_barrier();

  for (int t = 0; t < NT; ++t) {
    const int buf = t & 1, nb = buf ^ 1;
    const char* Lb = lds + buf * 49152;
    const int t1 = (t + 1 < NT) ? t + 1 : NT - 1;
    // ---------- P0: kh0 ----------
#pragma unroll
    for (int mf = 0; mf < 8; mf++) af[mf] = *(const bf16x8*)(Lb + abase + mf * 2048 + kq0);
    SSA(nb, t1);
    asm volatile("s_waitcnt vmcnt(4)" ::: "memory");
    __builtin_amdgcn_s_barrier();
    bq0[0] = *(const bf16x8*)(Lb + bbase + kq0);
    bq0[1] = *(const bf16x8*)(Lb + bbase + 2048 + kq0);
    bq1[0] = *(const bf16x8*)(Lb + bbase + kq1);
    bq1[1] = *(const bf16x8*)(Lb + bbase + 2048 + kq1);
    asm volatile("s_waitcnt lgkmcnt(0)" ::: "memory");
    __builtin_amdgcn_sched_barrier(0);
    __builtin_amdgcn_s_setprio(1);
#pragma unroll
    for (int mf = 0; mf < 8; mf++) {
      acc[mf][0] = __builtin_amdgcn_mfma_f32_16x16x32_bf16(af[mf], bq0[0], acc[mf][0], 0, 0, 0);
      acc[mf][1] = __builtin_amdgcn_mfma_f32_16x16x32_bf16(af[mf], bq0[1], acc[mf][1], 0, 0, 0);
    }
    __builtin_amdgcn_s_setprio(0);
    // ---------- P1: kh1 ----------
#pragma unroll
    for (int mf = 0; mf < 8; mf++) af[mf] = *(const bf16x8*)(Lb + abase + mf * 2048 + kq1);
    SSB(nb, t1);
    asm volatile("s_waitcnt vmcnt(2)" ::: "memory");
    asm volatile("s_waitcnt lgkmcnt(0)" ::: "memory");
    __builtin_amdgcn_sched_barrier(0);
    __builtin_amdgcn_s_barrier();
    __builtin_amdgcn_s_setprio(1);
#pragma unroll
    for (int mf = 0; mf < 8; mf++) {
      acc[mf][0] = __builtin_amdgcn_mfma_f32_16x16x32_bf16(af[mf], bq1[0], acc[mf][0], 0, 0, 0);
      acc[mf][1] = __builtin_amdgcn_mfma_f32_16x16x32_bf16(af[mf], bq1[1], acc[mf][1], 0, 0, 0);
    }
    __builtin_amdgcn_s_setprio(0);
  }
  asm volatile("s_waitcnt vmcnt(0)" ::: "memory");

  // ---------- epilogue ----------
#pragma unroll
  for (int mf = 0; mf < 8; mf++) {
#pragma unroll
    for (int jr = 0; jr < 4; jr++) {
      const int m = m0 + wm * 128 + mf * 16 + l4 * 4 + jr;
#pragma unroll
      for (int nf = 0; nf < 2; nf++) {
        const int n = n0 + wn * 32 + nf * 16 + l15;
        float v = acc[mf][nf][jr];
        size_t idx = (size_t)m * N + n;
        if (EPI == 0) {
          Cb[idx] = f2b(v);
        } else {
          Cf[idx] = Res[idx] + v;
        }
      }
    }
  }
#undef SSA
#undef SSB
}

// =====================================================================================
// gemm_fgu: fused gate+up (schedule unchanged; rect XCD swizzle).
// =====================================================================================
__global__ __launch_bounds__(512, 2) void gemm_fgu(const u16* __restrict__ A, const u16* __restrict__ Bg,
                                                   const u16* __restrict__ Bu, u16* __restrict__ G) {
  __shared__ char lds[131072];
  const int tid = threadIdx.x, lane = tid & 63, w = tid >> 6;
  const int wm = w >> 2, wn = w & 3;
  // rect XCD swizzle: grid (64,16)=1024; 32 rects of 4by x 8bx; 4 rects/XCD.
  const int bid = blockIdx.y * 64 + blockIdx.x;
  const int xcd = bid & 7, ii = bid >> 3;
  const int j = ii & 31, rin = ii >> 5;
  const int rectIdx = rin * 8 + xcd;
  const int ry = rectIdx & 3, rx = rectIdx >> 2;
  const int by = ry * 4 + (j >> 3), bx = rx * 8 + (j & 7);
  const int m0 = by * 256, n0 = bx * 128;
  const int NT = 32;

  const int srow = w * 8 + (lane >> 3);
  const int kko = ((lane & 7) ^ (lane >> 3)) * 8;
  const u16* Asrc = A + (size_t)(m0 + srow) * 2048 + kko;
  const u16* Bgsrc = Bg + (size_t)(n0 + srow) * 2048 + kko;
  const u16* Busrc = Bu + (size_t)(n0 + srow) * 2048 + kko;
  const int wofs = w * 1024;

#define SA0(buf, kt)                                                        \
  {                                                                         \
    gl_lds16(Asrc + (kt) * 64, lds + (buf) * 65536 + wofs);                 \
    gl_lds16(Asrc + 64 * 2048 + (kt) * 64, lds + (buf) * 65536 + 8192 + wofs); \
  }
#define SA1(buf, kt)                                                              \
  {                                                                               \
    gl_lds16(Asrc + 128 * 2048 + (kt) * 64, lds + (buf) * 65536 + 16384 + wofs);  \
    gl_lds16(Asrc + 192 * 2048 + (kt) * 64, lds + (buf) * 65536 + 24576 + wofs);  \
  }
#define SBG(buf, kt)                                                              \
  {                                                                               \
    gl_lds16(Bgsrc + (kt) * 64, lds + (buf) * 65536 + 32768 + wofs);              \
    gl_lds16(Bgsrc + 64 * 2048 + (kt) * 64, lds + (buf) * 65536 + 40960 + wofs);  \
  }
#define SBU(buf, kt)                                                              \
  {                                                                               \
    gl_lds16(Busrc + (kt) * 64, lds + (buf) * 65536 + 49152 + wofs);              \
    gl_lds16(Busrc + 64 * 2048 + (kt) * 64, lds + (buf) * 65536 + 57344 + wofs);  \
  }
#define LG0 { asm volatile("s_waitcnt lgkmcnt(0)" ::: "memory"); __builtin_amdgcn_sched_barrier(0); }

  const int l15 = lane & 15, l4 = lane >> 4;
  const int kq0 = ((l4) ^ (l15 & 7)) << 4;
  const int kq1 = ((4 + l4) ^ (l15 & 7)) << 4;
  const int abase = (wm * 128 + l15) * 128;
  const int gbase = 32768 + (wn * 32 + l15) * 128;
  const int ubase = 49152 + (wn * 32 + l15) * 128;

  const f32x4 fz = {0.f, 0.f, 0.f, 0.f};
  f32x4 ag[8][2], au[8][2];
#pragma unroll
  for (int i = 0; i < 8; i++)
#pragma unroll
    for (int jj = 0; jj < 2; jj++) { ag[i][jj] = fz; au[i][jj] = fz; }
  bf16x8 af[8], bgf[2], buf2[2];

  SA0(0, 0);
  SBG(0, 0);
  SA1(0, 0);
  SBU(0, 0);
  asm volatile("s_waitcnt vmcnt(2)" ::: "memory");
  __builtin_amdgcn_s_barrier();

  for (int t = 0; t < NT; ++t) {
    const int buf = t & 1, nb = buf ^ 1;
    const char* Lb = lds + buf * 65536;
    const int t1 = (t + 1 < NT) ? t + 1 : NT - 1;
    // P0: G kh0
#pragma unroll
    for (int mf = 0; mf < 8; mf++) af[mf] = *(const bf16x8*)(Lb + abase + mf * 2048 + kq0);
    bgf[0] = *(const bf16x8*)(Lb + gbase + kq0);
    bgf[1] = *(const bf16x8*)(Lb + gbase + 2048 + kq0);
    SA0(nb, t1);
    SBG(nb, t1);
    __builtin_amdgcn_s_barrier();
    LG0;
    __builtin_amdgcn_s_setprio(1);
#pragma unroll
    for (int mf = 0; mf < 8; mf++) {
      ag[mf][0] = __builtin_amdgcn_mfma_f32_16x16x32_bf16(af[mf], bgf[0], ag[mf][0], 0, 0, 0);
      ag[mf][1] = __builtin_amdgcn_mfma_f32_16x16x32_bf16(af[mf], bgf[1], ag[mf][1], 0, 0, 0);
    }
    __builtin_amdgcn_s_setprio(0);
    asm volatile("s_waitcnt vmcnt(4)" ::: "memory");
    __builtin_amdgcn_s_barrier();
    // P1: U kh0
    buf2[0] = *(const bf16x8*)(Lb + ubase + kq0);
    buf2[1] = *(const bf16x8*)(Lb + ubase + 2048 + kq0);
    SA1(nb, t1);
    __builtin_amdgcn_s_barrier();
    LG0;
    __builtin_amdgcn_s_setprio(1);
#pragma unroll
    for (int mf = 0; mf < 8; mf++) {
      au[mf][0] = __builtin_amdgcn_mfma_f32_16x16x32_bf16(af[mf], buf2[0], au[mf][0], 0, 0, 0);
      au[mf][1] = __builtin_amdgcn_mfma_f32_16x16x32_bf16(af[mf], buf2[1], au[mf][1], 0, 0, 0);
    }
    __builtin_amdgcn_s_setprio(0);
    __builtin_amdgcn_s_barrier();
    // P2: G kh1
#pragma unroll
    for (int mf = 0; mf < 8; mf++) af[mf] = *(const bf16x8*)(Lb + abase + mf * 2048 + kq1);
    bgf[0] = *(const bf16x8*)(Lb + gbase + kq1);
    bgf[1] = *(const bf16x8*)(Lb + gbase + 2048 + kq1);
    __builtin_amdgcn_s_barrier();
    LG0;
    __builtin_amdgcn_s_setprio(1);
#pragma unroll
    for (int mf = 0; mf < 8; mf++) {
      ag[mf][0] = __builtin_amdgcn_mfma_f32_16x16x32_bf16(af[mf], bgf[0], ag[mf][0], 0, 0, 0);
      ag[mf][1] = __builtin_amdgcn_mfma_f32_16x16x32_bf16(af[mf], bgf[1], ag[mf][1], 0, 0, 0);
    }
    __builtin_amdgcn_s_setprio(0);
    __builtin_amdgcn_s_barrier();
    // P3: U kh1
    buf2[0] = *(const bf16x8*)(Lb + ubase + kq1);
    buf2[1] = *(const bf16x8*)(Lb + ubase + 2048 + kq1);
    SBU(nb, t1);
    __builtin_amdgcn_s_barrier();
    LG0;
    __builtin_amdgcn_s_setprio(1);
#pragma unroll
    for (int mf = 0; mf < 8; mf++) {
      au[mf][0] = __builtin_amdgcn_mfma_f32_16x16x32_bf16(af[mf], buf2[0], au[mf][0], 0, 0, 0);
      au[mf][1] = __builtin_amdgcn_mfma_f32_16x16x32_bf16(af[mf], buf2[1], au[mf][1], 0, 0, 0);
    }
    __builtin_amdgcn_s_setprio(0);
    asm volatile("s_waitcnt vmcnt(2)" ::: "memory");
    __builtin_amdgcn_s_barrier();
  }
  asm volatile("s_waitcnt vmcnt(0)" ::: "memory");

  // epilogue: G = f2b(silu(g) * u)
#pragma unroll
  for (int mf = 0; mf < 8; mf++) {
#pragma unroll
    for (int jr = 0; jr < 4; jr++) {
      const int m = m0 + wm * 128 + mf * 16 + l4 * 4 + jr;
#pragma unroll
      for (int nf = 0; nf < 2; nf++) {
        const int n = n0 + wn * 32 + nf * 16 + l15;
        float g = ag[mf][nf][jr];
        float u = au[mf][nf][jr];
        float sg = g / (1.f + __expf(-g));
        G[(size_t)m * IDIM + n] = f2b(sg * u);
      }
    }
  }
#undef SA0
#undef SA1
#undef SBG
#undef SBU
#undef LG0
}

// =====================================================================================
// flash attention (unchanged): swapped-operand 32x32x16, in-register softmax.
// =====================================================================================
__global__ __launch_bounds__(512, 2) void attn_k(const u16* __restrict__ qkv, const u16* __restrict__ vt,
                                                 u16* __restrict__ out) {
  __shared__ char Kl[2][16384];
  __shared__ char Vl[2][16384];
  int tid = threadIdx.x, lane = tid & 63, w = tid >> 6;
  int bid = blockIdx.y * 8 + blockIdx.x;
  int swz = (bid & 7) * 32 + (bid >> 3);
  int qb = swz & 7, bh = swz >> 3;
  int b = bh >> 4, h = bh & 15;
  int l31 = lane & 31, hi = lane >> 5;
  const float c = 0.088388347648318447f * 1.4426950408889634f;
  const float RT = 90.51f;

  const int qrow = qb * 256 + w * 32 + l31;
  bf16x8 q[8];
  {
    const u16* qp = qkv + (size_t)(b * SEQ + qrow) * 6144 + h * HEADD + hi * 8;
#pragma unroll
    for (int dt = 0; dt < 8; dt++) q[dt] = *(const bf16x8*)(qp + dt * 16);
  }
  f32x16 o[4];
#pragma unroll
  for (int i = 0; i < 4; i++)
#pragma unroll
    for (int j = 0; j < 16; j++) o[i][j] = 0.f;
  float mrow = -1e30f, lrow = 0.f;

#define ASTAGE(buf, t)                                                                     \
  {                                                                                        \
    int kv0_ = (t) * 64;                                                                   \
    _Pragma("unroll") for (int i = 0; i < 2; i++) {                                        \
      int r = w * 8 + i * 4 + (lane >> 4);                                                 \
      int col = ((lane & 15) ^ (r & 15)) * 8;                                              \
      const u16* src = qkv + (size_t)(b * SEQ + kv0_ + r) * 6144 + HDIM + h * HEADD + col; \
      gl_lds16(src, &Kl[buf][(w * 8 + i * 4) * 256]);                                      \
    }                                                                                      \
    _Pragma("unroll") for (int i = 0; i < 2; i++) {                                        \
      int d = w * 16 + i * 8 + (lane >> 3);                                                \
      int col = ((lane & 7) ^ (d & 7)) * 8;                                                \
      const u16* src = vt + (size_t)(bh * HEADD + d) * SEQ + kv0_ + col;                   \
      gl_lds16(src, &Vl[buf][(w * 16 + i * 8) * 128]);                                     \
    }                                                                                      \
  }

  ASTAGE(0, 0);
  __syncthreads();

  for (int t = 0; t < SEQ / 64; t++) {
    const int buf = t & 1;
    if (t + 1 < SEQ / 64) ASTAGE(buf ^ 1, t + 1);
    const char* Kb = &Kl[buf][0];
    const char* Vb = &Vl[buf][0];
    f32x16 s0, s1;
#pragma unroll
    for (int j = 0; j < 16; j++) { s0[j] = 0.f; s1[j] = 0.f; }
    const int ksl = l31 & 15;
    __builtin_amdgcn_s_setprio(1);
#pragma unroll
    for (int dt = 0; dt < 8; dt++) {
      bf16x8 k0 = *(const bf16x8*)(Kb + (l31)*256 + (((dt * 2 + hi) ^ ksl) << 4));
      bf16x8 k1 = *(const bf16x8*)(Kb + (32 + l31) * 256 + (((dt * 2 + hi) ^ ksl) << 4));
      s0 = __builtin_amdgcn_mfma_f32_32x32x16_bf16(k0, q[dt], s0, 0, 0, 0);
      s1 = __builtin_amdgcn_mfma_f32_32x32x16_bf16(k1, q[dt], s1, 0, 0, 0);
    }
    __builtin_amdgcn_s_setprio(0);
    float m8[8];
#pragma unroll
    for (int g = 0; g < 4; g++) {
      m8[g] = fmaxf(fmaxf(s0[4 * g], s0[4 * g + 1]), fmaxf(s0[4 * g + 2], s0[4 * g + 3]));
      m8[4 + g] = fmaxf(fmaxf(s1[4 * g], s1[4 * g + 1]), fmaxf(s1[4 * g + 2], s1[4 * g + 3]));
    }
    float vmax = fmaxf(fmaxf(fmaxf(m8[0], m8[1]), fmaxf(m8[2], m8[3])),
                       fmaxf(fmaxf(m8[4], m8[5]), fmaxf(m8[6], m8[7])));
    {
      uv2 pr = __builtin_amdgcn_permlane32_swap(__builtin_bit_cast(unsigned, vmax),
                                                __builtin_bit_cast(unsigned, vmax), false, false);
      vmax = fmaxf(__builtin_bit_cast(float, pr[0]), __builtin_bit_cast(float, pr[1]));
    }
    if (__any(vmax > mrow + RT)) {
      float mnew = fmaxf(mrow, vmax);
      float alpha = exp2f((mrow - mnew) * c);
      mrow = mnew;
      lrow *= alpha;
#pragma unroll
      for (int i = 0; i < 4; i++)
#pragma unroll
        for (int j = 0; j < 16; j++) o[i][j] *= alpha;
    }
    const float mc = mrow * c;
    float r4[4] = {0.f, 0.f, 0.f, 0.f};
#pragma unroll
    for (int j = 0; j < 16; j++) {
      s0[j] = exp2f(s0[j] * c - mc);
      r4[j & 3] += s0[j];
    }
#pragma unroll
    for (int j = 0; j < 16; j++) {
      s1[j] = exp2f(s1[j] * c - mc);
      r4[j & 3] += s1[j];
    }
    float rsum = (r4[0] + r4[1]) + (r4[2] + r4[3]);
    {
      uv2 pr = __builtin_amdgcn_permlane32_swap(__builtin_bit_cast(unsigned, rsum),
                                                __builtin_bit_cast(unsigned, rsum), false, false);
      rsum = __builtin_bit_cast(float, pr[0]) + __builtin_bit_cast(float, pr[1]);
    }
    lrow += rsum;
    bf16x8 pa[4];
#pragma unroll
    for (int half = 0; half < 2; half++) {
      const f32x16& sv = half ? s1 : s0;
#pragma unroll
      for (int blk = 0; blk < 2; blk++) {
        int base = blk * 8;
        unsigned A = cvtpk(sv[base + 0], sv[base + 1]);
        unsigned B = cvtpk(sv[base + 2], sv[base + 3]);
        unsigned C = cvtpk(sv[base + 4], sv[base + 5]);
        unsigned D = cvtpk(sv[base + 6], sv[base + 7]);
        uv2 ac = __builtin_amdgcn_permlane32_swap(A, C, false, false);
        uv2 bd = __builtin_amdgcn_permlane32_swap(B, D, false, false);
        u32x4 w4;
        w4[0] = ac[0]; w4[1] = bd[0]; w4[2] = ac[1]; w4[3] = bd[1];
        pa[half * 2 + blk] = __builtin_bit_cast(bf16x8, w4);
      }
    }
    __builtin_amdgcn_s_setprio(1);
#pragma unroll
    for (int dt4 = 0; dt4 < 4; dt4++) {
      const char* vbase = Vb + (dt4 * 32 + l31) * 128;
      const int vsl = l31 & 7;
#pragma unroll
      for (int ks = 0; ks < 4; ks++) {
        bf16x8 vb = *(const bf16x8*)(vbase + (((ks * 2 + hi) ^ vsl) << 4));
        o[dt4] = __builtin_amdgcn_mfma_f32_32x32x16_bf16(vb, pa[ks], o[dt4], 0, 0, 0);
      }
    }
    __builtin_amdgcn_s_setprio(0);
    __syncthreads();
  }
#undef ASTAGE

  const float linv = 1.0f / lrow;
  u16* orow = out + (size_t)(b * SEQ + qrow) * HDIM + h * HEADD;
#pragma unroll
  for (int dt4 = 0; dt4 < 4; dt4++) {
#pragma unroll
    for (int g = 0; g < 4; g++) {
      u32x2 st;
      st[0] = cvtpk(o[dt4][4 * g + 0] * linv, o[dt4][4 * g + 1] * linv);
      st[1] = cvtpk(o[dt4][4 * g + 2] * linv, o[dt4][4 * g + 3] * linv);
      *(u32x2*)(orow + dt4 * 32 + 8 * g + 4 * hi) = st;
    }
  }
}

extern "C" void kernel_launch(void* const* d_in, const int* in_sizes, int n_in,
                              void* d_out, int out_size, void* d_ws, size_t ws_size,
                              hipStream_t stream) {
  const float* hs  = (const float*)d_in[0];
  const float* wq  = (const float*)d_in[1];
  const float* wk  = (const float*)d_in[2];
  const float* wv  = (const float*)d_in[3];
  const float* wo  = (const float*)d_in[4];
  const float* wg  = (const float*)d_in[5];
  const float* wu  = (const float*)d_in[6];
  const float* wd  = (const float*)d_in[7];
  const float* ln1 = (const float*)d_in[8];
  const float* ln2 = (const float*)d_in[9];
  char* ws = (char*)d_ws;
  u16*   wqkvT = (u16*)(ws);
  u16*   woT   = (u16*)(ws + 25165824ull);
  u16*   wgT   = (u16*)(ws + 33554432ull);
  u16*   wuT   = (u16*)(ws + 67108864ull);
  u16*   wdT   = (u16*)(ws + 100663296ull);
  u16*   xb    = (u16*)(ws + 134217728ull);
  float* hid   = (float*)(ws + 150994944ull);
  u16*   qkv   = (u16*)(ws + 184549376ull);
  u16*   vtb   = (u16*)(ws + 234881024ull);
  u16*   attn  = (u16*)(ws + 251658368ull);
  u16*   g     = qkv;  // alias M x I bf16 over qkv+vt region

  wtrans_all<<<16384, 256, 0, stream>>>(wq, wk, wv, wo, wg, wu, wd, wqkvT, woT, wgT, wuT, wdT);

  rmsnorm_k<<<MTOK, 256, 0, stream>>>(hs, ln1, xb);
  gemm_s<0><<<dim3(48, 16), 512, 0, stream>>>(xb, wqkvT, MTOK, 6144, HDIM, qkv, nullptr, nullptr);
  vtrans_k<<<dim3(64, 4, 32), dim3(32, 8), 0, stream>>>(qkv, vtb);
  attn_k<<<dim3(8, 32), 512, 0, stream>>>(qkv, vtb, attn);
  gemm_s<3><<<dim3(16, 16), 512, 0, stream>>>(attn, woT, MTOK, HDIM, HDIM, nullptr, hid, hs);
  rmsnorm_k<<<MTOK, 256, 0, stream>>>(hid, ln2, xb);
  gemm_fgu<<<dim3(64, 16), 512, 0, stream>>>(xb, wgT, wuT, g);
  gemm_s<3><<<dim3(16, 16), 512, 0, stream>>>(g, wdT, MTOK, HDIM, IDIM, nullptr, (float*)d_out, hid);
}

// Round 8
// 716.343 us; speedup vs baseline: 1.5297x; 1.0103x over previous
//
#include <hip/hip_runtime.h>
#include <hip/hip_bf16.h>

#define HDIM 2048
#define IDIM 8192
#define NHEADS 16
#define HEADD 128
#define BATCH 2
#define SEQ 2048
#define MTOK 4096

typedef unsigned short u16;
typedef __bf16 bf16x8 __attribute__((ext_vector_type(8)));
typedef float f32x4 __attribute__((ext_vector_type(4)));
typedef float f32x16 __attribute__((ext_vector_type(16)));
typedef unsigned short u16x8 __attribute__((ext_vector_type(8)));
typedef unsigned int u32x2 __attribute__((ext_vector_type(2)));
typedef unsigned int u32x4 __attribute__((ext_vector_type(4)));
typedef unsigned int uv2 __attribute__((ext_vector_type(2)));

__device__ __forceinline__ u16 f2b(float f) {
  unsigned u = __builtin_bit_cast(unsigned, f);
  u += 0x7FFFu + ((u >> 16) & 1u);
  return (u16)(u >> 16);
}
__device__ __forceinline__ float b2f(u16 b) {
  unsigned u = ((unsigned)b) << 16;
  return __builtin_bit_cast(float, u);
}
__device__ __forceinline__ void gl_lds16(const void* g, void* l) {
  auto gp = (const __attribute__((address_space(1))) unsigned int*)((unsigned long long)g);
  auto lp = (__attribute__((address_space(3))) unsigned int*)((unsigned)(unsigned long long)l);
  __builtin_amdgcn_global_load_lds(gp, lp, 16, 0, 0);
}
__device__ __forceinline__ unsigned cvtpk(float lo, float hi) {
  unsigned r;
  asm("v_cvt_pk_bf16_f32 %0, %1, %2" : "=v"(r) : "v"(lo), "v"(hi));
  return r;
}
// rect XCD mapping: co-resident blocks per XCD form a 4(by) x 8(bx) rectangle.
__device__ __forceinline__ void rect_swz(int gx, int gy, int& bx, int& by) {
  const int bid = blockIdx.y * gx + blockIdx.x;
  const int xcd = bid & 7, ii = bid >> 3;
  const int j = ii & 31, rin = ii >> 5;
  const int rectIdx = rin * 8 + xcd;
  const int nry = gy >> 2;
  const int ry = rectIdx % nry, rx = rectIdx / nry;
  by = ry * 4 + (j >> 3);
  bx = rx * 8 + (j & 7);
}

// ---------------- merged weight transpose-convert: all 7 weights, one launch ----------------
__global__ __launch_bounds__(256) void wtrans_all(const float* __restrict__ wq, const float* __restrict__ wk,
                                                  const float* __restrict__ wv, const float* __restrict__ wo,
                                                  const float* __restrict__ wg, const float* __restrict__ wu,
                                                  const float* __restrict__ wd,
                                                  u16* __restrict__ wqkvT, u16* __restrict__ woT,
                                                  u16* __restrict__ wgT, u16* __restrict__ wuT,
                                                  u16* __restrict__ wdT) {
  int bidf = blockIdx.x;
  const float* W;
  u16* Wt;
  int K, N, rowoff, bx, by;
  if (bidf < 3072) {
    int s = bidf >> 10, r = bidf & 1023;
    W = s == 0 ? wq : (s == 1 ? wk : wv);
    Wt = wqkvT; K = 2048; N = 2048; rowoff = s * 2048;
    bx = r & 31; by = r >> 5;
  } else if (bidf < 4096) {
    int r = bidf - 3072;
    W = wo; Wt = woT; K = 2048; N = 2048; rowoff = 0;
    bx = r & 31; by = r >> 5;
  } else if (bidf < 8192) {
    int r = bidf - 4096;
    W = wg; Wt = wgT; K = 2048; N = 8192; rowoff = 0;
    bx = r & 127; by = r >> 7;
  } else if (bidf < 12288) {
    int r = bidf - 8192;
    W = wu; Wt = wuT; K = 2048; N = 8192; rowoff = 0;
    bx = r & 127; by = r >> 7;
  } else {
    int r = bidf - 12288;
    W = wd; Wt = wdT; K = 8192; N = 2048; rowoff = 0;
    bx = r & 31; by = r >> 5;
  }
  __shared__ float t[64][65];
  int n0 = bx * 64, k0 = by * 64;
  int tid = threadIdx.x;
  int kr = tid >> 4, nc = (tid & 15) * 4;
#pragma unroll
  for (int p = 0; p < 4; p++) {
    float4 v = *(const float4*)&W[(size_t)(k0 + p * 16 + kr) * N + n0 + nc];
    t[nc + 0][p * 16 + kr] = v.x;
    t[nc + 1][p * 16 + kr] = v.y;
    t[nc + 2][p * 16 + kr] = v.z;
    t[nc + 3][p * 16 + kr] = v.w;
  }
  __syncthreads();
  int n = tid >> 2, kq = (tid & 3) * 16;
  u16 tmp[16];
#pragma unroll
  for (int i = 0; i < 16; i++) tmp[i] = f2b(t[n][kq + i]);
  *(u16x8*)&Wt[(size_t)(rowoff + n0 + n) * K + k0 + kq] = *(u16x8*)&tmp[0];
  *(u16x8*)&Wt[(size_t)(rowoff + n0 + n) * K + k0 + kq + 8] = *(u16x8*)&tmp[8];
}

// ---------------- V transpose ----------------
__global__ __launch_bounds__(256) void vtrans_k(const u16* __restrict__ qkv, u16* __restrict__ vt) {
  __shared__ u16 t[32][33];
  int s0 = blockIdx.x * 32, d0 = blockIdx.y * 32, bh = blockIdx.z;
  int b = bh >> 4, h = bh & 15;
  int tx = threadIdx.x, ty = threadIdx.y;
#pragma unroll
  for (int i = 0; i < 4; i++)
    t[ty + i * 8][tx] = qkv[(size_t)(b * SEQ + s0 + ty + i * 8) * 6144 + 4096 + h * HEADD + d0 + tx];
  __syncthreads();
#pragma unroll
  for (int i = 0; i < 4; i++)
    vt[(size_t)(bh * HEADD + d0 + ty + i * 8) * SEQ + s0 + tx] = t[tx][ty + i * 8];
}

// ---------------- RMSNorm: fp32 in -> bf16 out ----------------
__global__ __launch_bounds__(256) void rmsnorm_k(const float* __restrict__ X, const float* __restrict__ W,
                                                 u16* __restrict__ O) {
  int row = blockIdx.x;
  int tid = threadIdx.x;
  const float* x = X + (size_t)row * HDIM;
  float4 v0 = ((const float4*)x)[tid * 2];
  float4 v1 = ((const float4*)x)[tid * 2 + 1];
  float ss = v0.x * v0.x + v0.y * v0.y + v0.z * v0.z + v0.w * v0.w
           + v1.x * v1.x + v1.y * v1.y + v1.z * v1.z + v1.w * v1.w;
#pragma unroll
  for (int off = 32; off > 0; off >>= 1) ss += __shfl_down(ss, off);
  __shared__ float red[4];
  if ((tid & 63) == 0) red[tid >> 6] = ss;
  __syncthreads();
  float rs = rsqrtf((red[0] + red[1] + red[2] + red[3]) * (1.0f / HDIM) + 1e-6f);
  const float* w = W + tid * 8;
  u16* o = O + (size_t)row * HDIM + tid * 8;
  float vals[8] = {v0.x, v0.y, v0.z, v0.w, v1.x, v1.y, v1.z, v1.w};
#pragma unroll
  for (int j = 0; j < 8; j++) o[j] = f2b(w[j] * vals[j] * rs);
}

// =====================================================================================
// gemm_lean: C = A(MxK) * Bt(NxK)^T. BM=256, BN=128, BK=64.
// 512 thr = 8 waves 4M x 2N; per-wave 64x64; acc[4][4]; reads/tile = 16 (0.5/MFMA).
// LDS 96KB: 2 buf x {A 32KB, B 16KB}; rows 128B; slot^(row&7) swizzle, src pre-swz.
// Per K-tile (2 barriers, counted vmcnt, never drained):
//  P0: af[4]@kh0 | SSA(t+1)+4 | vmcnt(4)->SSB(t) landed | BAR | b[4]@kh0 | lgkm0 |
//      16 MFMA kh0
//  P1: af[4]@kh1 + b[4]@kh1 | SSB(t+1)+2 | vmcnt(2)->SSA(t+1) landed | lgkm0 | BAR |
//      16 MFMA kh1
// Overwrite ledger: every LDS region's reads drain (lgkm0) before a barrier that
// precedes the stage targeting it; vmcnt counts verified for 6 loads/tile.
// EPI: 0 store bf16; 3 Cf = Res + v (fp32).
// =====================================================================================
template <int EPI>
__global__ __launch_bounds__(512, 2) void gemm_lean(const u16* __restrict__ A, const u16* __restrict__ Bt,
                                                    int M, int N, int K,
                                                    u16* __restrict__ Cb, float* __restrict__ Cf,
                                                    const float* __restrict__ Res) {
  __shared__ char lds[98304];
  const int tid = threadIdx.x, lane = tid & 63, w = tid >> 6;
  const int wm = w >> 1, wn = w & 1;
  int bx, by;
  rect_swz(gridDim.x, gridDim.y, bx, by);
  const int m0 = by * 256, n0 = bx * 128;
  const int NT = K >> 6;

  const int srow = w * 8 + (lane >> 3);
  const int kko = ((lane & 7) ^ (lane >> 3)) * 8;
  const u16* Asrc = A + (size_t)(m0 + srow) * K + kko;
  const u16* Bsrc = Bt + (size_t)(n0 + srow) * K + kko;
  const int wofs = w * 1024;

#define SSA(buf, kt)                                                                          \
  {                                                                                           \
    gl_lds16(Asrc + (size_t)(kt) * 64, lds + (buf) * 49152 + wofs);                           \
    gl_lds16(Asrc + 64 * (size_t)K + (size_t)(kt) * 64, lds + (buf) * 49152 + 8192 + wofs);   \
    gl_lds16(Asrc + 128 * (size_t)K + (size_t)(kt) * 64, lds + (buf) * 49152 + 16384 + wofs); \
    gl_lds16(Asrc + 192 * (size_t)K + (size_t)(kt) * 64, lds + (buf) * 49152 + 24576 + wofs); \
  }
#define SSB(buf, kt)                                                                         \
  {                                                                                          \
    gl_lds16(Bsrc + (size_t)(kt) * 64, lds + (buf) * 49152 + 32768 + wofs);                  \
    gl_lds16(Bsrc + 64 * (size_t)K + (size_t)(kt) * 64, lds + (buf) * 49152 + 40960 + wofs); \
  }
#define LG0 { asm volatile("s_waitcnt lgkmcnt(0)" ::: "memory"); __builtin_amdgcn_sched_barrier(0); }

  const int l15 = lane & 15, l4 = lane >> 4;
  const int kq0 = ((l4) ^ (l15 & 7)) << 4;
  const int kq1 = ((4 + l4) ^ (l15 & 7)) << 4;
  const int abase = (wm * 64 + l15) * 128;
  const int bbase = 32768 + (wn * 64 + l15) * 128;

  const f32x4 fz = {0.f, 0.f, 0.f, 0.f};
  f32x4 acc[4][4];
#pragma unroll
  for (int i = 0; i < 4; i++)
#pragma unroll
    for (int jj = 0; jj < 4; jj++) acc[i][jj] = fz;
  bf16x8 af0[4], af1[4], b0[4], b1[4];

  SSA(0, 0);
  SSB(0, 0);
  asm volatile("s_waitcnt vmcnt(2)" ::: "memory");
  __builtin_amdgcn_s_barrier();

  for (int t = 0; t < NT; ++t) {
    const int buf = t & 1, nb = buf ^ 1;
    const char* Lb = lds + buf * 49152;
    const int t1 = (t + 1 < NT) ? t + 1 : NT - 1;
    // ---------- P0 ----------
#pragma unroll
    for (int mf = 0; mf < 4; mf++) af0[mf] = *(const bf16x8*)(Lb + abase + mf * 2048 + kq0);
    SSA(nb, t1);
    asm volatile("s_waitcnt vmcnt(4)" ::: "memory");
    __builtin_amdgcn_s_barrier();
#pragma unroll
    for (int nf = 0; nf < 4; nf++) b0[nf] = *(const bf16x8*)(Lb + bbase + nf * 2048 + kq0);
    LG0;
    __builtin_amdgcn_s_setprio(1);
#pragma unroll
    for (int mf = 0; mf < 4; mf++)
#pragma unroll
      for (int nf = 0; nf < 4; nf++)
        acc[mf][nf] = __builtin_amdgcn_mfma_f32_16x16x32_bf16(af0[mf], b0[nf], acc[mf][nf], 0, 0, 0);
    __builtin_amdgcn_s_setprio(0);
    // ---------- P1 ----------
#pragma unroll
    for (int mf = 0; mf < 4; mf++) af1[mf] = *(const bf16x8*)(Lb + abase + mf * 2048 + kq1);
#pragma unroll
    for (int nf = 0; nf < 4; nf++) b1[nf] = *(const bf16x8*)(Lb + bbase + nf * 2048 + kq1);
    SSB(nb, t1);
    asm volatile("s_waitcnt vmcnt(2)" ::: "memory");
    LG0;
    __builtin_amdgcn_s_barrier();
    __builtin_amdgcn_s_setprio(1);
#pragma unroll
    for (int mf = 0; mf < 4; mf++)
#pragma unroll
      for (int nf = 0; nf < 4; nf++)
        acc[mf][nf] = __builtin_amdgcn_mfma_f32_16x16x32_bf16(af1[mf], b1[nf], acc[mf][nf], 0, 0, 0);
    __builtin_amdgcn_s_setprio(0);
  }
  asm volatile("s_waitcnt vmcnt(0)" ::: "memory");

  // ---------- epilogue ----------
#pragma unroll
  for (int mf = 0; mf < 4; mf++) {
#pragma unroll
    for (int jr = 0; jr < 4; jr++) {
      const int m = m0 + wm * 64 + mf * 16 + l4 * 4 + jr;
#pragma unroll
      for (int nf = 0; nf < 4; nf++) {
        const int n = n0 + wn * 64 + nf * 16 + l15;
        float v = acc[mf][nf][jr];
        size_t idx = (size_t)m * N + n;
        if (EPI == 0) {
          Cb[idx] = f2b(v);
        } else {
          Cf[idx] = Res[idx] + v;
        }
      }
    }
  }
#undef SSA
#undef SSB
#undef LG0
}

// =====================================================================================
// gemm_fgu2: fused gate+up, lean 2-barrier schedule. G = silu(A*Wg^T)*(A*Wu^T).
// BM=256, BN=128/matrix, BK=64. 8 waves 2M x 4N; wave 128x32 per matrix; af shared.
// LDS 128KB: 2 buf x {A 32KB, Bg 16KB, Bu 16KB}. 24 reads / 64 MFMA per tile.
//  P0: af[8]@kh0 | SSA(t+1)+4 | vmcnt(4)->B(t) landed | BAR | b 8 reads (both kh) |
//      lgkm0 | 32 MFMA kh0 (G+U)
//  P1: af[8]@kh1 | SBG+SBU(t+1)+4 | vmcnt(4)->SSA(t+1) landed | lgkm0 | BAR |
//      32 MFMA kh1
// =====================================================================================
__global__ __launch_bounds__(512, 2) void gemm_fgu2(const u16* __restrict__ A, const u16* __restrict__ Bg,
                                                    const u16* __restrict__ Bu, u16* __restrict__ G) {
  __shared__ char lds[131072];
  const int tid = threadIdx.x, lane = tid & 63, w = tid >> 6;
  const int wm = w >> 2, wn = w & 3;
  int bx, by;
  rect_swz(64, 16, bx, by);
  const int m0 = by * 256, n0 = bx * 128;
  const int NT = 32;

  const int srow = w * 8 + (lane >> 3);
  const int kko = ((lane & 7) ^ (lane >> 3)) * 8;
  const u16* Asrc = A + (size_t)(m0 + srow) * 2048 + kko;
  const u16* Bgsrc = Bg + (size_t)(n0 + srow) * 2048 + kko;
  const u16* Busrc = Bu + (size_t)(n0 + srow) * 2048 + kko;
  const int wofs = w * 1024;

#define SSA(buf, kt)                                                              \
  {                                                                               \
    gl_lds16(Asrc + (kt) * 64, lds + (buf) * 65536 + wofs);                       \
    gl_lds16(Asrc + 64 * 2048 + (kt) * 64, lds + (buf) * 65536 + 8192 + wofs);    \
    gl_lds16(Asrc + 128 * 2048 + (kt) * 64, lds + (buf) * 65536 + 16384 + wofs);  \
    gl_lds16(Asrc + 192 * 2048 + (kt) * 64, lds + (buf) * 65536 + 24576 + wofs);  \
  }
#define SBGU(buf, kt)                                                             \
  {                                                                               \
    gl_lds16(Bgsrc + (kt) * 64, lds + (buf) * 65536 + 32768 + wofs);              \
    gl_lds16(Bgsrc + 64 * 2048 + (kt) * 64, lds + (buf) * 65536 + 40960 + wofs);  \
    gl_lds16(Busrc + (kt) * 64, lds + (buf) * 65536 + 49152 + wofs);              \
    gl_lds16(Busrc + 64 * 2048 + (kt) * 64, lds + (buf) * 65536 + 57344 + wofs);  \
  }
#define LG0 { asm volatile("s_waitcnt lgkmcnt(0)" ::: "memory"); __builtin_amdgcn_sched_barrier(0); }

  const int l15 = lane & 15, l4 = lane >> 4;
  const int kq0 = ((l4) ^ (l15 & 7)) << 4;
  const int kq1 = ((4 + l4) ^ (l15 & 7)) << 4;
  const int abase = (wm * 128 + l15) * 128;
  const int gbase = 32768 + (wn * 32 + l15) * 128;
  const int ubase = 49152 + (wn * 32 + l15) * 128;

  const f32x4 fz = {0.f, 0.f, 0.f, 0.f};
  f32x4 ag[8][2], au[8][2];
#pragma unroll
  for (int i = 0; i < 8; i++)
#pragma unroll
    for (int jj = 0; jj < 2; jj++) { ag[i][jj] = fz; au[i][jj] = fz; }
  bf16x8 af0[8], af1[8], bg0[2], bg1[2], bu0[2], bu1[2];

  SSA(0, 0);
  SBGU(0, 0);
  asm volatile("s_waitcnt vmcnt(4)" ::: "memory");
  __builtin_amdgcn_s_barrier();

  for (int t = 0; t < NT; ++t) {
    const int buf = t & 1, nb = buf ^ 1;
    const char* Lb = lds + buf * 65536;
    const int t1 = (t + 1 < NT) ? t + 1 : NT - 1;
    // ---------- P0 ----------
#pragma unroll
    for (int mf = 0; mf < 8; mf++) af0[mf] = *(const bf16x8*)(Lb + abase + mf * 2048 + kq0);
    SSA(nb, t1);
    asm volatile("s_waitcnt vmcnt(4)" ::: "memory");
    __builtin_amdgcn_s_barrier();
    bg0[0] = *(const bf16x8*)(Lb + gbase + kq0);
    bg0[1] = *(const bf16x8*)(Lb + gbase + 2048 + kq0);
    bu0[0] = *(const bf16x8*)(Lb + ubase + kq0);
    bu0[1] = *(const bf16x8*)(Lb + ubase + 2048 + kq0);
    bg1[0] = *(const bf16x8*)(Lb + gbase + kq1);
    bg1[1] = *(const bf16x8*)(Lb + gbase + 2048 + kq1);
    bu1[0] = *(const bf16x8*)(Lb + ubase + kq1);
    bu1[1] = *(const bf16x8*)(Lb + ubase + 2048 + kq1);
    LG0;
    __builtin_amdgcn_s_setprio(1);
#pragma unroll
    for (int mf = 0; mf < 8; mf++) {
      ag[mf][0] = __builtin_amdgcn_mfma_f32_16x16x32_bf16(af0[mf], bg0[0], ag[mf][0], 0, 0, 0);
      ag[mf][1] = __builtin_amdgcn_mfma_f32_16x16x32_bf16(af0[mf], bg0[1], ag[mf][1], 0, 0, 0);
      au[mf][0] = __builtin_amdgcn_mfma_f32_16x16x32_bf16(af0[mf], bu0[0], au[mf][0], 0, 0, 0);
      au[mf][1] = __builtin_amdgcn_mfma_f32_16x16x32_bf16(af0[mf], bu0[1], au[mf][1], 0, 0, 0);
    }
    __builtin_amdgcn_s_setprio(0);
    // ---------- P1 ----------
#pragma unroll
    for (int mf = 0; mf < 8; mf++) af1[mf] = *(const bf16x8*)(Lb + abase + mf * 2048 + kq1);
    SBGU(nb, t1);
    asm volatile("s_waitcnt vmcnt(4)" ::: "memory");
    LG0;
    __builtin_amdgcn_s_barrier();
    __builtin_amdgcn_s_setprio(1);
#pragma unroll
    for (int mf = 0; mf < 8; mf++) {
      ag[mf][0] = __builtin_amdgcn_mfma_f32_16x16x32_bf16(af1[mf], bg1[0], ag[mf][0], 0, 0, 0);
      ag[mf][1] = __builtin_amdgcn_mfma_f32_16x16x32_bf16(af1[mf], bg1[1], ag[mf][1], 0, 0, 0);
      au[mf][0] = __builtin_amdgcn_mfma_f32_16x16x32_bf16(af1[mf], bu1[0], au[mf][0], 0, 0, 0);
      au[mf][1] = __builtin_amdgcn_mfma_f32_16x16x32_bf16(af1[mf], bu1[1], au[mf][1], 0, 0, 0);
    }
    __builtin_amdgcn_s_setprio(0);
  }
  asm volatile("s_waitcnt vmcnt(0)" ::: "memory");

  // epilogue: G = f2b(silu(g) * u)
#pragma unroll
  for (int mf = 0; mf < 8; mf++) {
#pragma unroll
    for (int jr = 0; jr < 4; jr++) {
      const int m = m0 + wm * 128 + mf * 16 + l4 * 4 + jr;
#pragma unroll
      for (int nf = 0; nf < 2; nf++) {
        const int n = n0 + wn * 32 + nf * 16 + l15;
        float g = ag[mf][nf][jr];
        float u = au[mf][nf][jr];
        float sg = g / (1.f + __expf(-g));
        G[(size_t)m * IDIM + n] = f2b(sg * u);
      }
    }
  }
#undef SSA
#undef SBGU
#undef LG0
}

// =====================================================================================
// flash attention (unchanged): swapped-operand 32x32x16, in-register softmax.
// =====================================================================================
__global__ __launch_bounds__(512, 2) void attn_k(const u16* __restrict__ qkv, const u16* __restrict__ vt,
                                                 u16* __restrict__ out) {
  __shared__ char Kl[2][16384];
  __shared__ char Vl[2][16384];
  int tid = threadIdx.x, lane = tid & 63, w = tid >> 6;
  int bid = blockIdx.y * 8 + blockIdx.x;
  int swz = (bid & 7) * 32 + (bid >> 3);
  int qb = swz & 7, bh = swz >> 3;
  int b = bh >> 4, h = bh & 15;
  int l31 = lane & 31, hi = lane >> 5;
  const float c = 0.088388347648318447f * 1.4426950408889634f;
  const float RT = 90.51f;

  const int qrow = qb * 256 + w * 32 + l31;
  bf16x8 q[8];
  {
    const u16* qp = qkv + (size_t)(b * SEQ + qrow) * 6144 + h * HEADD + hi * 8;
#pragma unroll
    for (int dt = 0; dt < 8; dt++) q[dt] = *(const bf16x8*)(qp + dt * 16);
  }
  f32x16 o[4];
#pragma unroll
  for (int i = 0; i < 4; i++)
#pragma unroll
    for (int j = 0; j < 16; j++) o[i][j] = 0.f;
  float mrow = -1e30f, lrow = 0.f;

#define ASTAGE(buf, t)                                                                     \
  {                                                                                        \
    int kv0_ = (t) * 64;                                                                   \
    _Pragma("unroll") for (int i = 0; i < 2; i++) {                                        \
      int r = w * 8 + i * 4 + (lane >> 4);                                                 \
      int col = ((lane & 15) ^ (r & 15)) * 8;                                              \
      const u16* src = qkv + (size_t)(b * SEQ + kv0_ + r) * 6144 + HDIM + h * HEADD + col; \
      gl_lds16(src, &Kl[buf][(w * 8 + i * 4) * 256]);                                      \
    }                                                                                      \
    _Pragma("unroll") for (int i = 0; i < 2; i++) {                                        \
      int d = w * 16 + i * 8 + (lane >> 3);                                                \
      int col = ((lane & 7) ^ (d & 7)) * 8;                                                \
      const u16* src = vt + (size_t)(bh * HEADD + d) * SEQ + kv0_ + col;                   \
      gl_lds16(src, &Vl[buf][(w * 16 + i * 8) * 128]);                                     \
    }                                                                                      \
  }

  ASTAGE(0, 0);
  __syncthreads();

  for (int t = 0; t < SEQ / 64; t++) {
    const int buf = t & 1;
    if (t + 1 < SEQ / 64) ASTAGE(buf ^ 1, t + 1);
    const char* Kb = &Kl[buf][0];
    const char* Vb = &Vl[buf][0];
    f32x16 s0, s1;
#pragma unroll
    for (int j = 0; j < 16; j++) { s0[j] = 0.f; s1[j] = 0.f; }
    const int ksl = l31 & 15;
    __builtin_amdgcn_s_setprio(1);
#pragma unroll
    for (int dt = 0; dt < 8; dt++) {
      bf16x8 k0 = *(const bf16x8*)(Kb + (l31)*256 + (((dt * 2 + hi) ^ ksl) << 4));
      bf16x8 k1 = *(const bf16x8*)(Kb + (32 + l31) * 256 + (((dt * 2 + hi) ^ ksl) << 4));
      s0 = __builtin_amdgcn_mfma_f32_32x32x16_bf16(k0, q[dt], s0, 0, 0, 0);
      s1 = __builtin_amdgcn_mfma_f32_32x32x16_bf16(k1, q[dt], s1, 0, 0, 0);
    }
    __builtin_amdgcn_s_setprio(0);
    float m8[8];
#pragma unroll
    for (int g = 0; g < 4; g++) {
      m8[g] = fmaxf(fmaxf(s0[4 * g], s0[4 * g + 1]), fmaxf(s0[4 * g + 2], s0[4 * g + 3]));
      m8[4 + g] = fmaxf(fmaxf(s1[4 * g], s1[4 * g + 1]), fmaxf(s1[4 * g + 2], s1[4 * g + 3]));
    }
    float vmax = fmaxf(fmaxf(fmaxf(m8[0], m8[1]), fmaxf(m8[2], m8[3])),
                       fmaxf(fmaxf(m8[4], m8[5]), fmaxf(m8[6], m8[7])));
    {
      uv2 pr = __builtin_amdgcn_permlane32_swap(__builtin_bit_cast(unsigned, vmax),
                                                __builtin_bit_cast(unsigned, vmax), false, false);
      vmax = fmaxf(__builtin_bit_cast(float, pr[0]), __builtin_bit_cast(float, pr[1]));
    }
    if (__any(vmax > mrow + RT)) {
      float mnew = fmaxf(mrow, vmax);
      float alpha = exp2f((mrow - mnew) * c);
      mrow = mnew;
      lrow *= alpha;
#pragma unroll
      for (int i = 0; i < 4; i++)
#pragma unroll
        for (int j = 0; j < 16; j++) o[i][j] *= alpha;
    }
    const float mc = mrow * c;
    float r4[4] = {0.f, 0.f, 0.f, 0.f};
#pragma unroll
    for (int j = 0; j < 16; j++) {
      s0[j] = exp2f(s0[j] * c - mc);
      r4[j & 3] += s0[j];
    }
#pragma unroll
    for (int j = 0; j < 16; j++) {
      s1[j] = exp2f(s1[j] * c - mc);
      r4[j & 3] += s1[j];
    }
    float rsum = (r4[0] + r4[1]) + (r4[2] + r4[3]);
    {
      uv2 pr = __builtin_amdgcn_permlane32_swap(__builtin_bit_cast(unsigned, rsum),
                                                __builtin_bit_cast(unsigned, rsum), false, false);
      rsum = __builtin_bit_cast(float, pr[0]) + __builtin_bit_cast(float, pr[1]);
    }
    lrow += rsum;
    bf16x8 pa[4];
#pragma unroll
    for (int half = 0; half < 2; half++) {
      const f32x16& sv = half ? s1 : s0;
#pragma unroll
      for (int blk = 0; blk < 2; blk++) {
        int base = blk * 8;
        unsigned A = cvtpk(sv[base + 0], sv[base + 1]);
        unsigned B = cvtpk(sv[base + 2], sv[base + 3]);
        unsigned C = cvtpk(sv[base + 4], sv[base + 5]);
        unsigned D = cvtpk(sv[base + 6], sv[base + 7]);
        uv2 ac = __builtin_amdgcn_permlane32_swap(A, C, false, false);
        uv2 bd = __builtin_amdgcn_permlane32_swap(B, D, false, false);
        u32x4 w4;
        w4[0] = ac[0]; w4[1] = bd[0]; w4[2] = ac[1]; w4[3] = bd[1];
        pa[half * 2 + blk] = __builtin_bit_cast(bf16x8, w4);
      }
    }
    __builtin_amdgcn_s_setprio(1);
#pragma unroll
    for (int dt4 = 0; dt4 < 4; dt4++) {
      const char* vbase = Vb + (dt4 * 32 + l31) * 128;
      const int vsl = l31 & 7;
#pragma unroll
      for (int ks = 0; ks < 4; ks++) {
        bf16x8 vb = *(const bf16x8*)(vbase + (((ks * 2 + hi) ^ vsl) << 4));
        o[dt4] = __builtin_amdgcn_mfma_f32_32x32x16_bf16(vb, pa[ks], o[dt4], 0, 0, 0);
      }
    }
    __builtin_amdgcn_s_setprio(0);
    __syncthreads();
  }
#undef ASTAGE

  const float linv = 1.0f / lrow;
  u16* orow = out + (size_t)(b * SEQ + qrow) * HDIM + h * HEADD;
#pragma unroll
  for (int dt4 = 0; dt4 < 4; dt4++) {
#pragma unroll
    for (int g = 0; g < 4; g++) {
      u32x2 st;
      st[0] = cvtpk(o[dt4][4 * g + 0] * linv, o[dt4][4 * g + 1] * linv);
      st[1] = cvtpk(o[dt4][4 * g + 2] * linv, o[dt4][4 * g + 3] * linv);
      *(u32x2*)(orow + dt4 * 32 + 8 * g + 4 * hi) = st;
    }
  }
}

extern "C" void kernel_launch(void* const* d_in, const int* in_sizes, int n_in,
                              void* d_out, int out_size, void* d_ws, size_t ws_size,
                              hipStream_t stream) {
  const float* hs  = (const float*)d_in[0];
  const float* wq  = (const float*)d_in[1];
  const float* wk  = (const float*)d_in[2];
  const float* wv  = (const float*)d_in[3];
  const float* wo  = (const float*)d_in[4];
  const float* wg  = (const float*)d_in[5];
  const float* wu  = (const float*)d_in[6];
  const float* wd  = (const float*)d_in[7];
  const float* ln1 = (const float*)d_in[8];
  const float* ln2 = (const float*)d_in[9];
  char* ws = (char*)d_ws;
  u16*   wqkvT = (u16*)(ws);
  u16*   woT   = (u16*)(ws + 25165824ull);
  u16*   wgT   = (u16*)(ws + 33554432ull);
  u16*   wuT   = (u16*)(ws + 67108864ull);
  u16*   wdT   = (u16*)(ws + 100663296ull);
  u16*   xb    = (u16*)(ws + 134217728ull);
  float* hid   = (float*)(ws + 150994944ull);
  u16*   qkv   = (u16*)(ws + 184549376ull);
  u16*   vtb   = (u16*)(ws + 234881024ull);
  u16*   attn  = (u16*)(ws + 251658368ull);
  u16*   g     = qkv;  // alias M x I bf16 over qkv+vt region

  wtrans_all<<<16384, 256, 0, stream>>>(wq, wk, wv, wo, wg, wu, wd, wqkvT, woT, wgT, wuT, wdT);

  rmsnorm_k<<<MTOK, 256, 0, stream>>>(hs, ln1, xb);
  gemm_lean<0><<<dim3(48, 16), 512, 0, stream>>>(xb, wqkvT, MTOK, 6144, HDIM, qkv, nullptr, nullptr);
  vtrans_k<<<dim3(64, 4, 32), dim3(32, 8), 0, stream>>>(qkv, vtb);
  attn_k<<<dim3(8, 32), 512, 0, stream>>>(qkv, vtb, attn);
  gemm_lean<3><<<dim3(16, 16), 512, 0, stream>>>(attn, woT, MTOK, HDIM, HDIM, nullptr, hid, hs);
  rmsnorm_k<<<MTOK, 256, 0, stream>>>(hid, ln2, xb);
  gemm_fgu2<<<dim3(64, 16), 512, 0, stream>>>(xb, wgT, wuT, g);
  gemm_lean<3><<<dim3(16, 16), 512, 0, stream>>>(g, wdT, MTOK, HDIM, IDIM, nullptr, (float*)d_out, hid);
}